// Round 3
// baseline (2851.343 us; speedup 1.0000x reference)
//
#include <hip/hip_runtime.h>
#include <cstdint>

__device__ __forceinline__ float clamp01f(float v) { return fminf(fmaxf(v, 0.0f), 1.0f); }

// ======================= edge sort by dst (CSR build) =======================
__global__ __launch_bounds__(256) void edge_count_kernel(
    const int* __restrict__ edst, int* __restrict__ cnt, int E)
{
    int e = blockIdx.x * 256 + threadIdx.x;
    if (e < E) atomicAdd(&cnt[edst[e]], 1);
}

__global__ __launch_bounds__(256) void edge_scatter_kernel(
    const int* __restrict__ esrc, const int* __restrict__ edst,
    int* __restrict__ off, int* __restrict__ srcs, int E)
{
    int e = blockIdx.x * 256 + threadIdx.x;
    if (e >= E) return;
    int slot = atomicAdd(&off[edst[e]], 1);
    srcs[slot] = esrc[e];
}

// exclusive scan (scalar, proven); after edge_scatter, off[v] = segment END
__global__ __launch_bounds__(1024) void scan_kernel(
    const int* __restrict__ cnt, int* __restrict__ off, int Vc)
{
    __shared__ int s_sums[1024];
    const int t = threadIdx.x;
    const int chunk = (Vc + 1023) / 1024;
    const int b0 = min(t * chunk, Vc), b1 = min(b0 + chunk, Vc);
    int s = 0;
    for (int i = b0; i < b1; ++i) s += cnt[i];
    s_sums[t] = s;
    __syncthreads();
    for (int d = 1; d < 1024; d <<= 1) {
        int v = (t >= d) ? s_sums[t - d] : 0;
        __syncthreads();
        s_sums[t] += v;
        __syncthreads();
    }
    int base = (t == 0) ? 0 : s_sums[t - 1];
    for (int i = b0; i < b1; ++i) { off[i] = base; base += cnt[i]; }
}

// ======================= pack (x, pos) into float4 for layer-1 gathers =======
__global__ __launch_bounds__(256) void pack_xpos_kernel(
    const float* __restrict__ x, const float* __restrict__ pos,
    float4* __restrict__ xp, int V)
{
    int n = blockIdx.x * 256 + threadIdx.x;
    if (n >= V) return;
    xp[n] = make_float4(x[n], pos[n * 3 + 0], pos[n * 3 + 1], pos[n * 3 + 2]);
}

// ======================= Layer-1 fused gather-reduce (CIN=3 -> COUT=16) =======
// thread (v,c): one float4 gather per edge, basis+message in-register, epilogue fused.
__global__ __launch_bounds__(256) void l1_fused_kernel(
    const int* __restrict__ off, const int* __restrict__ cnt, const int* __restrict__ srcs,
    const float4* __restrict__ xp,
    const float* __restrict__ Wk, const float* __restrict__ Wr,
    const float* __restrict__ bias, float* __restrict__ out,
    float inv2mv, int V)
{
    int g = blockIdx.x * 256 + threadIdx.x;
    if (g >= V * 16) return;
    const int v = g >> 4, c = g & 15;
    float w[8][3];
#pragma unroll
    for (int s8 = 0; s8 < 8; ++s8)
#pragma unroll
        for (int ci = 0; ci < 3; ++ci)
            w[s8][ci] = Wk[s8 * 48 + ci * 16 + c];
    const float4 d = xp[v];  // x, px, py, pt
    const int e1 = off[v];
    const int n = cnt[v];
    float acc = 0.f;
    int j = e1 - n;
    for (; j + 1 < e1; j += 2) {
        int sa = srcs[j], sb = srcs[j + 1];
        float4 a = xp[sa];
        float4 b = xp[sb];
        {
            float p0 = clamp01f((d.y - a.y) * inv2mv + 0.5f);
            float p1 = clamp01f((d.z - a.z) * inv2mv + 0.5f);
            float p2 = clamp01f((d.w - a.w) * inv2mv + 0.5f);
            float q0 = 1.f - p0, q1 = 1.f - p1, q2 = 1.f - p2;
#pragma unroll
            for (int s8 = 0; s8 < 8; ++s8) {
                float bs = ((s8 & 1) ? p0 : q0) * ((s8 & 2) ? p1 : q1) * ((s8 & 4) ? p2 : q2);
                acc += bs * (a.x * w[s8][0] + a.y * w[s8][1] + a.z * w[s8][2]);
            }
        }
        {
            float p0 = clamp01f((d.y - b.y) * inv2mv + 0.5f);
            float p1 = clamp01f((d.z - b.z) * inv2mv + 0.5f);
            float p2 = clamp01f((d.w - b.w) * inv2mv + 0.5f);
            float q0 = 1.f - p0, q1 = 1.f - p1, q2 = 1.f - p2;
#pragma unroll
            for (int s8 = 0; s8 < 8; ++s8) {
                float bs = ((s8 & 1) ? p0 : q0) * ((s8 & 2) ? p1 : q1) * ((s8 & 4) ? p2 : q2);
                acc += bs * (b.x * w[s8][0] + b.y * w[s8][1] + b.z * w[s8][2]);
            }
        }
    }
    if (j < e1) {
        float4 a = xp[srcs[j]];
        float p0 = clamp01f((d.y - a.y) * inv2mv + 0.5f);
        float p1 = clamp01f((d.z - a.z) * inv2mv + 0.5f);
        float p2 = clamp01f((d.w - a.w) * inv2mv + 0.5f);
        float q0 = 1.f - p0, q1 = 1.f - p1, q2 = 1.f - p2;
#pragma unroll
        for (int s8 = 0; s8 < 8; ++s8) {
            float bs = ((s8 & 1) ? p0 : q0) * ((s8 & 2) ? p1 : q1) * ((s8 & 4) ? p2 : q2);
            acc += bs * (a.x * w[s8][0] + a.y * w[s8][1] + a.z * w[s8][2]);
        }
    }
    float r = acc / fmaxf((float)n, 1.0f)
            + d.x * Wr[c] + d.y * Wr[16 + c] + d.z * Wr[32 + c] + bias[c];
    out[g] = fmaxf(r, 0.0f);
}

// ======================= Layer-2 z quarter: z[v][s8][c16] = hcat[v] @ Wk[s8][:, q*16+c] ===
__global__ __launch_bounds__(256) void z_node_l2_kernel(
    const float* __restrict__ h16, const float* __restrict__ pos,
    const float* __restrict__ Wk, float* __restrict__ z, int V, int q)
{
    int g = blockIdx.x * 256 + threadIdx.x;
    if (g >= V * 128) return;
    int c = g & 15;
    int s8 = (g >> 4) & 7;
    int v = g >> 7;
    const float* w = Wk + s8 * (18 * 64) + q * 16 + c;
    const float* hv = h16 + (size_t)v * 16;
    float acc = 0.f;
#pragma unroll
    for (int ci = 0; ci < 16; ++ci)
        acc += hv[ci] * w[ci * 64];
    acc += pos[v * 3 + 0] * w[16 * 64] + pos[v * 3 + 1] * w[17 * 64];
    z[(size_t)v * 128 + s8 * 16 + c] = acc;
}

// ======================= Layer-2 fused gather-reduce + epilogue (quarter) =======
__global__ __launch_bounds__(256) void z_edge_l2_kernel(
    const int* __restrict__ off, const int* __restrict__ cnt, const int* __restrict__ srcs,
    const float* __restrict__ pos, const float* __restrict__ z,
    const float* __restrict__ h16, const float* __restrict__ Wr,
    const float* __restrict__ bias, float* __restrict__ out,
    float inv2mv, int V, int q)
{
    int g = blockIdx.x * 256 + threadIdx.x;
    if (g >= V * 16) return;
    const int v = g >> 4, c = g & 15;
    const int qc = q * 16 + c;
    const float pdx = pos[v * 3 + 0], pdy = pos[v * 3 + 1], pdt = pos[v * 3 + 2];
    float rb = bias[qc];
    const float* hv = h16 + (size_t)v * 16;
#pragma unroll
    for (int ci = 0; ci < 16; ++ci)
        rb += hv[ci] * Wr[ci * 64 + qc];
    rb += pdx * Wr[16 * 64 + qc] + pdy * Wr[17 * 64 + qc];
    const int e1 = off[v];
    const int n = cnt[v];
    float acc = 0.f;
    for (int j = e1 - n; j < e1; ++j) {
        int s = srcs[j];
        float p0 = clamp01f((pdx - pos[s * 3 + 0]) * inv2mv + 0.5f);
        float p1 = clamp01f((pdy - pos[s * 3 + 1]) * inv2mv + 0.5f);
        float p2 = clamp01f((pdt - pos[s * 3 + 2]) * inv2mv + 0.5f);
        float q0 = 1.f - p0, q1 = 1.f - p1, q2 = 1.f - p2;
        const float* zp = z + (size_t)s * 128 + c;
        acc += q0 * q1 * q2 * zp[0]  + p0 * q1 * q2 * zp[16]
             + q0 * p1 * q2 * zp[32] + p0 * p1 * q2 * zp[48]
             + q0 * q1 * p2 * zp[64] + p0 * q1 * p2 * zp[80]
             + q0 * p1 * p2 * zp[96] + p0 * p1 * p2 * zp[112];
    }
    out[(size_t)v * 64 + qc] = fmaxf(rb + acc / fmaxf((float)n, 1.0f), 0.0f);
}

// ======================= z precompute (layers 3-5): z[v, s, c] = hcat[v] @ Wk[s] =======
template<int CIN, int COUT, int TV>
__global__ __launch_bounds__(256) void z_node_kernel(
    const float* __restrict__ hcat, const float* __restrict__ Wk,
    float* __restrict__ z, int V)
{
    int g = blockIdx.x * 256 + threadIdx.x;
    int c = g % COUT;
    int s8 = (g / COUT) & 7;
    int vb = g / (COUT * 8);
    int v0 = vb * TV;
    if (v0 >= V) return;
    const float* w = Wk + s8 * CIN * COUT + c;
    float acc[TV];
#pragma unroll
    for (int t = 0; t < TV; ++t) acc[t] = 0.f;
    for (int ci = 0; ci < CIN; ++ci) {
        float wv = w[ci * COUT];
#pragma unroll
        for (int t = 0; t < TV; ++t)
            acc[t] += hcat[(v0 + t) * CIN + ci] * wv;
    }
#pragma unroll
    for (int t = 0; t < TV; ++t)
        z[(size_t)(v0 + t) * (8 * COUT) + s8 * COUT + c] = acc[t];
}

// ======================= z-based fused gather-reduce + epilogue (layers 3-5) =======
template<int COUT>
__global__ __launch_bounds__(256) void z_fused_kernel(
    const int* __restrict__ off, const int* __restrict__ cnt, const int* __restrict__ srcs,
    const float* __restrict__ pos, const float* __restrict__ z,
    const float* __restrict__ hcat, const float* __restrict__ Wr,
    const float* __restrict__ bias, float* __restrict__ out,
    float inv2mv, int V, int CIN)
{
    int g = blockIdx.x * 256 + threadIdx.x;
    if (g >= V * COUT) return;
    const int v = g / COUT, c = g % COUT;
    const float pdx = pos[v * 3 + 0], pdy = pos[v * 3 + 1], pdt = pos[v * 3 + 2];
    const int e1 = off[v];
    const int n = cnt[v];
    float acc = 0.f;
    for (int j = e1 - n; j < e1; ++j) {
        int s = srcs[j];
        float p0 = clamp01f((pdx - pos[s * 3 + 0]) * inv2mv + 0.5f);
        float p1 = clamp01f((pdy - pos[s * 3 + 1]) * inv2mv + 0.5f);
        float p2 = clamp01f((pdt - pos[s * 3 + 2]) * inv2mv + 0.5f);
        float q0 = 1.f - p0, q1 = 1.f - p1, q2 = 1.f - p2;
        const float* zp = z + (size_t)s * (8 * COUT) + c;
        float z0 = zp[0],        z1 = zp[COUT],     z2 = zp[2 * COUT], z3 = zp[3 * COUT];
        float z4 = zp[4 * COUT], z5 = zp[5 * COUT], z6 = zp[6 * COUT], z7 = zp[7 * COUT];
        acc += q0 * q1 * q2 * z0 + p0 * q1 * q2 * z1
             + q0 * p1 * q2 * z2 + p0 * p1 * q2 * z3
             + q0 * q1 * p2 * z4 + p0 * q1 * p2 * z5
             + q0 * p1 * p2 * z6 + p0 * p1 * p2 * z7;
    }
    float r = bias[c];
    const float* hv = hcat + (size_t)v * CIN;
    for (int ci = 0; ci < CIN; ++ci)
        r += hv[ci] * Wr[ci * COUT + c];
    r += acc / fmaxf((float)n, 1.0f);
    out[g] = fmaxf(r, 0.0f);
}

// ======================= voxel pooling: counting-sort + copy + sequential reduce =====
__global__ __launch_bounds__(256) void pool_cluster_kernel(
    const float* __restrict__ pos, const int* __restrict__ batch, int bdiv, int V,
    int nx, int ny, int nt, int* __restrict__ cl, int* __restrict__ cnt)
{
    int n = blockIdx.x * 256 + threadIdx.x;
    if (n >= V) return;
    int b = batch ? batch[n] : (n / bdiv);
    float px = pos[n * 3 + 0], py = pos[n * 3 + 1], pt = pos[n * 3 + 2];
    int ix = (int)floorf(px * (float)nx); ix = min(max(ix, 0), nx - 1);
    int iy = (int)floorf(py * (float)ny); iy = min(max(iy, 0), ny - 1);
    int it = (int)floorf(pt * (float)nt); it = min(max(it, 0), nt - 1);
    int c = ((b * nx + ix) * ny + iy) * nt + it;
    cl[n] = c;
    atomicAdd(&cnt[c], 1);
}

__global__ __launch_bounds__(256) void pool_scatter_kernel(
    const int* __restrict__ cl, int* __restrict__ off, int* __restrict__ order, int V)
{
    int n = blockIdx.x * 256 + threadIdx.x;
    if (n >= V) return;
    int slot = atomicAdd(&off[cl[n]], 1);
    order[slot] = n;
}

template<int COUT>
__global__ __launch_bounds__(256) void pool_copy_kernel(
    const int* __restrict__ order, const float* __restrict__ h,
    const float* __restrict__ pos,
    float* __restrict__ S, float* __restrict__ Spos, int V)
{
    int g = blockIdx.x * 256 + threadIdx.x;
    if (g >= V * COUT) return;
    int slot = g / COUT;
    int c = g % COUT;
    int n = order[slot];
    S[g] = h[(size_t)n * COUT + c];
    if (c < 3) Spos[slot * 3 + c] = pos[n * 3 + c];
}

// PAD=2: append pooled pos.xy after COUT channels (hcat layout); PAD=0: plain h.
template<int COUT, int DOMEAN, int PAD>
__global__ __launch_bounds__(256) void pool_reduce_kernel(
    const int* __restrict__ off, const int* __restrict__ cnt,
    const float* __restrict__ S, const float* __restrict__ Spos,
    float* __restrict__ hnext, float* __restrict__ pos_out, int Vc)
{
    const int g = blockIdx.x * 256 + threadIdx.x;
    if (g >= Vc * COUT) return;
    const int v = g / COUT;
    const int c = g % COUT;
    const int e1 = off[v];
    const int n0 = e1 - cnt[v];
    float acc = 0.0f;
    float ps = 0.0f;
    int j = n0;
    for (; j + 3 < e1; j += 4) {
        float a0 = S[(size_t)(j + 0) * COUT + c];
        float a1 = S[(size_t)(j + 1) * COUT + c];
        float a2 = S[(size_t)(j + 2) * COUT + c];
        float a3 = S[(size_t)(j + 3) * COUT + c];
        if (DOMEAN) acc += (a0 + a1) + (a2 + a3);
        else        acc = fmaxf(acc, fmaxf(fmaxf(a0, a1), fmaxf(a2, a3)));
        if (c < 3) {
            float p0 = Spos[(j + 0) * 3 + c];
            float p1 = Spos[(j + 1) * 3 + c];
            float p2 = Spos[(j + 2) * 3 + c];
            float p3 = Spos[(j + 3) * 3 + c];
            ps += (p0 + p1) + (p2 + p3);
        }
    }
    for (; j < e1; ++j) {
        float a0 = S[(size_t)j * COUT + c];
        acc = DOMEAN ? (acc + a0) : fmaxf(acc, a0);
        if (c < 3) ps += Spos[j * 3 + c];
    }
    float m = fmaxf((float)cnt[v], 1.0f);
    float* hp = hnext + (size_t)v * (COUT + PAD);
    hp[c] = DOMEAN ? (acc / m) : acc;
    if (c < 3) {
        float pm = ps / m;
        pos_out[v * 3 + c] = pm;
        if (PAD >= 2 && c < 2) hp[COUT + c] = pm;
    }
}

// ======================= host =======================
extern "C" void kernel_launch(void* const* d_in, const int* in_sizes, int n_in,
                              void* d_out, int out_size, void* d_ws, size_t ws_size,
                              hipStream_t stream)
{
    (void)in_sizes; (void)n_in; (void)out_size;
    const float* x    = (const float*)d_in[0];
    const float* pos0 = (const float*)d_in[1];
    const int*   bat  = (const int*)d_in[2];
    const int* e1 = (const int*)d_in[3];
    const int* e2 = (const int*)d_in[4];
    const int* e3 = (const int*)d_in[5];
    const int* e4 = (const int*)d_in[6];
    const int* e5 = (const int*)d_in[7];
    const float* W1 = (const float*)d_in[8],  *R1 = (const float*)d_in[9],  *B1 = (const float*)d_in[10];
    const float* W2 = (const float*)d_in[11], *R2 = (const float*)d_in[12], *B2 = (const float*)d_in[13];
    const float* W3 = (const float*)d_in[14], *R3 = (const float*)d_in[15], *B3 = (const float*)d_in[16];
    const float* W4 = (const float*)d_in[17], *R4 = (const float*)d_in[18], *B4 = (const float*)d_in[19];
    const float* W5 = (const float*)d_in[20], *R5 = (const float*)d_in[21], *B5 = (const float*)d_in[22];

    const int E1 = 3600000, E2 = 786432, E3 = 196608, E4 = 24576, E5 = 3072;

    if (ws_size < (size_t)21800000 * sizeof(float)) return;
    float* ws = (float*)d_ws;
    // pools (floats): P0 12.6M (z / big scratch) | P1 6.3M (layer out) | P2 1.6M (pooled h in)
    //                 P3 1.0M (CSR ints, L2-5)   | P4 0.3M (pos)
    float* P0 = ws;
    float* P1 = ws + 12600000;
    float* P2 = ws + 18900000;
    int*   P3 = (int*)(ws + 20500000);
    float* P4 = ws + 21500000;

    float* out3 = (float*)d_out;           // 1536*128
    float* hfin = (float*)d_out + 196608;  // 192*128

#define MSI(p, ni) hipMemsetAsync((p), 0, (size_t)(ni) * sizeof(int), stream)

    // Build dst-CSR: cnt/off/srcs at given int base. off[v] = segment END after scatter.
#define ESORT(base, ep, En, Vn)                                                                  \
    int* cnt_ = (base);                                                                          \
    int* off_ = cnt_ + (Vn);                                                                     \
    int* src_ = off_ + (Vn);                                                                     \
    MSI(cnt_, (Vn));                                                                             \
    edge_count_kernel<<<((En) + 255) / 256, 256, 0, stream>>>((ep) + (En), cnt_, En);            \
    scan_kernel<<<1, 1024, 0, stream>>>(cnt_, off_, Vn);                                         \
    edge_scatter_kernel<<<((En) + 255) / 256, 256, 0, stream>>>((ep), (ep) + (En), off_, src_, En)

    // Pool: scratch at float base SB: [SF Vn*COUT][Spos Vn*3][ICL Vn][IORD Vn][ICNT Vc][IOFF Vc]
#define POOL(SB, hsrc, possrc, batp, bdiv, Vn, NX, NY, NT, COUTV, DM, PADV, hdst, posdst)   \
    {                                                                                       \
        int Vc = 4 * (NX) * (NY) * (NT);                                                    \
        float* SF   = (SB);                                                                 \
        float* SPOS = SF + (size_t)(Vn) * (COUTV);                                          \
        int* ICL  = (int*)(SPOS + (size_t)(Vn) * 3);                                        \
        int* IORD = ICL + (Vn);                                                             \
        int* ICNT = IORD + (Vn);                                                            \
        int* IOFF = ICNT + Vc;                                                              \
        MSI(ICNT, Vc);                                                                      \
        pool_cluster_kernel<<<((Vn) + 255) / 256, 256, 0, stream>>>(                        \
            possrc, batp, bdiv, Vn, NX, NY, NT, ICL, ICNT);                                 \
        scan_kernel<<<1, 1024, 0, stream>>>(ICNT, IOFF, Vc);                                \
        pool_scatter_kernel<<<((Vn) + 255) / 256, 256, 0, stream>>>(ICL, IOFF, IORD, Vn);   \
        pool_copy_kernel<COUTV><<<((size_t)(Vn) * (COUTV) + 255) / 256, 256, 0, stream>>>(  \
            IORD, hsrc, possrc, SF, SPOS, Vn);                                              \
        pool_reduce_kernel<COUTV, DM, PADV><<<((size_t)Vc * (COUTV) + 255) / 256, 256, 0,   \
            stream>>>(IOFF, ICNT, SF, SPOS, hdst, posdst, Vc);                              \
    }

    // ---------- Layer 1: 300000 nodes, CIN=3, COUT=16 (CSR gather, float4-packed) ----------
    {
        ESORT((int*)P0, e1, E1, 300000);            // ints [0 .. 4.2M) in P0
        float4* xp4 = (float4*)(P0 + 4200000);      // 1.2M floats [4.2M .. 5.4M)
        pack_xpos_kernel<<<(300000 + 255) / 256, 256, 0, stream>>>(x, pos0, xp4, 300000);
        l1_fused_kernel<<<(300000 * 16) / 256, 256, 0, stream>>>(
            off_, cnt_, src_, xp4, W1, R1, B1, P1, 20.0f, 300000);
        // CSR1 + xp4 dead -> pool scratch at P0. h1p (stride 16) -> P2, pos2 -> P4.
        POOL(P0, P1, pos0, bat, 0, 300000, 64, 48, 8, 16, 0, 0, P2, P4);
    }
    // ---------- Layer 2: 98304 nodes, CIN=18, COUT=64 — quarter-z path, zero atomics ------
    {
        ESORT(P3, e2, E2, 98304);                   // 983K ints in P3
        for (int q = 0; q < 4; ++q) {
            z_node_l2_kernel<<<(98304 * 128) / 256, 256, 0, stream>>>(P2, P4, W2, P0, 98304, q);
            z_edge_l2_kernel<<<(98304 * 16) / 256, 256, 0, stream>>>(
                off_, cnt_, src_, P4, P0, P2, R2, B2, P1, 10.0f, 98304, q);
        }
        // z dead -> pool scratch at P0. h2p (hcat stride 66) -> P2, pos3 -> P4.
        POOL(P0, P1, P4, nullptr, 24576, 98304, 32, 24, 4, 64, 0, 2, P2, P4);
    }
    // ---------- Layer 3: 12288 nodes, CIN=66, COUT=128 (full z path) ----------
    {
        z_node_kernel<66, 128, 8><<<(12288 / 8) * 1024 / 256, 256, 0, stream>>>(P2, W3, P0, 12288);
        ESORT(P3, e3, E3, 12288);
        z_fused_kernel<128><<<(12288 * 128) / 256, 256, 0, stream>>>(
            off_, cnt_, src_, P4, P0, P2, R3, B3, P1, 6.0f, 12288, 66);
        // z3 dead -> pool scratch at P0. h3p (stride 130) -> P2, pos4 -> P4.
        POOL(P0, P1, P4, nullptr, 3072, 12288, 16, 12, 2, 128, 0, 2, P2, P4);
    }
    // ---------- Layer 4: 1536 nodes, CIN=130, COUT=128 -> out3 ----------
    {
        z_node_kernel<130, 128, 8><<<(1536 / 8) * 1024 / 256, 256, 0, stream>>>(P2, W4, P0, 1536);
        ESORT(P3, e4, E4, 1536);
        z_fused_kernel<128><<<(1536 * 128) / 256, 256, 0, stream>>>(
            off_, cnt_, src_, P4, P0, P2, R4, B4, out3, 3.0f, 1536, 130);
        POOL(P0, out3, P4, nullptr, 384, 1536, 8, 6, 1, 128, 1, 2, P2, P4);
    }
    // ---------- Layer 5: 192 nodes, CIN=130, COUT=128 -> hfin ----------
    {
        z_node_kernel<130, 128, 8><<<(192 / 8) * 1024 / 256, 256, 0, stream>>>(P2, W5, P0, 192);
        ESORT(P3, e5, E5, 192);
        z_fused_kernel<128><<<(192 * 128) / 256, 256, 0, stream>>>(
            off_, cnt_, src_, P4, P0, P2, R5, B5, hfin, 1.5f, 192, 130);
    }
#undef POOL
#undef ESORT
#undef MSI
}

// Round 4
// 2157.897 us; speedup vs baseline: 1.3214x; 1.3214x over previous
//
#include <hip/hip_runtime.h>
#include <cstdint>

__device__ __forceinline__ float clamp01f(float v) { return fminf(fmaxf(v, 0.0f), 1.0f); }

// ======================= edge sort by dst (CSR build) =======================
__global__ __launch_bounds__(256) void edge_count_kernel(
    const int* __restrict__ edst, int* __restrict__ cnt, int E)
{
    int e = blockIdx.x * 256 + threadIdx.x;
    if (e < E) atomicAdd(&cnt[edst[e]], 1);
}

__global__ __launch_bounds__(256) void edge_scatter_kernel(
    const int* __restrict__ esrc, const int* __restrict__ edst,
    int* __restrict__ off, int* __restrict__ srcs, int E)
{
    int e = blockIdx.x * 256 + threadIdx.x;
    if (e >= E) return;
    int slot = atomicAdd(&off[edst[e]], 1);
    srcs[slot] = esrc[e];
}

// ============== hierarchical exclusive scan ==============
// scan1: per-block (4096 elems) exclusive scan -> off; block total -> bsum[blockIdx] (if non-null).
__global__ __launch_bounds__(256) void scan1_kernel(
    const int* __restrict__ cnt, int* __restrict__ off, int* __restrict__ bsum, int V)
{
    __shared__ int lds[4096];
    __shared__ int ssum[256];
    const int t = threadIdx.x;
    const int base = blockIdx.x * 4096;
    for (int i = t; i < 4096; i += 256) {
        int g = base + i;
        lds[i] = (g < V) ? cnt[g] : 0;
    }
    __syncthreads();
    int loc[16];
    int s = 0;
#pragma unroll
    for (int k = 0; k < 16; ++k) { loc[k] = s; s += lds[t * 16 + k]; }
    ssum[t] = s;
    __syncthreads();
    for (int d = 1; d < 256; d <<= 1) {
        int v = (t >= d) ? ssum[t - d] : 0;
        __syncthreads();
        ssum[t] += v;
        __syncthreads();
    }
    const int tbase = (t == 0) ? 0 : ssum[t - 1];
    if (t == 255 && bsum) bsum[blockIdx.x] = ssum[255];
#pragma unroll
    for (int k = 0; k < 16; ++k) lds[t * 16 + k] = tbase + loc[k];
    __syncthreads();
    for (int i = t; i < 4096; i += 256) {
        int g = base + i;
        if (g < V) off[g] = lds[i];
    }
}

// scan_add: off[g] += scanned block sums [g/4096]
__global__ __launch_bounds__(256) void scan_add_kernel(
    int* __restrict__ off, const int* __restrict__ bso, int V)
{
    int g = blockIdx.x * 256 + threadIdx.x;
    if (g < V) off[g] += bso[g >> 12];
}

// ======================= pack (x, pos) into float4 for layer-1 gathers =======
__global__ __launch_bounds__(256) void pack_xpos_kernel(
    const float* __restrict__ x, const float* __restrict__ pos,
    float4* __restrict__ xp, int V)
{
    int n = blockIdx.x * 256 + threadIdx.x;
    if (n >= V) return;
    xp[n] = make_float4(x[n], pos[n * 3 + 0], pos[n * 3 + 1], pos[n * 3 + 2]);
}

// ======================= Layer-1 fused gather-reduce (CIN=3 -> COUT=16) =======
__global__ __launch_bounds__(256) void l1_fused_kernel(
    const int* __restrict__ off, const int* __restrict__ cnt, const int* __restrict__ srcs,
    const float4* __restrict__ xp,
    const float* __restrict__ Wk, const float* __restrict__ Wr,
    const float* __restrict__ bias, float* __restrict__ out,
    float inv2mv, int V)
{
    int g = blockIdx.x * 256 + threadIdx.x;
    if (g >= V * 16) return;
    const int v = g >> 4, c = g & 15;
    float w[8][3];
#pragma unroll
    for (int s8 = 0; s8 < 8; ++s8)
#pragma unroll
        for (int ci = 0; ci < 3; ++ci)
            w[s8][ci] = Wk[s8 * 48 + ci * 16 + c];
    const float4 d = xp[v];  // x, px, py, pt
    const int e1 = off[v];
    const int n = cnt[v];
    float acc = 0.f;
    int j = e1 - n;
    for (; j + 1 < e1; j += 2) {
        int sa = srcs[j], sb = srcs[j + 1];
        float4 a = xp[sa];
        float4 b = xp[sb];
        {
            float p0 = clamp01f((d.y - a.y) * inv2mv + 0.5f);
            float p1 = clamp01f((d.z - a.z) * inv2mv + 0.5f);
            float p2 = clamp01f((d.w - a.w) * inv2mv + 0.5f);
            float q0 = 1.f - p0, q1 = 1.f - p1, q2 = 1.f - p2;
#pragma unroll
            for (int s8 = 0; s8 < 8; ++s8) {
                float bs = ((s8 & 1) ? p0 : q0) * ((s8 & 2) ? p1 : q1) * ((s8 & 4) ? p2 : q2);
                acc += bs * (a.x * w[s8][0] + a.y * w[s8][1] + a.z * w[s8][2]);
            }
        }
        {
            float p0 = clamp01f((d.y - b.y) * inv2mv + 0.5f);
            float p1 = clamp01f((d.z - b.z) * inv2mv + 0.5f);
            float p2 = clamp01f((d.w - b.w) * inv2mv + 0.5f);
            float q0 = 1.f - p0, q1 = 1.f - p1, q2 = 1.f - p2;
#pragma unroll
            for (int s8 = 0; s8 < 8; ++s8) {
                float bs = ((s8 & 1) ? p0 : q0) * ((s8 & 2) ? p1 : q1) * ((s8 & 4) ? p2 : q2);
                acc += bs * (b.x * w[s8][0] + b.y * w[s8][1] + b.z * w[s8][2]);
            }
        }
    }
    if (j < e1) {
        float4 a = xp[srcs[j]];
        float p0 = clamp01f((d.y - a.y) * inv2mv + 0.5f);
        float p1 = clamp01f((d.z - a.z) * inv2mv + 0.5f);
        float p2 = clamp01f((d.w - a.w) * inv2mv + 0.5f);
        float q0 = 1.f - p0, q1 = 1.f - p1, q2 = 1.f - p2;
#pragma unroll
        for (int s8 = 0; s8 < 8; ++s8) {
            float bs = ((s8 & 1) ? p0 : q0) * ((s8 & 2) ? p1 : q1) * ((s8 & 4) ? p2 : q2);
            acc += bs * (a.x * w[s8][0] + a.y * w[s8][1] + a.z * w[s8][2]);
        }
    }
    float r = acc / fmaxf((float)n, 1.0f)
            + d.x * Wr[c] + d.y * Wr[16 + c] + d.z * Wr[32 + c] + bias[c];
    out[g] = fmaxf(r, 0.0f);
}

// ======================= Layer-2 z quarter: z[v][s8][c16] = hcat[v] @ Wk[s8][:, q*16+c] ===
__global__ __launch_bounds__(256) void z_node_l2_kernel(
    const float* __restrict__ h16, const float* __restrict__ pos,
    const float* __restrict__ Wk, float* __restrict__ z, int V, int q)
{
    int g = blockIdx.x * 256 + threadIdx.x;
    if (g >= V * 128) return;
    int c = g & 15;
    int s8 = (g >> 4) & 7;
    int v = g >> 7;
    const float* w = Wk + s8 * (18 * 64) + q * 16 + c;
    const float* hv = h16 + (size_t)v * 16;
    float acc = 0.f;
#pragma unroll
    for (int ci = 0; ci < 16; ++ci)
        acc += hv[ci] * w[ci * 64];
    acc += pos[v * 3 + 0] * w[16 * 64] + pos[v * 3 + 1] * w[17 * 64];
    z[(size_t)v * 128 + s8 * 16 + c] = acc;
}

// ======================= Layer-2 fused gather-reduce + epilogue (quarter) =======
__global__ __launch_bounds__(256) void z_edge_l2_kernel(
    const int* __restrict__ off, const int* __restrict__ cnt, const int* __restrict__ srcs,
    const float* __restrict__ pos, const float* __restrict__ z,
    const float* __restrict__ h16, const float* __restrict__ Wr,
    const float* __restrict__ bias, float* __restrict__ out,
    float inv2mv, int V, int q)
{
    int g = blockIdx.x * 256 + threadIdx.x;
    if (g >= V * 16) return;
    const int v = g >> 4, c = g & 15;
    const int qc = q * 16 + c;
    const float pdx = pos[v * 3 + 0], pdy = pos[v * 3 + 1], pdt = pos[v * 3 + 2];
    float rb = bias[qc];
    const float* hv = h16 + (size_t)v * 16;
#pragma unroll
    for (int ci = 0; ci < 16; ++ci)
        rb += hv[ci] * Wr[ci * 64 + qc];
    rb += pdx * Wr[16 * 64 + qc] + pdy * Wr[17 * 64 + qc];
    const int e1 = off[v];
    const int n = cnt[v];
    float acc = 0.f;
    for (int j = e1 - n; j < e1; ++j) {
        int s = srcs[j];
        float p0 = clamp01f((pdx - pos[s * 3 + 0]) * inv2mv + 0.5f);
        float p1 = clamp01f((pdy - pos[s * 3 + 1]) * inv2mv + 0.5f);
        float p2 = clamp01f((pdt - pos[s * 3 + 2]) * inv2mv + 0.5f);
        float q0 = 1.f - p0, q1 = 1.f - p1, q2 = 1.f - p2;
        const float* zp = z + (size_t)s * 128 + c;
        acc += q0 * q1 * q2 * zp[0]  + p0 * q1 * q2 * zp[16]
             + q0 * p1 * q2 * zp[32] + p0 * p1 * q2 * zp[48]
             + q0 * q1 * p2 * zp[64] + p0 * q1 * p2 * zp[80]
             + q0 * p1 * p2 * zp[96] + p0 * p1 * p2 * zp[112];
    }
    out[(size_t)v * 64 + qc] = fmaxf(rb + acc / fmaxf((float)n, 1.0f), 0.0f);
}

// ======================= z precompute (layers 3-5): z[v, s, c] = hcat[v] @ Wk[s] =======
template<int CIN, int COUT, int TV>
__global__ __launch_bounds__(256) void z_node_kernel(
    const float* __restrict__ hcat, const float* __restrict__ Wk,
    float* __restrict__ z, int V)
{
    int g = blockIdx.x * 256 + threadIdx.x;
    int c = g % COUT;
    int s8 = (g / COUT) & 7;
    int vb = g / (COUT * 8);
    int v0 = vb * TV;
    if (v0 >= V) return;
    const float* w = Wk + s8 * CIN * COUT + c;
    float acc[TV];
#pragma unroll
    for (int t = 0; t < TV; ++t) acc[t] = 0.f;
    for (int ci = 0; ci < CIN; ++ci) {
        float wv = w[ci * COUT];
#pragma unroll
        for (int t = 0; t < TV; ++t)
            acc[t] += hcat[(v0 + t) * CIN + ci] * wv;
    }
#pragma unroll
    for (int t = 0; t < TV; ++t)
        z[(size_t)(v0 + t) * (8 * COUT) + s8 * COUT + c] = acc[t];
}

// ======================= z-based fused gather-reduce + epilogue (layers 3-5) =======
template<int COUT>
__global__ __launch_bounds__(256) void z_fused_kernel(
    const int* __restrict__ off, const int* __restrict__ cnt, const int* __restrict__ srcs,
    const float* __restrict__ pos, const float* __restrict__ z,
    const float* __restrict__ hcat, const float* __restrict__ Wr,
    const float* __restrict__ bias, float* __restrict__ out,
    float inv2mv, int V, int CIN)
{
    int g = blockIdx.x * 256 + threadIdx.x;
    if (g >= V * COUT) return;
    const int v = g / COUT, c = g % COUT;
    const float pdx = pos[v * 3 + 0], pdy = pos[v * 3 + 1], pdt = pos[v * 3 + 2];
    const int e1 = off[v];
    const int n = cnt[v];
    float acc = 0.f;
    for (int j = e1 - n; j < e1; ++j) {
        int s = srcs[j];
        float p0 = clamp01f((pdx - pos[s * 3 + 0]) * inv2mv + 0.5f);
        float p1 = clamp01f((pdy - pos[s * 3 + 1]) * inv2mv + 0.5f);
        float p2 = clamp01f((pdt - pos[s * 3 + 2]) * inv2mv + 0.5f);
        float q0 = 1.f - p0, q1 = 1.f - p1, q2 = 1.f - p2;
        const float* zp = z + (size_t)s * (8 * COUT) + c;
        float z0 = zp[0],        z1 = zp[COUT],     z2 = zp[2 * COUT], z3 = zp[3 * COUT];
        float z4 = zp[4 * COUT], z5 = zp[5 * COUT], z6 = zp[6 * COUT], z7 = zp[7 * COUT];
        acc += q0 * q1 * q2 * z0 + p0 * q1 * q2 * z1
             + q0 * p1 * q2 * z2 + p0 * p1 * q2 * z3
             + q0 * q1 * p2 * z4 + p0 * q1 * p2 * z5
             + q0 * p1 * p2 * z6 + p0 * p1 * p2 * z7;
    }
    float r = bias[c];
    const float* hv = hcat + (size_t)v * CIN;
    for (int ci = 0; ci < CIN; ++ci)
        r += hv[ci] * Wr[ci * COUT + c];
    r += acc / fmaxf((float)n, 1.0f);
    out[g] = fmaxf(r, 0.0f);
}

// ======================= voxel pooling: counting-sort + copy + sequential reduce =====
__global__ __launch_bounds__(256) void pool_cluster_kernel(
    const float* __restrict__ pos, const int* __restrict__ batch, int bdiv, int V,
    int nx, int ny, int nt, int* __restrict__ cl, int* __restrict__ cnt)
{
    int n = blockIdx.x * 256 + threadIdx.x;
    if (n >= V) return;
    int b = batch ? batch[n] : (n / bdiv);
    float px = pos[n * 3 + 0], py = pos[n * 3 + 1], pt = pos[n * 3 + 2];
    int ix = (int)floorf(px * (float)nx); ix = min(max(ix, 0), nx - 1);
    int iy = (int)floorf(py * (float)ny); iy = min(max(iy, 0), ny - 1);
    int it = (int)floorf(pt * (float)nt); it = min(max(it, 0), nt - 1);
    int c = ((b * nx + ix) * ny + iy) * nt + it;
    cl[n] = c;
    atomicAdd(&cnt[c], 1);
}

__global__ __launch_bounds__(256) void pool_scatter_kernel(
    const int* __restrict__ cl, int* __restrict__ off, int* __restrict__ order, int V)
{
    int n = blockIdx.x * 256 + threadIdx.x;
    if (n >= V) return;
    int slot = atomicAdd(&off[cl[n]], 1);
    order[slot] = n;
}

template<int COUT>
__global__ __launch_bounds__(256) void pool_copy_kernel(
    const int* __restrict__ order, const float* __restrict__ h,
    const float* __restrict__ pos,
    float* __restrict__ S, float* __restrict__ Spos, int V)
{
    int g = blockIdx.x * 256 + threadIdx.x;
    if (g >= V * COUT) return;
    int slot = g / COUT;
    int c = g % COUT;
    int n = order[slot];
    S[g] = h[(size_t)n * COUT + c];
    if (c < 3) Spos[slot * 3 + c] = pos[n * 3 + c];
}

// PAD=2: append pooled pos.xy after COUT channels (hcat layout); PAD=0: plain h.
template<int COUT, int DOMEAN, int PAD>
__global__ __launch_bounds__(256) void pool_reduce_kernel(
    const int* __restrict__ off, const int* __restrict__ cnt,
    const float* __restrict__ S, const float* __restrict__ Spos,
    float* __restrict__ hnext, float* __restrict__ pos_out, int Vc)
{
    const int g = blockIdx.x * 256 + threadIdx.x;
    if (g >= Vc * COUT) return;
    const int v = g / COUT;
    const int c = g % COUT;
    const int e1 = off[v];
    const int n0 = e1 - cnt[v];
    float acc = 0.0f;
    float ps = 0.0f;
    int j = n0;
    for (; j + 3 < e1; j += 4) {
        float a0 = S[(size_t)(j + 0) * COUT + c];
        float a1 = S[(size_t)(j + 1) * COUT + c];
        float a2 = S[(size_t)(j + 2) * COUT + c];
        float a3 = S[(size_t)(j + 3) * COUT + c];
        if (DOMEAN) acc += (a0 + a1) + (a2 + a3);
        else        acc = fmaxf(acc, fmaxf(fmaxf(a0, a1), fmaxf(a2, a3)));
        if (c < 3) {
            float p0 = Spos[(j + 0) * 3 + c];
            float p1 = Spos[(j + 1) * 3 + c];
            float p2 = Spos[(j + 2) * 3 + c];
            float p3 = Spos[(j + 3) * 3 + c];
            ps += (p0 + p1) + (p2 + p3);
        }
    }
    for (; j < e1; ++j) {
        float a0 = S[(size_t)j * COUT + c];
        acc = DOMEAN ? (acc + a0) : fmaxf(acc, a0);
        if (c < 3) ps += Spos[j * 3 + c];
    }
    float m = fmaxf((float)cnt[v], 1.0f);
    float* hp = hnext + (size_t)v * (COUT + PAD);
    hp[c] = DOMEAN ? (acc / m) : acc;
    if (c < 3) {
        float pm = ps / m;
        pos_out[v * 3 + c] = pm;
        if (PAD >= 2 && c < 2) hp[COUT + c] = pm;
    }
}

// ======================= host =======================
extern "C" void kernel_launch(void* const* d_in, const int* in_sizes, int n_in,
                              void* d_out, int out_size, void* d_ws, size_t ws_size,
                              hipStream_t stream)
{
    (void)in_sizes; (void)n_in; (void)out_size;
    const float* x    = (const float*)d_in[0];
    const float* pos0 = (const float*)d_in[1];
    const int*   bat  = (const int*)d_in[2];
    const int* e1 = (const int*)d_in[3];
    const int* e2 = (const int*)d_in[4];
    const int* e3 = (const int*)d_in[5];
    const int* e4 = (const int*)d_in[6];
    const int* e5 = (const int*)d_in[7];
    const float* W1 = (const float*)d_in[8],  *R1 = (const float*)d_in[9],  *B1 = (const float*)d_in[10];
    const float* W2 = (const float*)d_in[11], *R2 = (const float*)d_in[12], *B2 = (const float*)d_in[13];
    const float* W3 = (const float*)d_in[14], *R3 = (const float*)d_in[15], *B3 = (const float*)d_in[16];
    const float* W4 = (const float*)d_in[17], *R4 = (const float*)d_in[18], *B4 = (const float*)d_in[19];
    const float* W5 = (const float*)d_in[20], *R5 = (const float*)d_in[21], *B5 = (const float*)d_in[22];

    const int E1 = 3600000, E2 = 786432, E3 = 196608, E4 = 24576, E5 = 3072;

    if (ws_size < (size_t)21800000 * sizeof(float)) return;
    float* ws = (float*)d_ws;
    // pools (floats): P0 12.6M (z / big scratch) | P1 6.3M (layer out) | P2 1.6M (pooled h in)
    //                 P3 1.0M (CSR ints, L2-5)   | P4 0.3M (pos)
    float* P0 = ws;
    float* P1 = ws + 12600000;
    float* P2 = ws + 18900000;
    int*   P3 = (int*)(ws + 20500000);
    float* P4 = ws + 21500000;
    // scan scratch: last 256 ints of P3 pool (never overlaps CSR usage <= 983040 ints)
    int* SCR_BS = P3 + 999744;          // block sums (<= 74)
    int* SCR_BO = SCR_BS + 96;          // scanned block sums

    float* out3 = (float*)d_out;           // 1536*128
    float* hfin = (float*)d_out + 196608;  // 192*128

#define MSI(p, ni) hipMemsetAsync((p), 0, (size_t)(ni) * sizeof(int), stream)

    // hierarchical exclusive scan: cntp[0..Vn) -> offp[0..Vn)
#define SCAN(cntp, offp, Vn)                                                                     \
    {                                                                                            \
        int nb_ = ((Vn) + 4095) / 4096;                                                          \
        if (nb_ <= 1) {                                                                          \
            scan1_kernel<<<1, 256, 0, stream>>>((cntp), (offp), nullptr, (Vn));                  \
        } else {                                                                                 \
            scan1_kernel<<<nb_, 256, 0, stream>>>((cntp), (offp), SCR_BS, (Vn));                 \
            scan1_kernel<<<1, 256, 0, stream>>>(SCR_BS, SCR_BO, nullptr, nb_);                   \
            scan_add_kernel<<<((Vn) + 255) / 256, 256, 0, stream>>>((offp), SCR_BO, (Vn));       \
        }                                                                                        \
    }

    // Build dst-CSR: cnt/off/srcs at given int base. off[v] = segment END after scatter.
#define ESORT(base, ep, En, Vn)                                                                  \
    int* cnt_ = (base);                                                                          \
    int* off_ = cnt_ + (Vn);                                                                     \
    int* src_ = off_ + (Vn);                                                                     \
    MSI(cnt_, (Vn));                                                                             \
    edge_count_kernel<<<((En) + 255) / 256, 256, 0, stream>>>((ep) + (En), cnt_, En);            \
    SCAN(cnt_, off_, (Vn));                                                                      \
    edge_scatter_kernel<<<((En) + 255) / 256, 256, 0, stream>>>((ep), (ep) + (En), off_, src_, En)

    // Pool: scratch at float base SB: [SF Vn*COUT][Spos Vn*3][ICL Vn][IORD Vn][ICNT Vc][IOFF Vc]
#define POOL(SB, hsrc, possrc, batp, bdiv, Vn, NX, NY, NT, COUTV, DM, PADV, hdst, posdst)   \
    {                                                                                       \
        int Vc = 4 * (NX) * (NY) * (NT);                                                    \
        float* SF   = (SB);                                                                 \
        float* SPOS = SF + (size_t)(Vn) * (COUTV);                                          \
        int* ICL  = (int*)(SPOS + (size_t)(Vn) * 3);                                        \
        int* IORD = ICL + (Vn);                                                             \
        int* ICNT = IORD + (Vn);                                                            \
        int* IOFF = ICNT + Vc;                                                              \
        MSI(ICNT, Vc);                                                                      \
        pool_cluster_kernel<<<((Vn) + 255) / 256, 256, 0, stream>>>(                        \
            possrc, batp, bdiv, Vn, NX, NY, NT, ICL, ICNT);                                 \
        SCAN(ICNT, IOFF, Vc);                                                               \
        pool_scatter_kernel<<<((Vn) + 255) / 256, 256, 0, stream>>>(ICL, IOFF, IORD, Vn);   \
        pool_copy_kernel<COUTV><<<((size_t)(Vn) * (COUTV) + 255) / 256, 256, 0, stream>>>(  \
            IORD, hsrc, possrc, SF, SPOS, Vn);                                              \
        pool_reduce_kernel<COUTV, DM, PADV><<<((size_t)Vc * (COUTV) + 255) / 256, 256, 0,   \
            stream>>>(IOFF, ICNT, SF, SPOS, hdst, posdst, Vc);                              \
    }

    // ---------- Layer 1: 300000 nodes, CIN=3, COUT=16 (CSR gather, float4-packed) ----------
    {
        ESORT((int*)P0, e1, E1, 300000);            // ints [0 .. 4.2M) in P0
        float4* xp4 = (float4*)(P0 + 4200000);      // 1.2M floats [4.2M .. 5.4M)
        pack_xpos_kernel<<<(300000 + 255) / 256, 256, 0, stream>>>(x, pos0, xp4, 300000);
        l1_fused_kernel<<<(300000 * 16) / 256, 256, 0, stream>>>(
            off_, cnt_, src_, xp4, W1, R1, B1, P1, 20.0f, 300000);
        // CSR1 + xp4 dead -> pool scratch at P0. h1p (stride 16) -> P2, pos2 -> P4.
        POOL(P0, P1, pos0, bat, 0, 300000, 64, 48, 8, 16, 0, 0, P2, P4);
    }
    // ---------- Layer 2: 98304 nodes, CIN=18, COUT=64 — quarter-z path, zero atomics ------
    {
        ESORT(P3, e2, E2, 98304);                   // 983K ints in P3
        for (int q = 0; q < 4; ++q) {
            z_node_l2_kernel<<<(98304 * 128) / 256, 256, 0, stream>>>(P2, P4, W2, P0, 98304, q);
            z_edge_l2_kernel<<<(98304 * 16) / 256, 256, 0, stream>>>(
                off_, cnt_, src_, P4, P0, P2, R2, B2, P1, 10.0f, 98304, q);
        }
        // z dead -> pool scratch at P0. h2p (hcat stride 66) -> P2, pos3 -> P4.
        POOL(P0, P1, P4, nullptr, 24576, 98304, 32, 24, 4, 64, 0, 2, P2, P4);
    }
    // ---------- Layer 3: 12288 nodes, CIN=66, COUT=128 (full z path) ----------
    {
        z_node_kernel<66, 128, 8><<<(12288 / 8) * 1024 / 256, 256, 0, stream>>>(P2, W3, P0, 12288);
        ESORT(P3, e3, E3, 12288);
        z_fused_kernel<128><<<(12288 * 128) / 256, 256, 0, stream>>>(
            off_, cnt_, src_, P4, P0, P2, R3, B3, P1, 6.0f, 12288, 66);
        // z3 dead -> pool scratch at P0. h3p (stride 130) -> P2, pos4 -> P4.
        POOL(P0, P1, P4, nullptr, 3072, 12288, 16, 12, 2, 128, 0, 2, P2, P4);
    }
    // ---------- Layer 4: 1536 nodes, CIN=130, COUT=128 -> out3 ----------
    {
        z_node_kernel<130, 128, 8><<<(1536 / 8) * 1024 / 256, 256, 0, stream>>>(P2, W4, P0, 1536);
        ESORT(P3, e4, E4, 1536);
        z_fused_kernel<128><<<(1536 * 128) / 256, 256, 0, stream>>>(
            off_, cnt_, src_, P4, P0, P2, R4, B4, out3, 3.0f, 1536, 130);
        POOL(P0, out3, P4, nullptr, 384, 1536, 8, 6, 1, 128, 1, 2, P2, P4);
    }
    // ---------- Layer 5: 192 nodes, CIN=130, COUT=128 -> hfin ----------
    {
        z_node_kernel<130, 128, 8><<<(192 / 8) * 1024 / 256, 256, 0, stream>>>(P2, W5, P0, 192);
        ESORT(P3, e5, E5, 192);
        z_fused_kernel<128><<<(192 * 128) / 256, 256, 0, stream>>>(
            off_, cnt_, src_, P4, P0, P2, R5, B5, hfin, 1.5f, 192, 130);
    }
#undef POOL
#undef ESORT
#undef SCAN
#undef MSI
}

// Round 5
// 1992.702 us; speedup vs baseline: 1.4309x; 1.0829x over previous
//
#include <hip/hip_runtime.h>
#include <cstdint>

__device__ __forceinline__ float clamp01f(float v) { return fminf(fmaxf(v, 0.0f), 1.0f); }

// ======================= edge sort by dst (CSR build) =======================
__global__ __launch_bounds__(256) void edge_count_kernel(
    const int* __restrict__ edst, int* __restrict__ cnt, int E)
{
    int e = blockIdx.x * 256 + threadIdx.x;
    if (e < E) atomicAdd(&cnt[edst[e]], 1);
}

// XCD-range-partitioned scatter: block b handles dst-range (b&7) over edge chunk (b>>3).
// blockIdx%8 == XCD on MI355X round-robin, so each CSR region is written by ONE XCD's L2
// -> full-line write combining instead of 64B/edge partial-line write-through.
// Correct regardless of the actual block->XCD mapping (only speed depends on it).
__global__ __launch_bounds__(256) void edge_scatter_kernel(
    const int* __restrict__ esrc, const int* __restrict__ edst,
    int* __restrict__ off, int* __restrict__ srcs, int E, int rv)
{
    const int lo = (int)(blockIdx.x & 7) * rv;
    const int hi = lo + rv;
    const int base = (int)(blockIdx.x >> 3) << 10;
#pragma unroll
    for (int k = 0; k < 4; ++k) {
        int e = base + (k << 8) + threadIdx.x;
        if (e < E) {
            int d = edst[e];
            if (d >= lo && d < hi) {
                int slot = atomicAdd(&off[d], 1);
                srcs[slot] = esrc[e];
            }
        }
    }
}

// ============== hierarchical exclusive scan ==============
__global__ __launch_bounds__(256) void scan1_kernel(
    const int* __restrict__ cnt, int* __restrict__ off, int* __restrict__ bsum, int V)
{
    __shared__ int lds[4096];
    __shared__ int ssum[256];
    const int t = threadIdx.x;
    const int base = blockIdx.x * 4096;
    for (int i = t; i < 4096; i += 256) {
        int g = base + i;
        lds[i] = (g < V) ? cnt[g] : 0;
    }
    __syncthreads();
    int loc[16];
    int s = 0;
#pragma unroll
    for (int k = 0; k < 16; ++k) { loc[k] = s; s += lds[t * 16 + k]; }
    ssum[t] = s;
    __syncthreads();
    for (int d = 1; d < 256; d <<= 1) {
        int v = (t >= d) ? ssum[t - d] : 0;
        __syncthreads();
        ssum[t] += v;
        __syncthreads();
    }
    const int tbase = (t == 0) ? 0 : ssum[t - 1];
    if (t == 255 && bsum) bsum[blockIdx.x] = ssum[255];
#pragma unroll
    for (int k = 0; k < 16; ++k) lds[t * 16 + k] = tbase + loc[k];
    __syncthreads();
    for (int i = t; i < 4096; i += 256) {
        int g = base + i;
        if (g < V) off[g] = lds[i];
    }
}

__global__ __launch_bounds__(256) void scan_add_kernel(
    int* __restrict__ off, const int* __restrict__ bso, int V)
{
    int g = blockIdx.x * 256 + threadIdx.x;
    if (g < V) off[g] += bso[g >> 12];
}

// ======================= pack (x, pos) into float4 for layer-1 gathers =======
__global__ __launch_bounds__(256) void pack_xpos_kernel(
    const float* __restrict__ x, const float* __restrict__ pos,
    float4* __restrict__ xp, int V)
{
    int n = blockIdx.x * 256 + threadIdx.x;
    if (n >= V) return;
    xp[n] = make_float4(x[n], pos[n * 3 + 0], pos[n * 3 + 1], pos[n * 3 + 2]);
}

// ======================= Layer-1 fused gather-reduce (CIN=3 -> COUT=16) =======
__global__ __launch_bounds__(256) void l1_fused_kernel(
    const int* __restrict__ off, const int* __restrict__ cnt, const int* __restrict__ srcs,
    const float4* __restrict__ xp,
    const float* __restrict__ Wk, const float* __restrict__ Wr,
    const float* __restrict__ bias, float* __restrict__ out,
    float inv2mv, int V)
{
    int g = blockIdx.x * 256 + threadIdx.x;
    if (g >= V * 16) return;
    const int v = g >> 4, c = g & 15;
    float w[8][3];
#pragma unroll
    for (int s8 = 0; s8 < 8; ++s8)
#pragma unroll
        for (int ci = 0; ci < 3; ++ci)
            w[s8][ci] = Wk[s8 * 48 + ci * 16 + c];
    const float4 d = xp[v];  // x, px, py, pt
    const int e1 = off[v];
    const int n = cnt[v];
    float acc = 0.f;
    int j = e1 - n;
    for (; j + 1 < e1; j += 2) {
        int sa = srcs[j], sb = srcs[j + 1];
        float4 a = xp[sa];
        float4 b = xp[sb];
        {
            float p0 = clamp01f((d.y - a.y) * inv2mv + 0.5f);
            float p1 = clamp01f((d.z - a.z) * inv2mv + 0.5f);
            float p2 = clamp01f((d.w - a.w) * inv2mv + 0.5f);
            float q0 = 1.f - p0, q1 = 1.f - p1, q2 = 1.f - p2;
#pragma unroll
            for (int s8 = 0; s8 < 8; ++s8) {
                float bs = ((s8 & 1) ? p0 : q0) * ((s8 & 2) ? p1 : q1) * ((s8 & 4) ? p2 : q2);
                acc += bs * (a.x * w[s8][0] + a.y * w[s8][1] + a.z * w[s8][2]);
            }
        }
        {
            float p0 = clamp01f((d.y - b.y) * inv2mv + 0.5f);
            float p1 = clamp01f((d.z - b.z) * inv2mv + 0.5f);
            float p2 = clamp01f((d.w - b.w) * inv2mv + 0.5f);
            float q0 = 1.f - p0, q1 = 1.f - p1, q2 = 1.f - p2;
#pragma unroll
            for (int s8 = 0; s8 < 8; ++s8) {
                float bs = ((s8 & 1) ? p0 : q0) * ((s8 & 2) ? p1 : q1) * ((s8 & 4) ? p2 : q2);
                acc += bs * (b.x * w[s8][0] + b.y * w[s8][1] + b.z * w[s8][2]);
            }
        }
    }
    if (j < e1) {
        float4 a = xp[srcs[j]];
        float p0 = clamp01f((d.y - a.y) * inv2mv + 0.5f);
        float p1 = clamp01f((d.z - a.z) * inv2mv + 0.5f);
        float p2 = clamp01f((d.w - a.w) * inv2mv + 0.5f);
        float q0 = 1.f - p0, q1 = 1.f - p1, q2 = 1.f - p2;
#pragma unroll
        for (int s8 = 0; s8 < 8; ++s8) {
            float bs = ((s8 & 1) ? p0 : q0) * ((s8 & 2) ? p1 : q1) * ((s8 & 4) ? p2 : q2);
            acc += bs * (a.x * w[s8][0] + a.y * w[s8][1] + a.z * w[s8][2]);
        }
    }
    float r = acc / fmaxf((float)n, 1.0f)
            + d.x * Wr[c] + d.y * Wr[16 + c] + d.z * Wr[32 + c] + bias[c];
    out[g] = fmaxf(r, 0.0f);
}

// ======================= Layer-2 z quarter: z[v][s8][c16] = hcat[v] @ Wk[s8][:, q*16+c] ===
__global__ __launch_bounds__(256) void z_node_l2_kernel(
    const float* __restrict__ h16, const float* __restrict__ pos,
    const float* __restrict__ Wk, float* __restrict__ z, int V, int q)
{
    int g = blockIdx.x * 256 + threadIdx.x;
    if (g >= V * 128) return;
    int c = g & 15;
    int s8 = (g >> 4) & 7;
    int v = g >> 7;
    const float* w = Wk + s8 * (18 * 64) + q * 16 + c;
    const float* hv = h16 + (size_t)v * 16;
    float acc = 0.f;
#pragma unroll
    for (int ci = 0; ci < 16; ++ci)
        acc += hv[ci] * w[ci * 64];
    acc += pos[v * 3 + 0] * w[16 * 64] + pos[v * 3 + 1] * w[17 * 64];
    z[(size_t)v * 128 + s8 * 16 + c] = acc;
}

// ======================= Layer-2 fused gather-reduce + epilogue (quarter) =======
__global__ __launch_bounds__(256) void z_edge_l2_kernel(
    const int* __restrict__ off, const int* __restrict__ cnt, const int* __restrict__ srcs,
    const float* __restrict__ pos, const float* __restrict__ z,
    const float* __restrict__ h16, const float* __restrict__ Wr,
    const float* __restrict__ bias, float* __restrict__ out,
    float inv2mv, int V, int q)
{
    int g = blockIdx.x * 256 + threadIdx.x;
    if (g >= V * 16) return;
    const int v = g >> 4, c = g & 15;
    const int qc = q * 16 + c;
    const float pdx = pos[v * 3 + 0], pdy = pos[v * 3 + 1], pdt = pos[v * 3 + 2];
    float rb = bias[qc];
    const float* hv = h16 + (size_t)v * 16;
#pragma unroll
    for (int ci = 0; ci < 16; ++ci)
        rb += hv[ci] * Wr[ci * 64 + qc];
    rb += pdx * Wr[16 * 64 + qc] + pdy * Wr[17 * 64 + qc];
    const int e1 = off[v];
    const int n = cnt[v];
    float acc = 0.f;
    for (int j = e1 - n; j < e1; ++j) {
        int s = srcs[j];
        float p0 = clamp01f((pdx - pos[s * 3 + 0]) * inv2mv + 0.5f);
        float p1 = clamp01f((pdy - pos[s * 3 + 1]) * inv2mv + 0.5f);
        float p2 = clamp01f((pdt - pos[s * 3 + 2]) * inv2mv + 0.5f);
        float q0 = 1.f - p0, q1 = 1.f - p1, q2 = 1.f - p2;
        const float* zp = z + (size_t)s * 128 + c;
        acc += q0 * q1 * q2 * zp[0]  + p0 * q1 * q2 * zp[16]
             + q0 * p1 * q2 * zp[32] + p0 * p1 * q2 * zp[48]
             + q0 * q1 * p2 * zp[64] + p0 * q1 * p2 * zp[80]
             + q0 * p1 * p2 * zp[96] + p0 * p1 * p2 * zp[112];
    }
    out[(size_t)v * 64 + qc] = fmaxf(rb + acc / fmaxf((float)n, 1.0f), 0.0f);
}

// ======================= z precompute (layers 3-5): z[v, s, c] = hcat[v] @ Wk[s] =======
template<int CIN, int COUT, int TV>
__global__ __launch_bounds__(256) void z_node_kernel(
    const float* __restrict__ hcat, const float* __restrict__ Wk,
    float* __restrict__ z, int V)
{
    int g = blockIdx.x * 256 + threadIdx.x;
    int c = g % COUT;
    int s8 = (g / COUT) & 7;
    int vb = g / (COUT * 8);
    int v0 = vb * TV;
    if (v0 >= V) return;
    const float* w = Wk + s8 * CIN * COUT + c;
    float acc[TV];
#pragma unroll
    for (int t = 0; t < TV; ++t) acc[t] = 0.f;
    for (int ci = 0; ci < CIN; ++ci) {
        float wv = w[ci * COUT];
#pragma unroll
        for (int t = 0; t < TV; ++t)
            acc[t] += hcat[(v0 + t) * CIN + ci] * wv;
    }
#pragma unroll
    for (int t = 0; t < TV; ++t)
        z[(size_t)(v0 + t) * (8 * COUT) + s8 * COUT + c] = acc[t];
}

// ======================= z-based fused gather-reduce + epilogue (layers 3-5) =======
template<int COUT>
__global__ __launch_bounds__(256) void z_fused_kernel(
    const int* __restrict__ off, const int* __restrict__ cnt, const int* __restrict__ srcs,
    const float* __restrict__ pos, const float* __restrict__ z,
    const float* __restrict__ hcat, const float* __restrict__ Wr,
    const float* __restrict__ bias, float* __restrict__ out,
    float inv2mv, int V, int CIN)
{
    int g = blockIdx.x * 256 + threadIdx.x;
    if (g >= V * COUT) return;
    const int v = g / COUT, c = g % COUT;
    const float pdx = pos[v * 3 + 0], pdy = pos[v * 3 + 1], pdt = pos[v * 3 + 2];
    const int e1 = off[v];
    const int n = cnt[v];
    float acc = 0.f;
    for (int j = e1 - n; j < e1; ++j) {
        int s = srcs[j];
        float p0 = clamp01f((pdx - pos[s * 3 + 0]) * inv2mv + 0.5f);
        float p1 = clamp01f((pdy - pos[s * 3 + 1]) * inv2mv + 0.5f);
        float p2 = clamp01f((pdt - pos[s * 3 + 2]) * inv2mv + 0.5f);
        float q0 = 1.f - p0, q1 = 1.f - p1, q2 = 1.f - p2;
        const float* zp = z + (size_t)s * (8 * COUT) + c;
        float z0 = zp[0],        z1 = zp[COUT],     z2 = zp[2 * COUT], z3 = zp[3 * COUT];
        float z4 = zp[4 * COUT], z5 = zp[5 * COUT], z6 = zp[6 * COUT], z7 = zp[7 * COUT];
        acc += q0 * q1 * q2 * z0 + p0 * q1 * q2 * z1
             + q0 * p1 * q2 * z2 + p0 * p1 * q2 * z3
             + q0 * q1 * p2 * z4 + p0 * q1 * p2 * z5
             + q0 * p1 * p2 * z6 + p0 * p1 * p2 * z7;
    }
    float r = bias[c];
    const float* hv = hcat + (size_t)v * CIN;
    for (int ci = 0; ci < CIN; ++ci)
        r += hv[ci] * Wr[ci * COUT + c];
    r += acc / fmaxf((float)n, 1.0f);
    out[g] = fmaxf(r, 0.0f);
}

// ======================= voxel pooling: counting-sort + copy + sequential reduce =====
__global__ __launch_bounds__(256) void pool_cluster_kernel(
    const float* __restrict__ pos, const int* __restrict__ batch, int bdiv, int V,
    int nx, int ny, int nt, int* __restrict__ cl, int* __restrict__ cnt)
{
    int n = blockIdx.x * 256 + threadIdx.x;
    if (n >= V) return;
    int b = batch ? batch[n] : (n / bdiv);
    float px = pos[n * 3 + 0], py = pos[n * 3 + 1], pt = pos[n * 3 + 2];
    int ix = (int)floorf(px * (float)nx); ix = min(max(ix, 0), nx - 1);
    int iy = (int)floorf(py * (float)ny); iy = min(max(iy, 0), ny - 1);
    int it = (int)floorf(pt * (float)nt); it = min(max(it, 0), nt - 1);
    int c = ((b * nx + ix) * ny + iy) * nt + it;
    cl[n] = c;
    atomicAdd(&cnt[c], 1);
}

__global__ __launch_bounds__(256) void pool_scatter_kernel(
    const int* __restrict__ cl, int* __restrict__ off, int* __restrict__ order, int V)
{
    int n = blockIdx.x * 256 + threadIdx.x;
    if (n >= V) return;
    int slot = atomicAdd(&off[cl[n]], 1);
    order[slot] = n;
}

template<int COUT>
__global__ __launch_bounds__(256) void pool_copy_kernel(
    const int* __restrict__ order, const float* __restrict__ h,
    const float* __restrict__ pos,
    float* __restrict__ S, float* __restrict__ Spos, int V)
{
    int g = blockIdx.x * 256 + threadIdx.x;
    if (g >= V * COUT) return;
    int slot = g / COUT;
    int c = g % COUT;
    int n = order[slot];
    S[g] = h[(size_t)n * COUT + c];
    if (c < 3) Spos[slot * 3 + c] = pos[n * 3 + c];
}

// PAD=2: append pooled pos.xy after COUT channels (hcat layout); PAD=0: plain h.
template<int COUT, int DOMEAN, int PAD>
__global__ __launch_bounds__(256) void pool_reduce_kernel(
    const int* __restrict__ off, const int* __restrict__ cnt,
    const float* __restrict__ S, const float* __restrict__ Spos,
    float* __restrict__ hnext, float* __restrict__ pos_out, int Vc)
{
    const int g = blockIdx.x * 256 + threadIdx.x;
    if (g >= Vc * COUT) return;
    const int v = g / COUT;
    const int c = g % COUT;
    const int e1 = off[v];
    const int n0 = e1 - cnt[v];
    float acc = 0.0f;
    float ps = 0.0f;
    int j = n0;
    for (; j + 3 < e1; j += 4) {
        float a0 = S[(size_t)(j + 0) * COUT + c];
        float a1 = S[(size_t)(j + 1) * COUT + c];
        float a2 = S[(size_t)(j + 2) * COUT + c];
        float a3 = S[(size_t)(j + 3) * COUT + c];
        if (DOMEAN) acc += (a0 + a1) + (a2 + a3);
        else        acc = fmaxf(acc, fmaxf(fmaxf(a0, a1), fmaxf(a2, a3)));
        if (c < 3) {
            float p0 = Spos[(j + 0) * 3 + c];
            float p1 = Spos[(j + 1) * 3 + c];
            float p2 = Spos[(j + 2) * 3 + c];
            float p3 = Spos[(j + 3) * 3 + c];
            ps += (p0 + p1) + (p2 + p3);
        }
    }
    for (; j < e1; ++j) {
        float a0 = S[(size_t)j * COUT + c];
        acc = DOMEAN ? (acc + a0) : fmaxf(acc, a0);
        if (c < 3) ps += Spos[j * 3 + c];
    }
    float m = fmaxf((float)cnt[v], 1.0f);
    float* hp = hnext + (size_t)v * (COUT + PAD);
    hp[c] = DOMEAN ? (acc / m) : acc;
    if (c < 3) {
        float pm = ps / m;
        pos_out[v * 3 + c] = pm;
        if (PAD >= 2 && c < 2) hp[COUT + c] = pm;
    }
}

// ======================= host =======================
extern "C" void kernel_launch(void* const* d_in, const int* in_sizes, int n_in,
                              void* d_out, int out_size, void* d_ws, size_t ws_size,
                              hipStream_t stream)
{
    (void)in_sizes; (void)n_in; (void)out_size;
    const float* x    = (const float*)d_in[0];
    const float* pos0 = (const float*)d_in[1];
    const int*   bat  = (const int*)d_in[2];
    const int* e1 = (const int*)d_in[3];
    const int* e2 = (const int*)d_in[4];
    const int* e3 = (const int*)d_in[5];
    const int* e4 = (const int*)d_in[6];
    const int* e5 = (const int*)d_in[7];
    const float* W1 = (const float*)d_in[8],  *R1 = (const float*)d_in[9],  *B1 = (const float*)d_in[10];
    const float* W2 = (const float*)d_in[11], *R2 = (const float*)d_in[12], *B2 = (const float*)d_in[13];
    const float* W3 = (const float*)d_in[14], *R3 = (const float*)d_in[15], *B3 = (const float*)d_in[16];
    const float* W4 = (const float*)d_in[17], *R4 = (const float*)d_in[18], *B4 = (const float*)d_in[19];
    const float* W5 = (const float*)d_in[20], *R5 = (const float*)d_in[21], *B5 = (const float*)d_in[22];

    const int E1 = 3600000, E2 = 786432, E3 = 196608, E4 = 24576, E5 = 3072;

    if (ws_size < (size_t)21800000 * sizeof(float)) return;
    float* ws = (float*)d_ws;
    // pools (floats): P0 12.6M (z / big scratch) | P1 6.3M (layer out) | P2 1.6M (pooled h in)
    //                 P3 1.0M (CSR ints, L2-5)   | P4 0.3M (pos)
    float* P0 = ws;
    float* P1 = ws + 12600000;
    float* P2 = ws + 18900000;
    int*   P3 = (int*)(ws + 20500000);
    float* P4 = ws + 21500000;
    // scan scratch: last 256 ints of P3 pool (never overlaps CSR usage <= 983040 ints)
    int* SCR_BS = P3 + 999744;          // block sums (<= 74)
    int* SCR_BO = SCR_BS + 96;          // scanned block sums

    float* out3 = (float*)d_out;           // 1536*128
    float* hfin = (float*)d_out + 196608;  // 192*128

#define MSI(p, ni) hipMemsetAsync((p), 0, (size_t)(ni) * sizeof(int), stream)

    // hierarchical exclusive scan: cntp[0..Vn) -> offp[0..Vn)
#define SCAN(cntp, offp, Vn)                                                                     \
    {                                                                                            \
        int nb_ = ((Vn) + 4095) / 4096;                                                          \
        if (nb_ <= 1) {                                                                          \
            scan1_kernel<<<1, 256, 0, stream>>>((cntp), (offp), nullptr, (Vn));                  \
        } else {                                                                                 \
            scan1_kernel<<<nb_, 256, 0, stream>>>((cntp), (offp), SCR_BS, (Vn));                 \
            scan1_kernel<<<1, 256, 0, stream>>>(SCR_BS, SCR_BO, nullptr, nb_);                   \
            scan_add_kernel<<<((Vn) + 255) / 256, 256, 0, stream>>>((offp), SCR_BO, (Vn));       \
        }                                                                                        \
    }

    // Build dst-CSR: cnt/off/srcs at given int base. off[v] = segment END after scatter.
    // Scatter is XCD-range-partitioned (8 ranges of Vn/8 dsts each).
#define ESORT(base, ep, En, Vn)                                                                  \
    int* cnt_ = (base);                                                                          \
    int* off_ = cnt_ + (Vn);                                                                     \
    int* src_ = off_ + (Vn);                                                                     \
    MSI(cnt_, (Vn));                                                                             \
    edge_count_kernel<<<((En) + 255) / 256, 256, 0, stream>>>((ep) + (En), cnt_, En);            \
    SCAN(cnt_, off_, (Vn));                                                                      \
    edge_scatter_kernel<<<8 * (((En) + 1023) / 1024), 256, 0, stream>>>(                         \
        (ep), (ep) + (En), off_, src_, En, (Vn) >> 3)

    // Pool: scratch at float base SB: [SF Vn*COUT][Spos Vn*3][ICL Vn][IORD Vn][ICNT Vc][IOFF Vc]
#define POOL(SB, hsrc, possrc, batp, bdiv, Vn, NX, NY, NT, COUTV, DM, PADV, hdst, posdst)   \
    {                                                                                       \
        int Vc = 4 * (NX) * (NY) * (NT);                                                    \
        float* SF   = (SB);                                                                 \
        float* SPOS = SF + (size_t)(Vn) * (COUTV);                                          \
        int* ICL  = (int*)(SPOS + (size_t)(Vn) * 3);                                        \
        int* IORD = ICL + (Vn);                                                             \
        int* ICNT = IORD + (Vn);                                                            \
        int* IOFF = ICNT + Vc;                                                              \
        MSI(ICNT, Vc);                                                                      \
        pool_cluster_kernel<<<((Vn) + 255) / 256, 256, 0, stream>>>(                        \
            possrc, batp, bdiv, Vn, NX, NY, NT, ICL, ICNT);                                 \
        SCAN(ICNT, IOFF, Vc);                                                               \
        pool_scatter_kernel<<<((Vn) + 255) / 256, 256, 0, stream>>>(ICL, IOFF, IORD, Vn);   \
        pool_copy_kernel<COUTV><<<((size_t)(Vn) * (COUTV) + 255) / 256, 256, 0, stream>>>(  \
            IORD, hsrc, possrc, SF, SPOS, Vn);                                              \
        pool_reduce_kernel<COUTV, DM, PADV><<<((size_t)Vc * (COUTV) + 255) / 256, 256, 0,   \
            stream>>>(IOFF, ICNT, SF, SPOS, hdst, posdst, Vc);                              \
    }

    // ---------- Layer 1: 300000 nodes, CIN=3, COUT=16 (CSR gather, float4-packed) ----------
    {
        ESORT((int*)P0, e1, E1, 300000);            // ints [0 .. 4.2M) in P0
        float4* xp4 = (float4*)(P0 + 4200000);      // 1.2M floats [4.2M .. 5.4M)
        pack_xpos_kernel<<<(300000 + 255) / 256, 256, 0, stream>>>(x, pos0, xp4, 300000);
        l1_fused_kernel<<<(300000 * 16) / 256, 256, 0, stream>>>(
            off_, cnt_, src_, xp4, W1, R1, B1, P1, 20.0f, 300000);
        // CSR1 + xp4 dead -> pool scratch at P0. h1p (stride 16) -> P2, pos2 -> P4.
        POOL(P0, P1, pos0, bat, 0, 300000, 64, 48, 8, 16, 0, 0, P2, P4);
    }
    // ---------- Layer 2: 98304 nodes, CIN=18, COUT=64 — quarter-z path, zero atomics ------
    {
        ESORT(P3, e2, E2, 98304);                   // 983K ints in P3
        for (int q = 0; q < 4; ++q) {
            z_node_l2_kernel<<<(98304 * 128) / 256, 256, 0, stream>>>(P2, P4, W2, P0, 98304, q);
            z_edge_l2_kernel<<<(98304 * 16) / 256, 256, 0, stream>>>(
                off_, cnt_, src_, P4, P0, P2, R2, B2, P1, 10.0f, 98304, q);
        }
        // z dead -> pool scratch at P0. h2p (hcat stride 66) -> P2, pos3 -> P4.
        POOL(P0, P1, P4, nullptr, 24576, 98304, 32, 24, 4, 64, 0, 2, P2, P4);
    }
    // ---------- Layer 3: 12288 nodes, CIN=66, COUT=128 (full z path) ----------
    {
        z_node_kernel<66, 128, 8><<<(12288 / 8) * 1024 / 256, 256, 0, stream>>>(P2, W3, P0, 12288);
        ESORT(P3, e3, E3, 12288);
        z_fused_kernel<128><<<(12288 * 128) / 256, 256, 0, stream>>>(
            off_, cnt_, src_, P4, P0, P2, R3, B3, P1, 6.0f, 12288, 66);
        // z3 dead -> pool scratch at P0. h3p (stride 130) -> P2, pos4 -> P4.
        POOL(P0, P1, P4, nullptr, 3072, 12288, 16, 12, 2, 128, 0, 2, P2, P4);
    }
    // ---------- Layer 4: 1536 nodes, CIN=130, COUT=128 -> out3 ----------
    {
        z_node_kernel<130, 128, 8><<<(1536 / 8) * 1024 / 256, 256, 0, stream>>>(P2, W4, P0, 1536);
        ESORT(P3, e4, E4, 1536);
        z_fused_kernel<128><<<(1536 * 128) / 256, 256, 0, stream>>>(
            off_, cnt_, src_, P4, P0, P2, R4, B4, out3, 3.0f, 1536, 130);
        POOL(P0, out3, P4, nullptr, 384, 1536, 8, 6, 1, 128, 1, 2, P2, P4);
    }
    // ---------- Layer 5: 192 nodes, CIN=130, COUT=128 -> hfin ----------
    {
        z_node_kernel<130, 128, 8><<<(192 / 8) * 1024 / 256, 256, 0, stream>>>(P2, W5, P0, 192);
        ESORT(P3, e5, E5, 192);
        z_fused_kernel<128><<<(192 * 128) / 256, 256, 0, stream>>>(
            off_, cnt_, src_, P4, P0, P2, R5, B5, hfin, 1.5f, 192, 130);
    }
#undef POOL
#undef ESORT
#undef SCAN
#undef MSI
}

// Round 6
// 1910.823 us; speedup vs baseline: 1.4922x; 1.0429x over previous
//
#include <hip/hip_runtime.h>
#include <cstdint>

__device__ __forceinline__ float clamp01f(float v) { return fminf(fmaxf(v, 0.0f), 1.0f); }

// ======================= edge sort by dst (CSR build) =======================
__global__ __launch_bounds__(256) void edge_count_kernel(
    const int* __restrict__ edst, int* __restrict__ cnt, int E)
{
    int e = blockIdx.x * 256 + threadIdx.x;
    if (e < E) atomicAdd(&cnt[__builtin_nontemporal_load(&edst[e])], 1);
}

// XCD-range-partitioned scatter. Edge streams use NON-TEMPORAL loads so the
// 28.8MB/XCD stream does not thrash the 4MB L2 -> srcs lines (1.8MB/XCD span)
// persist and partial-line writes combine into full 64B lines.
__global__ __launch_bounds__(256) void edge_scatter_kernel(
    const int* __restrict__ esrc, const int* __restrict__ edst,
    int* __restrict__ off, int* __restrict__ srcs, int E, int rv)
{
    const int lo = (int)(blockIdx.x & 7) * rv;
    const int hi = lo + rv;
    const int base = (int)(blockIdx.x >> 3) << 10;
#pragma unroll
    for (int k = 0; k < 4; ++k) {
        int e = base + (k << 8) + threadIdx.x;
        if (e < E) {
            int d = __builtin_nontemporal_load(&edst[e]);
            if (d >= lo && d < hi) {
                int s = __builtin_nontemporal_load(&esrc[e]);
                int slot = atomicAdd(&off[d], 1);
                srcs[slot] = s;
            }
        }
    }
}

// ============== hierarchical exclusive scan ==============
__global__ __launch_bounds__(256) void scan1_kernel(
    const int* __restrict__ cnt, int* __restrict__ off, int* __restrict__ bsum, int V)
{
    __shared__ int lds[4096];
    __shared__ int ssum[256];
    const int t = threadIdx.x;
    const int base = blockIdx.x * 4096;
    for (int i = t; i < 4096; i += 256) {
        int g = base + i;
        lds[i] = (g < V) ? cnt[g] : 0;
    }
    __syncthreads();
    int loc[16];
    int s = 0;
#pragma unroll
    for (int k = 0; k < 16; ++k) { loc[k] = s; s += lds[t * 16 + k]; }
    ssum[t] = s;
    __syncthreads();
    for (int d = 1; d < 256; d <<= 1) {
        int v = (t >= d) ? ssum[t - d] : 0;
        __syncthreads();
        ssum[t] += v;
        __syncthreads();
    }
    const int tbase = (t == 0) ? 0 : ssum[t - 1];
    if (t == 255 && bsum) bsum[blockIdx.x] = ssum[255];
#pragma unroll
    for (int k = 0; k < 16; ++k) lds[t * 16 + k] = tbase + loc[k];
    __syncthreads();
    for (int i = t; i < 4096; i += 256) {
        int g = base + i;
        if (g < V) off[g] = lds[i];
    }
}

__global__ __launch_bounds__(256) void scan_add_kernel(
    int* __restrict__ off, const int* __restrict__ bso, int V)
{
    int g = blockIdx.x * 256 + threadIdx.x;
    if (g < V) off[g] += bso[g >> 12];
}

// ======================= pack (x, pos) into float4 for layer-1 gathers =======
__global__ __launch_bounds__(256) void pack_xpos_kernel(
    const float* __restrict__ x, const float* __restrict__ pos,
    float4* __restrict__ xp, int V)
{
    int n = blockIdx.x * 256 + threadIdx.x;
    if (n >= V) return;
    xp[n] = make_float4(x[n], pos[n * 3 + 0], pos[n * 3 + 1], pos[n * 3 + 2]);
}

// ======================= Layer-1 fused gather-reduce (CIN=3 -> COUT=16) =======
__global__ __launch_bounds__(256) void l1_fused_kernel(
    const int* __restrict__ off, const int* __restrict__ cnt, const int* __restrict__ srcs,
    const float4* __restrict__ xp,
    const float* __restrict__ Wk, const float* __restrict__ Wr,
    const float* __restrict__ bias, float* __restrict__ out,
    float inv2mv, int V)
{
    int g = blockIdx.x * 256 + threadIdx.x;
    if (g >= V * 16) return;
    const int v = g >> 4, c = g & 15;
    float w[8][3];
#pragma unroll
    for (int s8 = 0; s8 < 8; ++s8)
#pragma unroll
        for (int ci = 0; ci < 3; ++ci)
            w[s8][ci] = Wk[s8 * 48 + ci * 16 + c];
    const float4 d = xp[v];  // x, px, py, pt
    const int e1 = off[v];
    const int n = cnt[v];
    float acc = 0.f;
    int j = e1 - n;
    for (; j + 1 < e1; j += 2) {
        int sa = srcs[j], sb = srcs[j + 1];
        float4 a = xp[sa];
        float4 b = xp[sb];
        {
            float p0 = clamp01f((d.y - a.y) * inv2mv + 0.5f);
            float p1 = clamp01f((d.z - a.z) * inv2mv + 0.5f);
            float p2 = clamp01f((d.w - a.w) * inv2mv + 0.5f);
            float q0 = 1.f - p0, q1 = 1.f - p1, q2 = 1.f - p2;
#pragma unroll
            for (int s8 = 0; s8 < 8; ++s8) {
                float bs = ((s8 & 1) ? p0 : q0) * ((s8 & 2) ? p1 : q1) * ((s8 & 4) ? p2 : q2);
                acc += bs * (a.x * w[s8][0] + a.y * w[s8][1] + a.z * w[s8][2]);
            }
        }
        {
            float p0 = clamp01f((d.y - b.y) * inv2mv + 0.5f);
            float p1 = clamp01f((d.z - b.z) * inv2mv + 0.5f);
            float p2 = clamp01f((d.w - b.w) * inv2mv + 0.5f);
            float q0 = 1.f - p0, q1 = 1.f - p1, q2 = 1.f - p2;
#pragma unroll
            for (int s8 = 0; s8 < 8; ++s8) {
                float bs = ((s8 & 1) ? p0 : q0) * ((s8 & 2) ? p1 : q1) * ((s8 & 4) ? p2 : q2);
                acc += bs * (b.x * w[s8][0] + b.y * w[s8][1] + b.z * w[s8][2]);
            }
        }
    }
    if (j < e1) {
        float4 a = xp[srcs[j]];
        float p0 = clamp01f((d.y - a.y) * inv2mv + 0.5f);
        float p1 = clamp01f((d.z - a.z) * inv2mv + 0.5f);
        float p2 = clamp01f((d.w - a.w) * inv2mv + 0.5f);
        float q0 = 1.f - p0, q1 = 1.f - p1, q2 = 1.f - p2;
#pragma unroll
        for (int s8 = 0; s8 < 8; ++s8) {
            float bs = ((s8 & 1) ? p0 : q0) * ((s8 & 2) ? p1 : q1) * ((s8 & 4) ? p2 : q2);
            acc += bs * (a.x * w[s8][0] + a.y * w[s8][1] + a.z * w[s8][2]);
        }
    }
    float r = acc / fmaxf((float)n, 1.0f)
            + d.x * Wr[c] + d.y * Wr[16 + c] + d.z * Wr[32 + c] + bias[c];
    out[g] = fmaxf(r, 0.0f);
}

// ======= Layer-2 z quarter, TRANSPOSED layout: z[v][cq][s8], 32B/thread writes =======
__global__ __launch_bounds__(256) void z_node_l2_kernel(
    const float* __restrict__ h16, const float* __restrict__ pos,
    const float* __restrict__ Wk, float* __restrict__ z, int V, int q)
{
    int g = blockIdx.x * 256 + threadIdx.x;
    if (g >= V * 16) return;
    const int cq = g & 15;
    const int v = g >> 4;
    const int qc = q * 16 + cq;
    float acc[8];
#pragma unroll
    for (int s8 = 0; s8 < 8; ++s8) acc[s8] = 0.f;
    const float* hv = h16 + (size_t)v * 16;
#pragma unroll
    for (int ci = 0; ci < 16; ++ci) {
        float h = hv[ci];
#pragma unroll
        for (int s8 = 0; s8 < 8; ++s8)
            acc[s8] += h * Wk[s8 * 1152 + ci * 64 + qc];
    }
    const float px = pos[v * 3 + 0], py = pos[v * 3 + 1];
#pragma unroll
    for (int s8 = 0; s8 < 8; ++s8)
        acc[s8] += px * Wk[s8 * 1152 + 16 * 64 + qc] + py * Wk[s8 * 1152 + 17 * 64 + qc];
    float4* zp = (float4*)(z + (size_t)v * 128 + cq * 8);
    zp[0] = make_float4(acc[0], acc[1], acc[2], acc[3]);
    zp[1] = make_float4(acc[4], acc[5], acc[6], acc[7]);
}

// ======= Layer-2 fused gather-reduce (quarter): 2x float4 contiguous z reads =======
__global__ __launch_bounds__(256) void z_edge_l2_kernel(
    const int* __restrict__ off, const int* __restrict__ cnt, const int* __restrict__ srcs,
    const float* __restrict__ pos, const float* __restrict__ z,
    const float* __restrict__ h16, const float* __restrict__ Wr,
    const float* __restrict__ bias, float* __restrict__ out,
    float inv2mv, int V, int q)
{
    int g = blockIdx.x * 256 + threadIdx.x;
    if (g >= V * 16) return;
    const int v = g >> 4, c = g & 15;
    const int qc = q * 16 + c;
    const float pdx = pos[v * 3 + 0], pdy = pos[v * 3 + 1], pdt = pos[v * 3 + 2];
    float rb = bias[qc];
    const float* hv = h16 + (size_t)v * 16;
#pragma unroll
    for (int ci = 0; ci < 16; ++ci)
        rb += hv[ci] * Wr[ci * 64 + qc];
    rb += pdx * Wr[16 * 64 + qc] + pdy * Wr[17 * 64 + qc];
    const int e1 = off[v];
    const int n = cnt[v];
    float acc = 0.f;
    for (int j = e1 - n; j < e1; ++j) {
        int s = srcs[j];
        float p0 = clamp01f((pdx - pos[s * 3 + 0]) * inv2mv + 0.5f);
        float p1 = clamp01f((pdy - pos[s * 3 + 1]) * inv2mv + 0.5f);
        float p2 = clamp01f((pdt - pos[s * 3 + 2]) * inv2mv + 0.5f);
        float q0 = 1.f - p0, q1 = 1.f - p1, q2 = 1.f - p2;
        const float4* zp = (const float4*)(z + (size_t)s * 128 + c * 8);
        float4 za = zp[0], zb = zp[1];
        acc += q0 * q1 * q2 * za.x + p0 * q1 * q2 * za.y
             + q0 * p1 * q2 * za.z + p0 * p1 * q2 * za.w
             + q0 * q1 * p2 * zb.x + p0 * q1 * p2 * zb.y
             + q0 * p1 * p2 * zb.z + p0 * p1 * p2 * zb.w;
    }
    out[(size_t)v * 64 + qc] = fmaxf(rb + acc / fmaxf((float)n, 1.0f), 0.0f);
}

// ==== z precompute (L3-5), TRANSPOSED layout z[v][c][s8]; 32B/thread writes ====
template<int CIN, int COUT>
__global__ __launch_bounds__(256) void z_node_kernel(
    const float* __restrict__ hcat, const float* __restrict__ Wk,
    float* __restrict__ z, int V)
{
    int g = blockIdx.x * 256 + threadIdx.x;
    if (g >= V * COUT) return;
    const int c = g % COUT;
    const int v = g / COUT;
    float acc[8];
#pragma unroll
    for (int s8 = 0; s8 < 8; ++s8) acc[s8] = 0.f;
    const float* hv = hcat + (size_t)v * CIN;
    for (int ci = 0; ci < CIN; ++ci) {
        float h = hv[ci];
#pragma unroll
        for (int s8 = 0; s8 < 8; ++s8)
            acc[s8] += h * Wk[s8 * CIN * COUT + ci * COUT + c];
    }
    float4* zp = (float4*)(z + (size_t)v * (8 * COUT) + c * 8);
    zp[0] = make_float4(acc[0], acc[1], acc[2], acc[3]);
    zp[1] = make_float4(acc[4], acc[5], acc[6], acc[7]);
}

// ==== z-based fused gather-reduce (L3-5): 2x float4 contiguous z reads ====
template<int COUT>
__global__ __launch_bounds__(256) void z_fused_kernel(
    const int* __restrict__ off, const int* __restrict__ cnt, const int* __restrict__ srcs,
    const float* __restrict__ pos, const float* __restrict__ z,
    const float* __restrict__ hcat, const float* __restrict__ Wr,
    const float* __restrict__ bias, float* __restrict__ out,
    float inv2mv, int V, int CIN)
{
    int g = blockIdx.x * 256 + threadIdx.x;
    if (g >= V * COUT) return;
    const int v = g / COUT, c = g % COUT;
    const float pdx = pos[v * 3 + 0], pdy = pos[v * 3 + 1], pdt = pos[v * 3 + 2];
    const int e1 = off[v];
    const int n = cnt[v];
    float acc = 0.f;
    for (int j = e1 - n; j < e1; ++j) {
        int s = srcs[j];
        float p0 = clamp01f((pdx - pos[s * 3 + 0]) * inv2mv + 0.5f);
        float p1 = clamp01f((pdy - pos[s * 3 + 1]) * inv2mv + 0.5f);
        float p2 = clamp01f((pdt - pos[s * 3 + 2]) * inv2mv + 0.5f);
        float q0 = 1.f - p0, q1 = 1.f - p1, q2 = 1.f - p2;
        const float4* zp = (const float4*)(z + (size_t)s * (8 * COUT) + c * 8);
        float4 za = zp[0], zb = zp[1];
        acc += q0 * q1 * q2 * za.x + p0 * q1 * q2 * za.y
             + q0 * p1 * q2 * za.z + p0 * p1 * q2 * za.w
             + q0 * q1 * p2 * zb.x + p0 * q1 * p2 * zb.y
             + q0 * p1 * p2 * zb.z + p0 * p1 * p2 * zb.w;
    }
    float r = bias[c];
    const float* hv = hcat + (size_t)v * CIN;
    for (int ci = 0; ci < CIN; ++ci)
        r += hv[ci] * Wr[ci * COUT + c];
    r += acc / fmaxf((float)n, 1.0f);
    out[g] = fmaxf(r, 0.0f);
}

// ======================= voxel pooling: counting-sort + copy + sequential reduce =====
__global__ __launch_bounds__(256) void pool_cluster_kernel(
    const float* __restrict__ pos, const int* __restrict__ batch, int bdiv, int V,
    int nx, int ny, int nt, int* __restrict__ cl, int* __restrict__ cnt)
{
    int n = blockIdx.x * 256 + threadIdx.x;
    if (n >= V) return;
    int b = batch ? batch[n] : (n / bdiv);
    float px = pos[n * 3 + 0], py = pos[n * 3 + 1], pt = pos[n * 3 + 2];
    int ix = (int)floorf(px * (float)nx); ix = min(max(ix, 0), nx - 1);
    int iy = (int)floorf(py * (float)ny); iy = min(max(iy, 0), ny - 1);
    int it = (int)floorf(pt * (float)nt); it = min(max(it, 0), nt - 1);
    int c = ((b * nx + ix) * ny + iy) * nt + it;
    cl[n] = c;
    atomicAdd(&cnt[c], 1);
}

// XCD-range-partitioned (by cluster id), nt-loads on the cl stream.
__global__ __launch_bounds__(256) void pool_scatter_kernel(
    const int* __restrict__ cl, int* __restrict__ off, int* __restrict__ order, int V, int rv)
{
    const int lo = (int)(blockIdx.x & 7) * rv;
    const int hi = lo + rv;
    const int base = (int)(blockIdx.x >> 3) << 10;
#pragma unroll
    for (int k = 0; k < 4; ++k) {
        int n = base + (k << 8) + threadIdx.x;
        if (n < V) {
            int c = __builtin_nontemporal_load(&cl[n]);
            if (c >= lo && c < hi) {
                int slot = atomicAdd(&off[c], 1);
                order[slot] = n;
            }
        }
    }
}

template<int COUT>
__global__ __launch_bounds__(256) void pool_copy_kernel(
    const int* __restrict__ order, const float* __restrict__ h,
    const float* __restrict__ pos,
    float* __restrict__ S, float* __restrict__ Spos, int V)
{
    int g = blockIdx.x * 256 + threadIdx.x;
    if (g >= V * COUT) return;
    int slot = g / COUT;
    int c = g % COUT;
    int n = order[slot];
    S[g] = h[(size_t)n * COUT + c];
    if (c < 3) Spos[slot * 3 + c] = pos[n * 3 + c];
}

// PAD=2: append pooled pos.xy after COUT channels (hcat layout); PAD=0: plain h.
template<int COUT, int DOMEAN, int PAD>
__global__ __launch_bounds__(256) void pool_reduce_kernel(
    const int* __restrict__ off, const int* __restrict__ cnt,
    const float* __restrict__ S, const float* __restrict__ Spos,
    float* __restrict__ hnext, float* __restrict__ pos_out, int Vc)
{
    const int g = blockIdx.x * 256 + threadIdx.x;
    if (g >= Vc * COUT) return;
    const int v = g / COUT;
    const int c = g % COUT;
    const int e1 = off[v];
    const int n0 = e1 - cnt[v];
    float acc = 0.0f;
    float ps = 0.0f;
    int j = n0;
    for (; j + 3 < e1; j += 4) {
        float a0 = S[(size_t)(j + 0) * COUT + c];
        float a1 = S[(size_t)(j + 1) * COUT + c];
        float a2 = S[(size_t)(j + 2) * COUT + c];
        float a3 = S[(size_t)(j + 3) * COUT + c];
        if (DOMEAN) acc += (a0 + a1) + (a2 + a3);
        else        acc = fmaxf(acc, fmaxf(fmaxf(a0, a1), fmaxf(a2, a3)));
        if (c < 3) {
            float p0 = Spos[(j + 0) * 3 + c];
            float p1 = Spos[(j + 1) * 3 + c];
            float p2 = Spos[(j + 2) * 3 + c];
            float p3 = Spos[(j + 3) * 3 + c];
            ps += (p0 + p1) + (p2 + p3);
        }
    }
    for (; j < e1; ++j) {
        float a0 = S[(size_t)j * COUT + c];
        acc = DOMEAN ? (acc + a0) : fmaxf(acc, a0);
        if (c < 3) ps += Spos[j * 3 + c];
    }
    float m = fmaxf((float)cnt[v], 1.0f);
    float* hp = hnext + (size_t)v * (COUT + PAD);
    hp[c] = DOMEAN ? (acc / m) : acc;
    if (c < 3) {
        float pm = ps / m;
        pos_out[v * 3 + c] = pm;
        if (PAD >= 2 && c < 2) hp[COUT + c] = pm;
    }
}

// ======================= host =======================
extern "C" void kernel_launch(void* const* d_in, const int* in_sizes, int n_in,
                              void* d_out, int out_size, void* d_ws, size_t ws_size,
                              hipStream_t stream)
{
    (void)in_sizes; (void)n_in; (void)out_size;
    const float* x    = (const float*)d_in[0];
    const float* pos0 = (const float*)d_in[1];
    const int*   bat  = (const int*)d_in[2];
    const int* e1 = (const int*)d_in[3];
    const int* e2 = (const int*)d_in[4];
    const int* e3 = (const int*)d_in[5];
    const int* e4 = (const int*)d_in[6];
    const int* e5 = (const int*)d_in[7];
    const float* W1 = (const float*)d_in[8],  *R1 = (const float*)d_in[9],  *B1 = (const float*)d_in[10];
    const float* W2 = (const float*)d_in[11], *R2 = (const float*)d_in[12], *B2 = (const float*)d_in[13];
    const float* W3 = (const float*)d_in[14], *R3 = (const float*)d_in[15], *B3 = (const float*)d_in[16];
    const float* W4 = (const float*)d_in[17], *R4 = (const float*)d_in[18], *B4 = (const float*)d_in[19];
    const float* W5 = (const float*)d_in[20], *R5 = (const float*)d_in[21], *B5 = (const float*)d_in[22];

    const int E1 = 3600000, E2 = 786432, E3 = 196608, E4 = 24576, E5 = 3072;

    if (ws_size < (size_t)21800000 * sizeof(float)) return;
    float* ws = (float*)d_ws;
    // pools (floats): P0 12.6M (z / big scratch) | P1 6.3M (layer out) | P2 1.6M (pooled h in)
    //                 P3 1.0M (CSR ints, L2-5)   | P4 0.3M (pos)
    float* P0 = ws;
    float* P1 = ws + 12600000;
    float* P2 = ws + 18900000;
    int*   P3 = (int*)(ws + 20500000);
    float* P4 = ws + 21500000;
    // scan scratch: last 256 ints of P3 pool (never overlaps CSR usage <= 983040 ints)
    int* SCR_BS = P3 + 999744;          // block sums (<= 74)
    int* SCR_BO = SCR_BS + 96;          // scanned block sums

    float* out3 = (float*)d_out;           // 1536*128
    float* hfin = (float*)d_out + 196608;  // 192*128

#define MSI(p, ni) hipMemsetAsync((p), 0, (size_t)(ni) * sizeof(int), stream)

    // hierarchical exclusive scan: cntp[0..Vn) -> offp[0..Vn)
#define SCAN(cntp, offp, Vn)                                                                     \
    {                                                                                            \
        int nb_ = ((Vn) + 4095) / 4096;                                                          \
        if (nb_ <= 1) {                                                                          \
            scan1_kernel<<<1, 256, 0, stream>>>((cntp), (offp), nullptr, (Vn));                  \
        } else {                                                                                 \
            scan1_kernel<<<nb_, 256, 0, stream>>>((cntp), (offp), SCR_BS, (Vn));                 \
            scan1_kernel<<<1, 256, 0, stream>>>(SCR_BS, SCR_BO, nullptr, nb_);                   \
            scan_add_kernel<<<((Vn) + 255) / 256, 256, 0, stream>>>((offp), SCR_BO, (Vn));       \
        }                                                                                        \
    }

    // Build dst-CSR: cnt/off/srcs at given int base. off[v] = segment END after scatter.
#define ESORT(base, ep, En, Vn)                                                                  \
    int* cnt_ = (base);                                                                          \
    int* off_ = cnt_ + (Vn);                                                                     \
    int* src_ = off_ + (Vn);                                                                     \
    MSI(cnt_, (Vn));                                                                             \
    edge_count_kernel<<<((En) + 255) / 256, 256, 0, stream>>>((ep) + (En), cnt_, En);            \
    SCAN(cnt_, off_, (Vn));                                                                      \
    edge_scatter_kernel<<<8 * (((En) + 1023) / 1024), 256, 0, stream>>>(                         \
        (ep), (ep) + (En), off_, src_, En, (Vn) >> 3)

    // Pool: scratch at float base SB: [SF Vn*COUT][Spos Vn*3][ICL Vn][IORD Vn][ICNT Vc][IOFF Vc]
#define POOL(SB, hsrc, possrc, batp, bdiv, Vn, NX, NY, NT, COUTV, DM, PADV, hdst, posdst)   \
    {                                                                                       \
        int Vc = 4 * (NX) * (NY) * (NT);                                                    \
        float* SF   = (SB);                                                                 \
        float* SPOS = SF + (size_t)(Vn) * (COUTV);                                          \
        int* ICL  = (int*)(SPOS + (size_t)(Vn) * 3);                                        \
        int* IORD = ICL + (Vn);                                                             \
        int* ICNT = IORD + (Vn);                                                            \
        int* IOFF = ICNT + Vc;                                                              \
        MSI(ICNT, Vc);                                                                      \
        pool_cluster_kernel<<<((Vn) + 255) / 256, 256, 0, stream>>>(                        \
            possrc, batp, bdiv, Vn, NX, NY, NT, ICL, ICNT);                                 \
        SCAN(ICNT, IOFF, Vc);                                                               \
        pool_scatter_kernel<<<8 * (((Vn) + 1023) / 1024), 256, 0, stream>>>(                \
            ICL, IOFF, IORD, Vn, Vc >> 3);                                                  \
        pool_copy_kernel<COUTV><<<((size_t)(Vn) * (COUTV) + 255) / 256, 256, 0, stream>>>(  \
            IORD, hsrc, possrc, SF, SPOS, Vn);                                              \
        pool_reduce_kernel<COUTV, DM, PADV><<<((size_t)Vc * (COUTV) + 255) / 256, 0,        \
            stream>>>(IOFF, ICNT, SF, SPOS, hdst, posdst, Vc);                              \
    }
    // NOTE: the above accidentally dropped block size; fixed by re-expansion below.
#undef POOL
#define POOL(SB, hsrc, possrc, batp, bdiv, Vn, NX, NY, NT, COUTV, DM, PADV, hdst, posdst)   \
    {                                                                                       \
        int Vc = 4 * (NX) * (NY) * (NT);                                                    \
        float* SF   = (SB);                                                                 \
        float* SPOS = SF + (size_t)(Vn) * (COUTV);                                          \
        int* ICL  = (int*)(SPOS + (size_t)(Vn) * 3);                                        \
        int* IORD = ICL + (Vn);                                                             \
        int* ICNT = IORD + (Vn);                                                            \
        int* IOFF = ICNT + Vc;                                                              \
        MSI(ICNT, Vc);                                                                      \
        pool_cluster_kernel<<<((Vn) + 255) / 256, 256, 0, stream>>>(                        \
            possrc, batp, bdiv, Vn, NX, NY, NT, ICL, ICNT);                                 \
        SCAN(ICNT, IOFF, Vc);                                                               \
        pool_scatter_kernel<<<8 * (((Vn) + 1023) / 1024), 256, 0, stream>>>(                \
            ICL, IOFF, IORD, Vn, Vc >> 3);                                                  \
        pool_copy_kernel<COUTV><<<((size_t)(Vn) * (COUTV) + 255) / 256, 256, 0, stream>>>(  \
            IORD, hsrc, possrc, SF, SPOS, Vn);                                              \
        pool_reduce_kernel<COUTV, DM, PADV><<<((size_t)Vc * (COUTV) + 255) / 256, 256, 0,   \
            stream>>>(IOFF, ICNT, SF, SPOS, hdst, posdst, Vc);                              \
    }

    // ---------- Layer 1: 300000 nodes, CIN=3, COUT=16 (CSR gather, float4-packed) ----------
    {
        ESORT((int*)P0, e1, E1, 300000);            // ints [0 .. 4.2M) in P0
        float4* xp4 = (float4*)(P0 + 4200000);      // 1.2M floats [4.2M .. 5.4M)
        pack_xpos_kernel<<<(300000 + 255) / 256, 256, 0, stream>>>(x, pos0, xp4, 300000);
        l1_fused_kernel<<<(300000 * 16) / 256, 256, 0, stream>>>(
            off_, cnt_, src_, xp4, W1, R1, B1, P1, 20.0f, 300000);
        // CSR1 + xp4 dead -> pool scratch at P0. h1p (stride 16) -> P2, pos2 -> P4.
        POOL(P0, P1, pos0, bat, 0, 300000, 64, 48, 8, 16, 0, 0, P2, P4);
    }
    // ---------- Layer 2: 98304 nodes, CIN=18, COUT=64 — quarter-z path, zero atomics ------
    {
        ESORT(P3, e2, E2, 98304);                   // 983K ints in P3
        for (int q = 0; q < 4; ++q) {
            z_node_l2_kernel<<<(98304 * 16) / 256, 256, 0, stream>>>(P2, P4, W2, P0, 98304, q);
            z_edge_l2_kernel<<<(98304 * 16) / 256, 256, 0, stream>>>(
                off_, cnt_, src_, P4, P0, P2, R2, B2, P1, 10.0f, 98304, q);
        }
        // z dead -> pool scratch at P0. h2p (hcat stride 66) -> P2, pos3 -> P4.
        POOL(P0, P1, P4, nullptr, 24576, 98304, 32, 24, 4, 64, 0, 2, P2, P4);
    }
    // ---------- Layer 3: 12288 nodes, CIN=66, COUT=128 (full z path) ----------
    {
        z_node_kernel<66, 128><<<(12288 * 128) / 256, 256, 0, stream>>>(P2, W3, P0, 12288);
        ESORT(P3, e3, E3, 12288);
        z_fused_kernel<128><<<(12288 * 128) / 256, 256, 0, stream>>>(
            off_, cnt_, src_, P4, P0, P2, R3, B3, P1, 6.0f, 12288, 66);
        // z3 dead -> pool scratch at P0. h3p (stride 130) -> P2, pos4 -> P4.
        POOL(P0, P1, P4, nullptr, 3072, 12288, 16, 12, 2, 128, 0, 2, P2, P4);
    }
    // ---------- Layer 4: 1536 nodes, CIN=130, COUT=128 -> out3 ----------
    {
        z_node_kernel<130, 128><<<(1536 * 128) / 256, 256, 0, stream>>>(P2, W4, P0, 1536);
        ESORT(P3, e4, E4, 1536);
        z_fused_kernel<128><<<(1536 * 128) / 256, 256, 0, stream>>>(
            off_, cnt_, src_, P4, P0, P2, R4, B4, out3, 3.0f, 1536, 130);
        POOL(P0, out3, P4, nullptr, 384, 1536, 8, 6, 1, 128, 1, 2, P2, P4);
    }
    // ---------- Layer 5: 192 nodes, CIN=130, COUT=128 -> hfin ----------
    {
        z_node_kernel<130, 128><<<(192 * 128) / 256, 256, 0, stream>>>(P2, W5, P0, 192);
        ESORT(P3, e5, E5, 192);
        z_fused_kernel<128><<<(192 * 128) / 256, 256, 0, stream>>>(
            off_, cnt_, src_, P4, P0, P2, R5, B5, hfin, 1.5f, 192, 130);
    }
#undef POOL
#undef ESORT
#undef SCAN
#undef MSI
}

// Round 7
// 1600.266 us; speedup vs baseline: 1.7818x; 1.1941x over previous
//
#include <hip/hip_runtime.h>
#include <cstdint>

__device__ __forceinline__ float clamp01f(float v) { return fminf(fmaxf(v, 0.0f), 1.0f); }

// ======================= legacy CSR build (layers 3-5, small E) =======================
__global__ __launch_bounds__(256) void edge_count_kernel(
    const int* __restrict__ edst, int* __restrict__ cnt, int E)
{
    int e = blockIdx.x * 256 + threadIdx.x;
    if (e < E) atomicAdd(&cnt[__builtin_nontemporal_load(&edst[e])], 1);
}

__global__ __launch_bounds__(256) void edge_scatter_kernel(
    const int* __restrict__ esrc, const int* __restrict__ edst,
    int* __restrict__ off, int* __restrict__ srcs, int E, int rv)
{
    const int lo = (int)(blockIdx.x & 7) * rv;
    const int hi = lo + rv;
    const int base = (int)(blockIdx.x >> 3) << 10;
#pragma unroll
    for (int k = 0; k < 4; ++k) {
        int e = base + (k << 8) + threadIdx.x;
        if (e < E) {
            int d = __builtin_nontemporal_load(&edst[e]);
            if (d >= lo && d < hi) {
                int s = __builtin_nontemporal_load(&esrc[e]);
                int slot = atomicAdd(&off[d], 1);
                srcs[slot] = s;
            }
        }
    }
}

// ============== hierarchical exclusive scan ==============
__global__ __launch_bounds__(256) void scan1_kernel(
    const int* __restrict__ cnt, int* __restrict__ off, int* __restrict__ bsum, int V)
{
    __shared__ int lds[4096];
    __shared__ int ssum[256];
    const int t = threadIdx.x;
    const int base = blockIdx.x * 4096;
    for (int i = t; i < 4096; i += 256) {
        int g = base + i;
        lds[i] = (g < V) ? cnt[g] : 0;
    }
    __syncthreads();
    int loc[16];
    int s = 0;
#pragma unroll
    for (int k = 0; k < 16; ++k) { loc[k] = s; s += lds[t * 16 + k]; }
    ssum[t] = s;
    __syncthreads();
    for (int d = 1; d < 256; d <<= 1) {
        int v = (t >= d) ? ssum[t - d] : 0;
        __syncthreads();
        ssum[t] += v;
        __syncthreads();
    }
    const int tbase = (t == 0) ? 0 : ssum[t - 1];
    if (t == 255 && bsum) bsum[blockIdx.x] = ssum[255];
#pragma unroll
    for (int k = 0; k < 16; ++k) lds[t * 16 + k] = tbase + loc[k];
    __syncthreads();
    for (int i = t; i < 4096; i += 256) {
        int g = base + i;
        if (g < V) off[g] = lds[i];
    }
}

__global__ __launch_bounds__(256) void scan_add_kernel(
    int* __restrict__ off, const int* __restrict__ bso, int V)
{
    int g = blockIdx.x * 256 + threadIdx.x;
    if (g < V) off[g] += bso[g >> 12];
}

// ======================= bucketed CSR build (L1, L2) =======================
// Pass A1: global per-bucket counts (bucket = dst >> shift, NB <= 256).
__global__ __launch_bounds__(256) void bin_count_kernel(
    const int* __restrict__ edst, int* __restrict__ gcnt, int E, int shift)
{
    __shared__ int h[256];
    const int t = threadIdx.x;
    h[t] = 0;
    __syncthreads();
    const int base = blockIdx.x << 12;
#pragma unroll
    for (int k = 0; k < 16; ++k) {
        int e = base + (k << 8) + t;
        if (e < E) {
            int d = __builtin_nontemporal_load(&edst[e]);
            atomicAdd(&h[d >> shift], 1);
        }
    }
    __syncthreads();
    if (h[t]) atomicAdd(&gcnt[t], h[t]);
}

// Pass A2: scatter (dst,src) into bucket-contiguous staging; per-(block,bucket) runs
// reserved with ONE atomic per pair -> staged writes are ~112B full-line runs.
__global__ __launch_bounds__(256) void bin_scatter_kernel(
    const int* __restrict__ esrc, const int* __restrict__ edst,
    int* __restrict__ gcur, int* __restrict__ stD, int* __restrict__ stS,
    int E, int shift)
{
    __shared__ int d_l[4096];
    __shared__ int s_l[4096];
    __shared__ int h[256];
    __shared__ int rbase[256];
    const int t = threadIdx.x;
    h[t] = 0;
    __syncthreads();
    const int base = blockIdx.x << 12;
#pragma unroll
    for (int k = 0; k < 16; ++k) {
        int i = (k << 8) + t;
        int e = base + i;
        if (e < E) {
            int d = __builtin_nontemporal_load(&edst[e]);
            int s = __builtin_nontemporal_load(&esrc[e]);
            d_l[i] = d; s_l[i] = s;
            atomicAdd(&h[d >> shift], 1);
        }
    }
    __syncthreads();
    rbase[t] = h[t] ? atomicAdd(&gcur[t], h[t]) : 0;
    h[t] = 0;   // reuse as cursor
    __syncthreads();
#pragma unroll
    for (int k = 0; k < 16; ++k) {
        int i = (k << 8) + t;
        int e = base + i;
        if (e < E) {
            int d = d_l[i];
            int b = d >> shift;
            int r = atomicAdd(&h[b], 1);
            int pos = rbase[b] + r;
            stD[pos] = d;
            stS[pos] = s_l[i];
        }
    }
}

// Pass B: one block per bucket. LDS histogram -> LDS scan -> LDS-cursor scatter.
// Zero fabric atomics; srcs writes confined to the bucket's L2-resident span.
// gcur[b] (post-A2) = bucket base + count; gcnt[b] = count.
__global__ __launch_bounds__(1024) void bucket_csr_kernel(
    const int* __restrict__ gcur, const int* __restrict__ gcnt,
    const int* __restrict__ stD, const int* __restrict__ stS,
    int* __restrict__ cnt, int* __restrict__ off, int* __restrict__ srcs,
    int V, int shift)
{
    __shared__ int h[2048];
    __shared__ int o[2048];
    __shared__ int ps[1024];
    const int t = threadIdx.x;
    const int b = blockIdx.x;
    const int v0 = b << shift;
    const int nv = min(1 << shift, V - v0);
    const int s1 = gcur[b];
    const int s0 = s1 - gcnt[b];
    h[t] = 0; h[t + 1024] = 0;
    __syncthreads();
    for (int i = s0 + t; i < s1; i += 1024)
        atomicAdd(&h[stD[i] - v0], 1);
    __syncthreads();
    int a = h[2 * t], b2 = h[2 * t + 1];
    ps[t] = a + b2;
    __syncthreads();
    for (int d = 1; d < 1024; d <<= 1) {
        int v = (t >= d) ? ps[t - d] : 0;
        __syncthreads();
        ps[t] += v;
        __syncthreads();
    }
    int pb = (t == 0) ? 0 : ps[t - 1];
    o[2 * t] = pb;
    o[2 * t + 1] = pb + a;
    __syncthreads();
    for (int i = t; i < nv; i += 1024) {
        int hv = h[i];
        cnt[v0 + i] = hv;
        off[v0 + i] = s0 + o[i] + hv;   // segment END convention
    }
    __syncthreads();
    for (int i = s0 + t; i < s1; i += 1024) {
        int d = stD[i];
        int r = atomicAdd(&o[d - v0], 1);
        srcs[s0 + r] = stS[i];
    }
}

// ======================= pack (x, pos) into float4 for layer-1 gathers =======
__global__ __launch_bounds__(256) void pack_xpos_kernel(
    const float* __restrict__ x, const float* __restrict__ pos,
    float4* __restrict__ xp, int V)
{
    int n = blockIdx.x * 256 + threadIdx.x;
    if (n >= V) return;
    xp[n] = make_float4(x[n], pos[n * 3 + 0], pos[n * 3 + 1], pos[n * 3 + 2]);
}

// ========== Layer-1 fused, tsum formulation: one THREAD per node ==========
// agg[c] = sum_{s8,ci} tsum[s8][ci] * Wk[s8,ci,c], tsum = sum_edges basis(8) (x) xs(3).
// ~52 VALU + one 16B gather per edge (vs 960 VALU + 16 gathers before).
__global__ __launch_bounds__(256) void l1_fused_kernel(
    const int* __restrict__ off, const int* __restrict__ cnt, const int* __restrict__ srcs,
    const float4* __restrict__ xp,
    const float* __restrict__ Wk, const float* __restrict__ Wr,
    const float* __restrict__ bias, float* __restrict__ out,
    float inv2mv, int V)
{
    __shared__ float sWk[384];
    __shared__ float sWr[48];
    __shared__ float sB[16];
    const int t = threadIdx.x;
    for (int i = t; i < 384; i += 256) sWk[i] = Wk[i];
    if (t < 48) sWr[t] = Wr[t];
    if (t < 16) sB[t] = bias[t];
    __syncthreads();
    const int v = blockIdx.x * 256 + t;
    if (v >= V) return;
    const float4 d = xp[v];  // x, px, py, pt
    const int e1 = off[v];
    const int n = cnt[v];
    float ts[8][3];
#pragma unroll
    for (int s8 = 0; s8 < 8; ++s8) { ts[s8][0] = 0.f; ts[s8][1] = 0.f; ts[s8][2] = 0.f; }
    for (int j = e1 - n; j < e1; ++j) {
        float4 a = xp[srcs[j]];
        float p0 = clamp01f((d.y - a.y) * inv2mv + 0.5f);
        float p1 = clamp01f((d.z - a.z) * inv2mv + 0.5f);
        float p2 = clamp01f((d.w - a.w) * inv2mv + 0.5f);
        float q0 = 1.f - p0, q1 = 1.f - p1, q2 = 1.f - p2;
#pragma unroll
        for (int s8 = 0; s8 < 8; ++s8) {
            float bs = ((s8 & 1) ? p0 : q0) * ((s8 & 2) ? p1 : q1) * ((s8 & 4) ? p2 : q2);
            ts[s8][0] += bs * a.x;
            ts[s8][1] += bs * a.y;
            ts[s8][2] += bs * a.z;
        }
    }
    const float invn = 1.0f / fmaxf((float)n, 1.0f);
    float rr[16];
#pragma unroll
    for (int c = 0; c < 16; ++c) {
        float m = 0.f;
#pragma unroll
        for (int s8 = 0; s8 < 8; ++s8)
            m += ts[s8][0] * sWk[s8 * 48 + c]
               + ts[s8][1] * sWk[s8 * 48 + 16 + c]
               + ts[s8][2] * sWk[s8 * 48 + 32 + c];
        float r = m * invn + d.x * sWr[c] + d.y * sWr[16 + c] + d.z * sWr[32 + c] + sB[c];
        rr[c] = fmaxf(r, 0.0f);
    }
    float4* op = (float4*)(out + (size_t)v * 16);
#pragma unroll
    for (int k = 0; k < 4; ++k)
        op[k] = make_float4(rr[4 * k], rr[4 * k + 1], rr[4 * k + 2], rr[4 * k + 3]);
}

// ======= Layer-2 z quarter, TRANSPOSED layout: z[v][cq][s8], 32B/thread writes =======
__global__ __launch_bounds__(256) void z_node_l2_kernel(
    const float* __restrict__ h16, const float* __restrict__ pos,
    const float* __restrict__ Wk, float* __restrict__ z, int V, int q)
{
    int g = blockIdx.x * 256 + threadIdx.x;
    if (g >= V * 16) return;
    const int cq = g & 15;
    const int v = g >> 4;
    const int qc = q * 16 + cq;
    float acc[8];
#pragma unroll
    for (int s8 = 0; s8 < 8; ++s8) acc[s8] = 0.f;
    const float* hv = h16 + (size_t)v * 16;
#pragma unroll
    for (int ci = 0; ci < 16; ++ci) {
        float h = hv[ci];
#pragma unroll
        for (int s8 = 0; s8 < 8; ++s8)
            acc[s8] += h * Wk[s8 * 1152 + ci * 64 + qc];
    }
    const float px = pos[v * 3 + 0], py = pos[v * 3 + 1];
#pragma unroll
    for (int s8 = 0; s8 < 8; ++s8)
        acc[s8] += px * Wk[s8 * 1152 + 16 * 64 + qc] + py * Wk[s8 * 1152 + 17 * 64 + qc];
    float4* zp = (float4*)(z + (size_t)v * 128 + cq * 8);
    zp[0] = make_float4(acc[0], acc[1], acc[2], acc[3]);
    zp[1] = make_float4(acc[4], acc[5], acc[6], acc[7]);
}

// ======= Layer-2 fused gather-reduce (quarter): 2x float4 contiguous z reads =======
__global__ __launch_bounds__(256) void z_edge_l2_kernel(
    const int* __restrict__ off, const int* __restrict__ cnt, const int* __restrict__ srcs,
    const float* __restrict__ pos, const float* __restrict__ z,
    const float* __restrict__ h16, const float* __restrict__ Wr,
    const float* __restrict__ bias, float* __restrict__ out,
    float inv2mv, int V, int q)
{
    int g = blockIdx.x * 256 + threadIdx.x;
    if (g >= V * 16) return;
    const int v = g >> 4, c = g & 15;
    const int qc = q * 16 + c;
    const float pdx = pos[v * 3 + 0], pdy = pos[v * 3 + 1], pdt = pos[v * 3 + 2];
    float rb = bias[qc];
    const float* hv = h16 + (size_t)v * 16;
#pragma unroll
    for (int ci = 0; ci < 16; ++ci)
        rb += hv[ci] * Wr[ci * 64 + qc];
    rb += pdx * Wr[16 * 64 + qc] + pdy * Wr[17 * 64 + qc];
    const int e1 = off[v];
    const int n = cnt[v];
    float acc = 0.f;
    for (int j = e1 - n; j < e1; ++j) {
        int s = srcs[j];
        float p0 = clamp01f((pdx - pos[s * 3 + 0]) * inv2mv + 0.5f);
        float p1 = clamp01f((pdy - pos[s * 3 + 1]) * inv2mv + 0.5f);
        float p2 = clamp01f((pdt - pos[s * 3 + 2]) * inv2mv + 0.5f);
        float q0 = 1.f - p0, q1 = 1.f - p1, q2 = 1.f - p2;
        const float4* zp = (const float4*)(z + (size_t)s * 128 + c * 8);
        float4 za = zp[0], zb = zp[1];
        acc += q0 * q1 * q2 * za.x + p0 * q1 * q2 * za.y
             + q0 * p1 * q2 * za.z + p0 * p1 * q2 * za.w
             + q0 * q1 * p2 * zb.x + p0 * q1 * p2 * zb.y
             + q0 * p1 * p2 * zb.z + p0 * p1 * p2 * zb.w;
    }
    out[(size_t)v * 64 + qc] = fmaxf(rb + acc / fmaxf((float)n, 1.0f), 0.0f);
}

// ==== z precompute (L3-5), TRANSPOSED layout z[v][c][s8]; 32B/thread writes ====
template<int CIN, int COUT>
__global__ __launch_bounds__(256) void z_node_kernel(
    const float* __restrict__ hcat, const float* __restrict__ Wk,
    float* __restrict__ z, int V)
{
    int g = blockIdx.x * 256 + threadIdx.x;
    if (g >= V * COUT) return;
    const int c = g % COUT;
    const int v = g / COUT;
    float acc[8];
#pragma unroll
    for (int s8 = 0; s8 < 8; ++s8) acc[s8] = 0.f;
    const float* hv = hcat + (size_t)v * CIN;
    for (int ci = 0; ci < CIN; ++ci) {
        float h = hv[ci];
#pragma unroll
        for (int s8 = 0; s8 < 8; ++s8)
            acc[s8] += h * Wk[s8 * CIN * COUT + ci * COUT + c];
    }
    float4* zp = (float4*)(z + (size_t)v * (8 * COUT) + c * 8);
    zp[0] = make_float4(acc[0], acc[1], acc[2], acc[3]);
    zp[1] = make_float4(acc[4], acc[5], acc[6], acc[7]);
}

// ==== z-based fused gather-reduce (L3-5): 2x float4 contiguous z reads ====
template<int COUT>
__global__ __launch_bounds__(256) void z_fused_kernel(
    const int* __restrict__ off, const int* __restrict__ cnt, const int* __restrict__ srcs,
    const float* __restrict__ pos, const float* __restrict__ z,
    const float* __restrict__ hcat, const float* __restrict__ Wr,
    const float* __restrict__ bias, float* __restrict__ out,
    float inv2mv, int V, int CIN)
{
    int g = blockIdx.x * 256 + threadIdx.x;
    if (g >= V * COUT) return;
    const int v = g / COUT, c = g % COUT;
    const float pdx = pos[v * 3 + 0], pdy = pos[v * 3 + 1], pdt = pos[v * 3 + 2];
    const int e1 = off[v];
    const int n = cnt[v];
    float acc = 0.f;
    for (int j = e1 - n; j < e1; ++j) {
        int s = srcs[j];
        float p0 = clamp01f((pdx - pos[s * 3 + 0]) * inv2mv + 0.5f);
        float p1 = clamp01f((pdy - pos[s * 3 + 1]) * inv2mv + 0.5f);
        float p2 = clamp01f((pdt - pos[s * 3 + 2]) * inv2mv + 0.5f);
        float q0 = 1.f - p0, q1 = 1.f - p1, q2 = 1.f - p2;
        const float4* zp = (const float4*)(z + (size_t)s * (8 * COUT) + c * 8);
        float4 za = zp[0], zb = zp[1];
        acc += q0 * q1 * q2 * za.x + p0 * q1 * q2 * za.y
             + q0 * p1 * q2 * za.z + p0 * p1 * q2 * za.w
             + q0 * q1 * p2 * zb.x + p0 * q1 * p2 * zb.y
             + q0 * p1 * p2 * zb.z + p0 * p1 * p2 * zb.w;
    }
    float r = bias[c];
    const float* hv = hcat + (size_t)v * CIN;
    for (int ci = 0; ci < CIN; ++ci)
        r += hv[ci] * Wr[ci * COUT + c];
    r += acc / fmaxf((float)n, 1.0f);
    out[g] = fmaxf(r, 0.0f);
}

// ======================= voxel pooling: counting-sort + copy + sequential reduce =====
__global__ __launch_bounds__(256) void pool_cluster_kernel(
    const float* __restrict__ pos, const int* __restrict__ batch, int bdiv, int V,
    int nx, int ny, int nt, int* __restrict__ cl, int* __restrict__ cnt)
{
    int n = blockIdx.x * 256 + threadIdx.x;
    if (n >= V) return;
    int b = batch ? batch[n] : (n / bdiv);
    float px = pos[n * 3 + 0], py = pos[n * 3 + 1], pt = pos[n * 3 + 2];
    int ix = (int)floorf(px * (float)nx); ix = min(max(ix, 0), nx - 1);
    int iy = (int)floorf(py * (float)ny); iy = min(max(iy, 0), ny - 1);
    int it = (int)floorf(pt * (float)nt); it = min(max(it, 0), nt - 1);
    int c = ((b * nx + ix) * ny + iy) * nt + it;
    cl[n] = c;
    atomicAdd(&cnt[c], 1);
}

__global__ __launch_bounds__(256) void pool_scatter_kernel(
    const int* __restrict__ cl, int* __restrict__ off, int* __restrict__ order, int V, int rv)
{
    const int lo = (int)(blockIdx.x & 7) * rv;
    const int hi = lo + rv;
    const int base = (int)(blockIdx.x >> 3) << 10;
#pragma unroll
    for (int k = 0; k < 4; ++k) {
        int n = base + (k << 8) + threadIdx.x;
        if (n < V) {
            int c = __builtin_nontemporal_load(&cl[n]);
            if (c >= lo && c < hi) {
                int slot = atomicAdd(&off[c], 1);
                order[slot] = n;
            }
        }
    }
}

template<int COUT>
__global__ __launch_bounds__(256) void pool_copy_kernel(
    const int* __restrict__ order, const float* __restrict__ h,
    const float* __restrict__ pos,
    float* __restrict__ S, float* __restrict__ Spos, int V)
{
    int g = blockIdx.x * 256 + threadIdx.x;
    if (g >= V * COUT) return;
    int slot = g / COUT;
    int c = g % COUT;
    int n = order[slot];
    S[g] = h[(size_t)n * COUT + c];
    if (c < 3) Spos[slot * 3 + c] = pos[n * 3 + c];
}

template<int COUT, int DOMEAN, int PAD>
__global__ __launch_bounds__(256) void pool_reduce_kernel(
    const int* __restrict__ off, const int* __restrict__ cnt,
    const float* __restrict__ S, const float* __restrict__ Spos,
    float* __restrict__ hnext, float* __restrict__ pos_out, int Vc)
{
    const int g = blockIdx.x * 256 + threadIdx.x;
    if (g >= Vc * COUT) return;
    const int v = g / COUT;
    const int c = g % COUT;
    const int e1 = off[v];
    const int n0 = e1 - cnt[v];
    float acc = 0.0f;
    float ps = 0.0f;
    int j = n0;
    for (; j + 3 < e1; j += 4) {
        float a0 = S[(size_t)(j + 0) * COUT + c];
        float a1 = S[(size_t)(j + 1) * COUT + c];
        float a2 = S[(size_t)(j + 2) * COUT + c];
        float a3 = S[(size_t)(j + 3) * COUT + c];
        if (DOMEAN) acc += (a0 + a1) + (a2 + a3);
        else        acc = fmaxf(acc, fmaxf(fmaxf(a0, a1), fmaxf(a2, a3)));
        if (c < 3) {
            float p0 = Spos[(j + 0) * 3 + c];
            float p1 = Spos[(j + 1) * 3 + c];
            float p2 = Spos[(j + 2) * 3 + c];
            float p3 = Spos[(j + 3) * 3 + c];
            ps += (p0 + p1) + (p2 + p3);
        }
    }
    for (; j < e1; ++j) {
        float a0 = S[(size_t)j * COUT + c];
        acc = DOMEAN ? (acc + a0) : fmaxf(acc, a0);
        if (c < 3) ps += Spos[j * 3 + c];
    }
    float m = fmaxf((float)cnt[v], 1.0f);
    float* hp = hnext + (size_t)v * (COUT + PAD);
    hp[c] = DOMEAN ? (acc / m) : acc;
    if (c < 3) {
        float pm = ps / m;
        pos_out[v * 3 + c] = pm;
        if (PAD >= 2 && c < 2) hp[COUT + c] = pm;
    }
}

// ======================= host =======================
extern "C" void kernel_launch(void* const* d_in, const int* in_sizes, int n_in,
                              void* d_out, int out_size, void* d_ws, size_t ws_size,
                              hipStream_t stream)
{
    (void)in_sizes; (void)n_in; (void)out_size;
    const float* x    = (const float*)d_in[0];
    const float* pos0 = (const float*)d_in[1];
    const int*   bat  = (const int*)d_in[2];
    const int* e1 = (const int*)d_in[3];
    const int* e2 = (const int*)d_in[4];
    const int* e3 = (const int*)d_in[5];
    const int* e4 = (const int*)d_in[6];
    const int* e5 = (const int*)d_in[7];
    const float* W1 = (const float*)d_in[8],  *R1 = (const float*)d_in[9],  *B1 = (const float*)d_in[10];
    const float* W2 = (const float*)d_in[11], *R2 = (const float*)d_in[12], *B2 = (const float*)d_in[13];
    const float* W3 = (const float*)d_in[14], *R3 = (const float*)d_in[15], *B3 = (const float*)d_in[16];
    const float* W4 = (const float*)d_in[17], *R4 = (const float*)d_in[18], *B4 = (const float*)d_in[19];
    const float* W5 = (const float*)d_in[20], *R5 = (const float*)d_in[21], *B5 = (const float*)d_in[22];

    const int E1 = 3600000, E2 = 786432, E3 = 196608, E4 = 24576, E5 = 3072;

    if (ws_size < (size_t)21800000 * sizeof(float)) return;
    float* ws = (float*)d_ws;
    // pools (floats): P0 12.6M (z / staging / big scratch) | P1 6.3M (layer out)
    //                 P2 1.6M (pooled h in) | P3 1.0M ints (CSR L2-5 + bucket scratch) | P4 0.3M (pos)
    float* P0 = ws;
    float* P1 = ws + 12600000;
    float* P2 = ws + 18900000;
    int*   P3 = (int*)(ws + 20500000);
    float* P4 = ws + 21500000;
    int* GCNT   = P3 + 990000;   // 256 ints (bucket counts)
    int* GCUR   = P3 + 990256;   // 256 ints (bucket cursors / bases)
    int* SCR_BS = P3 + 999744;   // pool-scan block sums
    int* SCR_BO = SCR_BS + 96;

    float* out3 = (float*)d_out;           // 1536*128
    float* hfin = (float*)d_out + 196608;  // 192*128

#define MSI(p, ni) hipMemsetAsync((p), 0, (size_t)(ni) * sizeof(int), stream)

#define SCAN(cntp, offp, Vn)                                                                     \
    {                                                                                            \
        int nb_ = ((Vn) + 4095) / 4096;                                                          \
        if (nb_ <= 1) {                                                                          \
            scan1_kernel<<<1, 256, 0, stream>>>((cntp), (offp), nullptr, (Vn));                  \
        } else {                                                                                 \
            scan1_kernel<<<nb_, 256, 0, stream>>>((cntp), (offp), SCR_BS, (Vn));                 \
            scan1_kernel<<<1, 256, 0, stream>>>(SCR_BS, SCR_BO, nullptr, nb_);                   \
            scan_add_kernel<<<((Vn) + 255) / 256, 256, 0, stream>>>((offp), SCR_BO, (Vn));       \
        }                                                                                        \
    }

    // Bucketed CSR build (L1/L2): cnt/off/srcs + staging stD/stS; NB = ceil(Vn / 2^SHIFT) <= 256.
#define BSORT(cntP, offP, srcP, stD, stS, ep, En, Vn, SHIFT, NB)                                 \
    {                                                                                            \
        MSI(GCNT, 256);                                                                          \
        bin_count_kernel<<<((En) + 4095) / 4096, 256, 0, stream>>>((ep) + (En), GCNT, En, SHIFT);\
        scan1_kernel<<<1, 256, 0, stream>>>(GCNT, GCUR, nullptr, NB);                            \
        bin_scatter_kernel<<<((En) + 4095) / 4096, 256, 0, stream>>>(                            \
            (ep), (ep) + (En), GCUR, stD, stS, En, SHIFT);                                       \
        bucket_csr_kernel<<<NB, 1024, 0, stream>>>(                                              \
            GCUR, GCNT, stD, stS, cntP, offP, srcP, Vn, SHIFT);                                  \
    }

    // legacy CSR build for small layers
#define ESORT(base, ep, En, Vn)                                                                  \
    int* cnt_ = (base);                                                                          \
    int* off_ = cnt_ + (Vn);                                                                     \
    int* src_ = off_ + (Vn);                                                                     \
    MSI(cnt_, (Vn));                                                                             \
    edge_count_kernel<<<((En) + 255) / 256, 256, 0, stream>>>((ep) + (En), cnt_, En);            \
    SCAN(cnt_, off_, (Vn));                                                                      \
    edge_scatter_kernel<<<8 * (((En) + 1023) / 1024), 256, 0, stream>>>(                         \
        (ep), (ep) + (En), off_, src_, En, (Vn) >> 3)

#define POOL(SB, hsrc, possrc, batp, bdiv, Vn, NX, NY, NT, COUTV, DM, PADV, hdst, posdst)   \
    {                                                                                       \
        int Vc = 4 * (NX) * (NY) * (NT);                                                    \
        float* SF   = (SB);                                                                 \
        float* SPOS = SF + (size_t)(Vn) * (COUTV);                                          \
        int* ICL  = (int*)(SPOS + (size_t)(Vn) * 3);                                        \
        int* IORD = ICL + (Vn);                                                             \
        int* ICNT = IORD + (Vn);                                                            \
        int* IOFF = ICNT + Vc;                                                              \
        MSI(ICNT, Vc);                                                                      \
        pool_cluster_kernel<<<((Vn) + 255) / 256, 256, 0, stream>>>(                        \
            possrc, batp, bdiv, Vn, NX, NY, NT, ICL, ICNT);                                 \
        SCAN(ICNT, IOFF, Vc);                                                               \
        pool_scatter_kernel<<<8 * (((Vn) + 1023) / 1024), 256, 0, stream>>>(                \
            ICL, IOFF, IORD, Vn, Vc >> 3);                                                  \
        pool_copy_kernel<COUTV><<<((size_t)(Vn) * (COUTV) + 255) / 256, 256, 0, stream>>>(  \
            IORD, hsrc, possrc, SF, SPOS, Vn);                                              \
        pool_reduce_kernel<COUTV, DM, PADV><<<((size_t)Vc * (COUTV) + 255) / 256, 256, 0,   \
            stream>>>(IOFF, ICNT, SF, SPOS, hdst, posdst, Vc);                              \
    }

    // ---------- Layer 1: 300000 nodes, CIN=3, COUT=16 ----------
    {
        // P0 ints: cnt 300000 | off 300000 | srcs 3.6M | stD 3.6M | stS 3.6M = 11.4M ints;
        // xp4 at P0+11400000 floats (1.2M) -> 12.6M exact.
        int* cnt1 = (int*)P0;
        int* off1 = cnt1 + 300000;
        int* src1 = off1 + 300000;
        int* stD  = src1 + 3600000;
        int* stS  = stD + 3600000;
        float4* xp4 = (float4*)(P0 + 11400000);
        BSORT(cnt1, off1, src1, stD, stS, e1, E1, 300000, 11, 147);
        pack_xpos_kernel<<<(300000 + 255) / 256, 256, 0, stream>>>(x, pos0, xp4, 300000);
        l1_fused_kernel<<<(300000 + 255) / 256, 256, 0, stream>>>(
            off1, cnt1, src1, xp4, W1, R1, B1, P1, 20.0f, 300000);
        // CSR + staging + xp4 dead -> pool scratch at P0. h1p (stride 16) -> P2, pos2 -> P4.
        POOL(P0, P1, pos0, bat, 0, 300000, 64, 48, 8, 16, 0, 0, P2, P4);
    }
    // ---------- Layer 2: 98304 nodes, CIN=18, COUT=64 — quarter-z path ----------
    {
        int* cnt2 = P3;
        int* off2 = cnt2 + 98304;
        int* src2 = off2 + 98304;
        int* stD  = (int*)P0;          // staging in P0 (free before z quarters)
        int* stS  = stD + E2;
        BSORT(cnt2, off2, src2, stD, stS, e2, E2, 98304, 10, 96);
        for (int q = 0; q < 4; ++q) {
            z_node_l2_kernel<<<(98304 * 16) / 256, 256, 0, stream>>>(P2, P4, W2, P0, 98304, q);
            z_edge_l2_kernel<<<(98304 * 16) / 256, 256, 0, stream>>>(
                off2, cnt2, src2, P4, P0, P2, R2, B2, P1, 10.0f, 98304, q);
        }
        POOL(P0, P1, P4, nullptr, 24576, 98304, 32, 24, 4, 64, 0, 2, P2, P4);
    }
    // ---------- Layer 3: 12288 nodes, CIN=66, COUT=128 (full z path) ----------
    {
        z_node_kernel<66, 128><<<(12288 * 128) / 256, 256, 0, stream>>>(P2, W3, P0, 12288);
        ESORT(P3, e3, E3, 12288);
        z_fused_kernel<128><<<(12288 * 128) / 256, 256, 0, stream>>>(
            off_, cnt_, src_, P4, P0, P2, R3, B3, P1, 6.0f, 12288, 66);
        POOL(P0, P1, P4, nullptr, 3072, 12288, 16, 12, 2, 128, 0, 2, P2, P4);
    }
    // ---------- Layer 4: 1536 nodes, CIN=130, COUT=128 -> out3 ----------
    {
        z_node_kernel<130, 128><<<(1536 * 128) / 256, 256, 0, stream>>>(P2, W4, P0, 1536);
        ESORT(P3, e4, E4, 1536);
        z_fused_kernel<128><<<(1536 * 128) / 256, 256, 0, stream>>>(
            off_, cnt_, src_, P4, P0, P2, R4, B4, out3, 3.0f, 1536, 130);
        POOL(P0, out3, P4, nullptr, 384, 1536, 8, 6, 1, 128, 1, 2, P2, P4);
    }
    // ---------- Layer 5: 192 nodes, CIN=130, COUT=128 -> hfin ----------
    {
        z_node_kernel<130, 128><<<(192 * 128) / 256, 256, 0, stream>>>(P2, W5, P0, 192);
        ESORT(P3, e5, E5, 192);
        z_fused_kernel<128><<<(192 * 128) / 256, 256, 0, stream>>>(
            off_, cnt_, src_, P4, P0, P2, R5, B5, hfin, 1.5f, 192, 130);
    }
#undef POOL
#undef ESORT
#undef BSORT
#undef SCAN
#undef MSI
}

// Round 8
// 1172.888 us; speedup vs baseline: 2.4310x; 1.3644x over previous
//
#include <hip/hip_runtime.h>
#include <cstdint>

__device__ __forceinline__ float clamp01f(float v) { return fminf(fmaxf(v, 0.0f), 1.0f); }

// ======================= legacy CSR build (layers 3-5, small E) =======================
__global__ __launch_bounds__(256) void edge_count_kernel(
    const int* __restrict__ edst, int* __restrict__ cnt, int E)
{
    int e = blockIdx.x * 256 + threadIdx.x;
    if (e < E) atomicAdd(&cnt[__builtin_nontemporal_load(&edst[e])], 1);
}

__global__ __launch_bounds__(256) void edge_scatter_kernel(
    const int* __restrict__ esrc, const int* __restrict__ edst,
    int* __restrict__ off, int* __restrict__ srcs, int E, int rv)
{
    const int lo = (int)(blockIdx.x & 7) * rv;
    const int hi = lo + rv;
    const int base = (int)(blockIdx.x >> 3) << 10;
#pragma unroll
    for (int k = 0; k < 4; ++k) {
        int e = base + (k << 8) + threadIdx.x;
        if (e < E) {
            int d = __builtin_nontemporal_load(&edst[e]);
            if (d >= lo && d < hi) {
                int s = __builtin_nontemporal_load(&esrc[e]);
                int slot = atomicAdd(&off[d], 1);
                srcs[slot] = s;
            }
        }
    }
}

// ============== hierarchical exclusive scan ==============
__global__ __launch_bounds__(256) void scan1_kernel(
    const int* __restrict__ cnt, int* __restrict__ off, int* __restrict__ bsum, int V)
{
    __shared__ int lds[4096];
    __shared__ int ssum[256];
    const int t = threadIdx.x;
    const int base = blockIdx.x * 4096;
    for (int i = t; i < 4096; i += 256) {
        int g = base + i;
        lds[i] = (g < V) ? cnt[g] : 0;
    }
    __syncthreads();
    int loc[16];
    int s = 0;
#pragma unroll
    for (int k = 0; k < 16; ++k) { loc[k] = s; s += lds[t * 16 + k]; }
    ssum[t] = s;
    __syncthreads();
    for (int d = 1; d < 256; d <<= 1) {
        int v = (t >= d) ? ssum[t - d] : 0;
        __syncthreads();
        ssum[t] += v;
        __syncthreads();
    }
    const int tbase = (t == 0) ? 0 : ssum[t - 1];
    if (t == 255 && bsum) bsum[blockIdx.x] = ssum[255];
#pragma unroll
    for (int k = 0; k < 16; ++k) lds[t * 16 + k] = tbase + loc[k];
    __syncthreads();
    for (int i = t; i < 4096; i += 256) {
        int g = base + i;
        if (g < V) off[g] = lds[i];
    }
}

__global__ __launch_bounds__(256) void scan_add_kernel(
    int* __restrict__ off, const int* __restrict__ bso, int V)
{
    int g = blockIdx.x * 256 + threadIdx.x;
    if (g < V) off[g] += bso[g >> 12];
}

// ======================= bucketed CSR build (L1, L2) =======================
__global__ __launch_bounds__(256) void bin_count_kernel(
    const int* __restrict__ edst, int* __restrict__ gcnt, int E, int shift)
{
    __shared__ int h[256];
    const int t = threadIdx.x;
    h[t] = 0;
    __syncthreads();
    const int base = blockIdx.x << 12;
#pragma unroll
    for (int k = 0; k < 16; ++k) {
        int e = base + (k << 8) + t;
        if (e < E) {
            int d = __builtin_nontemporal_load(&edst[e]);
            atomicAdd(&h[d >> shift], 1);
        }
    }
    __syncthreads();
    if (h[t]) atomicAdd(&gcnt[t], h[t]);
}

__global__ __launch_bounds__(256) void bin_scatter_kernel(
    const int* __restrict__ esrc, const int* __restrict__ edst,
    int* __restrict__ gcur, int* __restrict__ stD, int* __restrict__ stS,
    int E, int shift)
{
    __shared__ int d_l[4096];
    __shared__ int s_l[4096];
    __shared__ int h[256];
    __shared__ int rbase[256];
    const int t = threadIdx.x;
    h[t] = 0;
    __syncthreads();
    const int base = blockIdx.x << 12;
#pragma unroll
    for (int k = 0; k < 16; ++k) {
        int i = (k << 8) + t;
        int e = base + i;
        if (e < E) {
            int d = __builtin_nontemporal_load(&edst[e]);
            int s = __builtin_nontemporal_load(&esrc[e]);
            d_l[i] = d; s_l[i] = s;
            atomicAdd(&h[d >> shift], 1);
        }
    }
    __syncthreads();
    rbase[t] = h[t] ? atomicAdd(&gcur[t], h[t]) : 0;
    h[t] = 0;   // reuse as cursor
    __syncthreads();
#pragma unroll
    for (int k = 0; k < 16; ++k) {
        int i = (k << 8) + t;
        int e = base + i;
        if (e < E) {
            int d = d_l[i];
            int b = d >> shift;
            int r = atomicAdd(&h[b], 1);
            int pos = rbase[b] + r;
            stD[pos] = d;
            stS[pos] = s_l[i];
        }
    }
}

__global__ __launch_bounds__(1024) void bucket_csr_kernel(
    const int* __restrict__ gcur, const int* __restrict__ gcnt,
    const int* __restrict__ stD, const int* __restrict__ stS,
    int* __restrict__ cnt, int* __restrict__ off, int* __restrict__ srcs,
    int V, int shift)
{
    __shared__ int h[2048];
    __shared__ int o[2048];
    __shared__ int ps[1024];
    const int t = threadIdx.x;
    const int b = blockIdx.x;
    const int v0 = b << shift;
    const int nv = min(1 << shift, V - v0);
    const int s1 = gcur[b];
    const int s0 = s1 - gcnt[b];
    h[t] = 0; h[t + 1024] = 0;
    __syncthreads();
    for (int i = s0 + t; i < s1; i += 1024)
        atomicAdd(&h[stD[i] - v0], 1);
    __syncthreads();
    int a = h[2 * t], b2 = h[2 * t + 1];
    ps[t] = a + b2;
    __syncthreads();
    for (int d = 1; d < 1024; d <<= 1) {
        int v = (t >= d) ? ps[t - d] : 0;
        __syncthreads();
        ps[t] += v;
        __syncthreads();
    }
    int pb = (t == 0) ? 0 : ps[t - 1];
    o[2 * t] = pb;
    o[2 * t + 1] = pb + a;
    __syncthreads();
    for (int i = t; i < nv; i += 1024) {
        int hv = h[i];
        cnt[v0 + i] = hv;
        off[v0 + i] = s0 + o[i] + hv;   // segment END convention
    }
    __syncthreads();
    for (int i = s0 + t; i < s1; i += 1024) {
        int d = stD[i];
        int r = atomicAdd(&o[d - v0], 1);
        srcs[s0 + r] = stS[i];
    }
}

// ======================= pack (x, pos) into float4 for layer-1 gathers =======
__global__ __launch_bounds__(256) void pack_xpos_kernel(
    const float* __restrict__ x, const float* __restrict__ pos,
    float4* __restrict__ xp, int V)
{
    int n = blockIdx.x * 256 + threadIdx.x;
    if (n >= V) return;
    xp[n] = make_float4(x[n], pos[n * 3 + 0], pos[n * 3 + 1], pos[n * 3 + 2]);
}

// ========== Layer-1 fused, tsum formulation: one THREAD per node ==========
__global__ __launch_bounds__(256) void l1_fused_kernel(
    const int* __restrict__ off, const int* __restrict__ cnt, const int* __restrict__ srcs,
    const float4* __restrict__ xp,
    const float* __restrict__ Wk, const float* __restrict__ Wr,
    const float* __restrict__ bias, float* __restrict__ out,
    float inv2mv, int V)
{
    __shared__ float sWk[384];
    __shared__ float sWr[48];
    __shared__ float sB[16];
    const int t = threadIdx.x;
    for (int i = t; i < 384; i += 256) sWk[i] = Wk[i];
    if (t < 48) sWr[t] = Wr[t];
    if (t < 16) sB[t] = bias[t];
    __syncthreads();
    const int v = blockIdx.x * 256 + t;
    if (v >= V) return;
    const float4 d = xp[v];  // x, px, py, pt
    const int e1 = off[v];
    const int n = cnt[v];
    float ts[8][3];
#pragma unroll
    for (int s8 = 0; s8 < 8; ++s8) { ts[s8][0] = 0.f; ts[s8][1] = 0.f; ts[s8][2] = 0.f; }
    for (int j = e1 - n; j < e1; ++j) {
        float4 a = xp[srcs[j]];
        float p0 = clamp01f((d.y - a.y) * inv2mv + 0.5f);
        float p1 = clamp01f((d.z - a.z) * inv2mv + 0.5f);
        float p2 = clamp01f((d.w - a.w) * inv2mv + 0.5f);
        float q0 = 1.f - p0, q1 = 1.f - p1, q2 = 1.f - p2;
#pragma unroll
        for (int s8 = 0; s8 < 8; ++s8) {
            float bs = ((s8 & 1) ? p0 : q0) * ((s8 & 2) ? p1 : q1) * ((s8 & 4) ? p2 : q2);
            ts[s8][0] += bs * a.x;
            ts[s8][1] += bs * a.y;
            ts[s8][2] += bs * a.z;
        }
    }
    const float invn = 1.0f / fmaxf((float)n, 1.0f);
    float rr[16];
#pragma unroll
    for (int c = 0; c < 16; ++c) {
        float m = 0.f;
#pragma unroll
        for (int s8 = 0; s8 < 8; ++s8)
            m += ts[s8][0] * sWk[s8 * 48 + c]
               + ts[s8][1] * sWk[s8 * 48 + 16 + c]
               + ts[s8][2] * sWk[s8 * 48 + 32 + c];
        float r = m * invn + d.x * sWr[c] + d.y * sWr[16 + c] + d.z * sWr[32 + c] + sB[c];
        rr[c] = fmaxf(r, 0.0f);
    }
    float4* op = (float4*)(out + (size_t)v * 16);
#pragma unroll
    for (int k = 0; k < 4; ++k)
        op[k] = make_float4(rr[4 * k], rr[4 * k + 1], rr[4 * k + 2], rr[4 * k + 3]);
}

// ========== Generic tsum layer (L2-5): wave-per-node gather + batched contraction ====
// agg[c] = sum_{s8,ci} T[s8][ci]*Wk[s8,ci,c];  T = sum_edges basis (x) hcat[src].
// hcat = [feat(CINF) | pos.x | pos.y].  Slice 9 of tsum holds hcat[v] for the Wr term.
// Per-edge traffic: CINF*4+12 B (vs 4KB z-row).  Wk/Wr read from L2, amortized over NV nodes.
template<int CINF, int COUT, int NV, int NW>
__global__ __launch_bounds__(64 * NW) void tsum_layer_kernel(
    const int* __restrict__ off, const int* __restrict__ cnt, const int* __restrict__ srcs,
    const float* __restrict__ pos, const float* __restrict__ feat,
    const float* __restrict__ Wk, const float* __restrict__ Wr,
    const float* __restrict__ bias, float* __restrict__ out,
    float inv2mv, int V)
{
    constexpr int CIN = CINF + 2;
    constexpr int NCI = (CIN + 63) / 64;   // ci chunks per lane
    constexpr int NCC = COUT / 64;         // c per lane
    __shared__ float tsum[NW][NV][CIN][9];
    const int tid = threadIdx.x;
    const int w = tid >> 6, lane = tid & 63;
    const int vbase = (blockIdx.x * NW + w) * NV;

    // ---- gather: accumulate T in registers, dump to LDS ----
    for (int b = 0; b < NV; ++b) {
        const int v = vbase + b;
        if (v >= V) break;
        const float pdx = pos[v * 3 + 0], pdy = pos[v * 3 + 1], pdt = pos[v * 3 + 2];
        float acc[NCI][8];
#pragma unroll
        for (int k = 0; k < NCI; ++k)
#pragma unroll
            for (int s8 = 0; s8 < 8; ++s8) acc[k][s8] = 0.f;
        const int e1 = off[v];
        for (int j = e1 - cnt[v]; j < e1; ++j) {
            const int s = srcs[j];
            const float sx = pos[s * 3 + 0], sy = pos[s * 3 + 1], st = pos[s * 3 + 2];
            float p0 = clamp01f((pdx - sx) * inv2mv + 0.5f);
            float p1 = clamp01f((pdy - sy) * inv2mv + 0.5f);
            float p2 = clamp01f((pdt - st) * inv2mv + 0.5f);
            float q0 = 1.f - p0, q1 = 1.f - p1, q2 = 1.f - p2;
            float bs[8];
#pragma unroll
            for (int s8 = 0; s8 < 8; ++s8)
                bs[s8] = ((s8 & 1) ? p0 : q0) * ((s8 & 2) ? p1 : q1) * ((s8 & 4) ? p2 : q2);
#pragma unroll
            for (int k = 0; k < NCI; ++k) {
                int ci = lane + 64 * k;
                if (ci < CIN) {
                    float f = (ci < CINF) ? feat[(size_t)s * CINF + ci]
                                          : (ci == CINF ? sx : sy);
#pragma unroll
                    for (int s8 = 0; s8 < 8; ++s8)
                        acc[k][s8] += bs[s8] * f;
                }
            }
        }
#pragma unroll
        for (int k = 0; k < NCI; ++k) {
            int ci = lane + 64 * k;
            if (ci < CIN) {
#pragma unroll
                for (int s8 = 0; s8 < 8; ++s8)
                    tsum[w][b][ci][s8] = acc[k][s8];
                tsum[w][b][ci][8] = (ci < CINF) ? feat[(size_t)v * CINF + ci]
                                                : (ci == CINF ? pdx : pdy);
            }
        }
    }
    __syncthreads();

    // ---- contraction: Wk (8 slices) -> oA; Wr -> oR; fused epilogue ----
    float oA[NV][NCC], oR[NV][NCC];
#pragma unroll
    for (int b = 0; b < NV; ++b)
#pragma unroll
        for (int cc = 0; cc < NCC; ++cc) { oA[b][cc] = 0.f; oR[b][cc] = 0.f; }
    for (int s8 = 0; s8 < 8; ++s8) {
        const float* W = Wk + (size_t)s8 * CIN * COUT;
        for (int ci = 0; ci < CIN; ++ci) {
            float wv[NCC];
#pragma unroll
            for (int cc = 0; cc < NCC; ++cc)
                wv[cc] = W[(size_t)ci * COUT + cc * 64 + lane];
#pragma unroll
            for (int b = 0; b < NV; ++b) {
                float tv = tsum[w][b][ci][s8];
#pragma unroll
                for (int cc = 0; cc < NCC; ++cc) oA[b][cc] += tv * wv[cc];
            }
        }
    }
    for (int ci = 0; ci < CIN; ++ci) {
        float wv[NCC];
#pragma unroll
        for (int cc = 0; cc < NCC; ++cc)
            wv[cc] = Wr[(size_t)ci * COUT + cc * 64 + lane];
#pragma unroll
        for (int b = 0; b < NV; ++b) {
            float tv = tsum[w][b][ci][8];
#pragma unroll
            for (int cc = 0; cc < NCC; ++cc) oR[b][cc] += tv * wv[cc];
        }
    }
    for (int b = 0; b < NV; ++b) {
        int v = vbase + b;
        if (v >= V) break;
        float invn = 1.0f / fmaxf((float)cnt[v], 1.0f);
#pragma unroll
        for (int cc = 0; cc < NCC; ++cc) {
            int c = cc * 64 + lane;
            out[(size_t)v * COUT + c] =
                fmaxf(oA[b][cc] * invn + oR[b][cc] + bias[c], 0.0f);
        }
    }
}

// ======================= voxel pooling: counting-sort + copy + sequential reduce =====
__global__ __launch_bounds__(256) void pool_cluster_kernel(
    const float* __restrict__ pos, const int* __restrict__ batch, int bdiv, int V,
    int nx, int ny, int nt, int* __restrict__ cl, int* __restrict__ cnt)
{
    int n = blockIdx.x * 256 + threadIdx.x;
    if (n >= V) return;
    int b = batch ? batch[n] : (n / bdiv);
    float px = pos[n * 3 + 0], py = pos[n * 3 + 1], pt = pos[n * 3 + 2];
    int ix = (int)floorf(px * (float)nx); ix = min(max(ix, 0), nx - 1);
    int iy = (int)floorf(py * (float)ny); iy = min(max(iy, 0), ny - 1);
    int it = (int)floorf(pt * (float)nt); it = min(max(it, 0), nt - 1);
    int c = ((b * nx + ix) * ny + iy) * nt + it;
    cl[n] = c;
    atomicAdd(&cnt[c], 1);
}

__global__ __launch_bounds__(256) void pool_scatter_kernel(
    const int* __restrict__ cl, int* __restrict__ off, int* __restrict__ order, int V, int rv)
{
    const int lo = (int)(blockIdx.x & 7) * rv;
    const int hi = lo + rv;
    const int base = (int)(blockIdx.x >> 3) << 10;
#pragma unroll
    for (int k = 0; k < 4; ++k) {
        int n = base + (k << 8) + threadIdx.x;
        if (n < V) {
            int c = __builtin_nontemporal_load(&cl[n]);
            if (c >= lo && c < hi) {
                int slot = atomicAdd(&off[c], 1);
                order[slot] = n;
            }
        }
    }
}

template<int COUT>
__global__ __launch_bounds__(256) void pool_copy_kernel(
    const int* __restrict__ order, const float* __restrict__ h,
    const float* __restrict__ pos,
    float* __restrict__ S, float* __restrict__ Spos, int V)
{
    int g = blockIdx.x * 256 + threadIdx.x;
    if (g >= V * COUT) return;
    int slot = g / COUT;
    int c = g % COUT;
    int n = order[slot];
    S[g] = h[(size_t)n * COUT + c];
    if (c < 3) Spos[slot * 3 + c] = pos[n * 3 + c];
}

template<int COUT, int DOMEAN>
__global__ __launch_bounds__(256) void pool_reduce_kernel(
    const int* __restrict__ off, const int* __restrict__ cnt,
    const float* __restrict__ S, const float* __restrict__ Spos,
    float* __restrict__ hnext, float* __restrict__ pos_out, int Vc)
{
    const int g = blockIdx.x * 256 + threadIdx.x;
    if (g >= Vc * COUT) return;
    const int v = g / COUT;
    const int c = g % COUT;
    const int e1 = off[v];
    const int n0 = e1 - cnt[v];
    float acc = 0.0f;
    float ps = 0.0f;
    int j = n0;
    for (; j + 3 < e1; j += 4) {
        float a0 = S[(size_t)(j + 0) * COUT + c];
        float a1 = S[(size_t)(j + 1) * COUT + c];
        float a2 = S[(size_t)(j + 2) * COUT + c];
        float a3 = S[(size_t)(j + 3) * COUT + c];
        if (DOMEAN) acc += (a0 + a1) + (a2 + a3);
        else        acc = fmaxf(acc, fmaxf(fmaxf(a0, a1), fmaxf(a2, a3)));
        if (c < 3) {
            float p0 = Spos[(j + 0) * 3 + c];
            float p1 = Spos[(j + 1) * 3 + c];
            float p2 = Spos[(j + 2) * 3 + c];
            float p3 = Spos[(j + 3) * 3 + c];
            ps += (p0 + p1) + (p2 + p3);
        }
    }
    for (; j < e1; ++j) {
        float a0 = S[(size_t)j * COUT + c];
        acc = DOMEAN ? (acc + a0) : fmaxf(acc, a0);
        if (c < 3) ps += Spos[j * 3 + c];
    }
    float m = fmaxf((float)cnt[v], 1.0f);
    hnext[(size_t)v * COUT + c] = DOMEAN ? (acc / m) : acc;
    if (c < 3) pos_out[v * 3 + c] = ps / m;
}

// ======================= host =======================
extern "C" void kernel_launch(void* const* d_in, const int* in_sizes, int n_in,
                              void* d_out, int out_size, void* d_ws, size_t ws_size,
                              hipStream_t stream)
{
    (void)in_sizes; (void)n_in; (void)out_size;
    const float* x    = (const float*)d_in[0];
    const float* pos0 = (const float*)d_in[1];
    const int*   bat  = (const int*)d_in[2];
    const int* e1 = (const int*)d_in[3];
    const int* e2 = (const int*)d_in[4];
    const int* e3 = (const int*)d_in[5];
    const int* e4 = (const int*)d_in[6];
    const int* e5 = (const int*)d_in[7];
    const float* W1 = (const float*)d_in[8],  *R1 = (const float*)d_in[9],  *B1 = (const float*)d_in[10];
    const float* W2 = (const float*)d_in[11], *R2 = (const float*)d_in[12], *B2 = (const float*)d_in[13];
    const float* W3 = (const float*)d_in[14], *R3 = (const float*)d_in[15], *B3 = (const float*)d_in[16];
    const float* W4 = (const float*)d_in[17], *R4 = (const float*)d_in[18], *B4 = (const float*)d_in[19];
    const float* W5 = (const float*)d_in[20], *R5 = (const float*)d_in[21], *B5 = (const float*)d_in[22];

    const int E1 = 3600000, E2 = 786432, E3 = 196608, E4 = 24576, E5 = 3072;

    if (ws_size < (size_t)21800000 * sizeof(float)) return;
    float* ws = (float*)d_ws;
    // pools (floats): P0 12.6M (staging / pool scratch) | P1 6.3M (layer out)
    //                 P2 1.6M (pooled feat in) | P3 1.0M ints (CSR L2-5) | P4 0.3M (pos)
    float* P0 = ws;
    float* P1 = ws + 12600000;
    float* P2 = ws + 18900000;
    int*   P3 = (int*)(ws + 20500000);
    float* P4 = ws + 21500000;
    int* GCNT   = P3 + 990000;   // 256 ints (bucket counts)
    int* GCUR   = P3 + 990256;   // 256 ints (bucket cursors / bases)
    int* SCR_BS = P3 + 999744;   // pool-scan block sums
    int* SCR_BO = SCR_BS + 96;

    float* out3 = (float*)d_out;           // 1536*128
    float* hfin = (float*)d_out + 196608;  // 192*128

#define MSI(p, ni) hipMemsetAsync((p), 0, (size_t)(ni) * sizeof(int), stream)

#define SCAN(cntp, offp, Vn)                                                                     \
    {                                                                                            \
        int nb_ = ((Vn) + 4095) / 4096;                                                          \
        if (nb_ <= 1) {                                                                          \
            scan1_kernel<<<1, 256, 0, stream>>>((cntp), (offp), nullptr, (Vn));                  \
        } else {                                                                                 \
            scan1_kernel<<<nb_, 256, 0, stream>>>((cntp), (offp), SCR_BS, (Vn));                 \
            scan1_kernel<<<1, 256, 0, stream>>>(SCR_BS, SCR_BO, nullptr, nb_);                   \
            scan_add_kernel<<<((Vn) + 255) / 256, 256, 0, stream>>>((offp), SCR_BO, (Vn));       \
        }                                                                                        \
    }

#define BSORT(cntP, offP, srcP, stD, stS, ep, En, Vn, SHIFT, NB)                                 \
    {                                                                                            \
        MSI(GCNT, 256);                                                                          \
        bin_count_kernel<<<((En) + 4095) / 4096, 256, 0, stream>>>((ep) + (En), GCNT, En, SHIFT);\
        scan1_kernel<<<1, 256, 0, stream>>>(GCNT, GCUR, nullptr, NB);                            \
        bin_scatter_kernel<<<((En) + 4095) / 4096, 256, 0, stream>>>(                            \
            (ep), (ep) + (En), GCUR, stD, stS, En, SHIFT);                                       \
        bucket_csr_kernel<<<NB, 1024, 0, stream>>>(                                              \
            GCUR, GCNT, stD, stS, cntP, offP, srcP, Vn, SHIFT);                                  \
    }

#define ESORT(base, ep, En, Vn)                                                                  \
    int* cnt_ = (base);                                                                          \
    int* off_ = cnt_ + (Vn);                                                                     \
    int* src_ = off_ + (Vn);                                                                     \
    MSI(cnt_, (Vn));                                                                             \
    edge_count_kernel<<<((En) + 255) / 256, 256, 0, stream>>>((ep) + (En), cnt_, En);            \
    SCAN(cnt_, off_, (Vn));                                                                      \
    edge_scatter_kernel<<<8 * (((En) + 1023) / 1024), 256, 0, stream>>>(                         \
        (ep), (ep) + (En), off_, src_, En, (Vn) >> 3)

#define POOL(SB, hsrc, possrc, batp, bdiv, Vn, NX, NY, NT, COUTV, DM, hdst, posdst)         \
    {                                                                                       \
        int Vc = 4 * (NX) * (NY) * (NT);                                                    \
        float* SF   = (SB);                                                                 \
        float* SPOS = SF + (size_t)(Vn) * (COUTV);                                          \
        int* ICL  = (int*)(SPOS + (size_t)(Vn) * 3);                                        \
        int* IORD = ICL + (Vn);                                                             \
        int* ICNT = IORD + (Vn);                                                            \
        int* IOFF = ICNT + Vc;                                                              \
        MSI(ICNT, Vc);                                                                      \
        pool_cluster_kernel<<<((Vn) + 255) / 256, 256, 0, stream>>>(                        \
            possrc, batp, bdiv, Vn, NX, NY, NT, ICL, ICNT);                                 \
        SCAN(ICNT, IOFF, Vc);                                                               \
        pool_scatter_kernel<<<8 * (((Vn) + 1023) / 1024), 256, 0, stream>>>(                \
            ICL, IOFF, IORD, Vn, Vc >> 3);                                                  \
        pool_copy_kernel<COUTV><<<((size_t)(Vn) * (COUTV) + 255) / 256, 256, 0, stream>>>(  \
            IORD, hsrc, possrc, SF, SPOS, Vn);                                              \
        pool_reduce_kernel<COUTV, DM><<<((size_t)Vc * (COUTV) + 255) / 256, 256, 0,         \
            stream>>>(IOFF, ICNT, SF, SPOS, hdst, posdst, Vc);                              \
    }

    // ---------- Layer 1: 300000 nodes, CIN=3, COUT=16 ----------
    {
        int* cnt1 = (int*)P0;
        int* off1 = cnt1 + 300000;
        int* src1 = off1 + 300000;
        int* stD  = src1 + 3600000;
        int* stS  = stD + 3600000;
        float4* xp4 = (float4*)(P0 + 11400000);
        BSORT(cnt1, off1, src1, stD, stS, e1, E1, 300000, 11, 147);
        pack_xpos_kernel<<<(300000 + 255) / 256, 256, 0, stream>>>(x, pos0, xp4, 300000);
        l1_fused_kernel<<<(300000 + 255) / 256, 256, 0, stream>>>(
            off1, cnt1, src1, xp4, W1, R1, B1, P1, 20.0f, 300000);
        // CSR + staging + xp4 dead -> pool scratch at P0. h1 (stride 16) -> P2, pos2 -> P4.
        POOL(P0, P1, pos0, bat, 0, 300000, 64, 48, 8, 16, 0, P2, P4);
    }
    // ---------- Layer 2: 98304 nodes, CINF=16, COUT=64 (tsum path) ----------
    {
        int* cnt2 = P3;
        int* off2 = cnt2 + 98304;
        int* src2 = off2 + 98304;
        int* stD  = (int*)P0;
        int* stS  = stD + E2;
        BSORT(cnt2, off2, src2, stD, stS, e2, E2, 98304, 10, 96);
        tsum_layer_kernel<16, 64, 8, 4><<<98304 / 32, 256, 0, stream>>>(
            off2, cnt2, src2, P4, P2, W2, R2, B2, P1, 10.0f, 98304);
        POOL(P0, P1, P4, nullptr, 24576, 98304, 32, 24, 4, 64, 0, P2, P4);
    }
    // ---------- Layer 3: 12288 nodes, CINF=64, COUT=128 (tsum path) ----------
    {
        ESORT(P3, e3, E3, 12288);
        tsum_layer_kernel<64, 128, 4, 4><<<12288 / 16, 256, 0, stream>>>(
            off_, cnt_, src_, P4, P2, W3, R3, B3, P1, 6.0f, 12288);
        POOL(P0, P1, P4, nullptr, 3072, 12288, 16, 12, 2, 128, 0, P2, P4);
    }
    // ---------- Layer 4: 1536 nodes, CINF=128, COUT=128 -> out3 ----------
    {
        ESORT(P3, e4, E4, 1536);
        tsum_layer_kernel<128, 128, 2, 4><<<1536 / 8, 256, 0, stream>>>(
            off_, cnt_, src_, P4, P2, W4, R4, B4, out3, 3.0f, 1536);
        POOL(P0, out3, P4, nullptr, 384, 1536, 8, 6, 1, 128, 1, P2, P4);
    }
    // ---------- Layer 5: 192 nodes, CINF=128, COUT=128 -> hfin ----------
    {
        ESORT(P3, e5, E5, 192);
        tsum_layer_kernel<128, 128, 2, 4><<<192 / 8, 256, 0, stream>>>(
            off_, cnt_, src_, P4, P2, W5, R5, B5, hfin, 1.5f, 192);
    }
#undef POOL
#undef ESORT
#undef BSORT
#undef SCAN
#undef MSI
}

// Round 9
// 1041.232 us; speedup vs baseline: 2.7384x; 1.1264x over previous
//
#include <hip/hip_runtime.h>
#include <cstdint>

__device__ __forceinline__ float clamp01f(float v) { return fminf(fmaxf(v, 0.0f), 1.0f); }

// ======================= legacy CSR build (layers 3-5, small E) =======================
__global__ __launch_bounds__(256) void edge_count_kernel(
    const int* __restrict__ edst, int* __restrict__ cnt, int E)
{
    int e = blockIdx.x * 256 + threadIdx.x;
    if (e < E) atomicAdd(&cnt[__builtin_nontemporal_load(&edst[e])], 1);
}

__global__ __launch_bounds__(256) void edge_scatter_kernel(
    const int* __restrict__ esrc, const int* __restrict__ edst,
    int* __restrict__ off, int* __restrict__ srcs, int E, int rv)
{
    const int lo = (int)(blockIdx.x & 7) * rv;
    const int hi = lo + rv;
    const int base = (int)(blockIdx.x >> 3) << 10;
#pragma unroll
    for (int k = 0; k < 4; ++k) {
        int e = base + (k << 8) + threadIdx.x;
        if (e < E) {
            int d = __builtin_nontemporal_load(&edst[e]);
            if (d >= lo && d < hi) {
                int s = __builtin_nontemporal_load(&esrc[e]);
                int slot = atomicAdd(&off[d], 1);
                srcs[slot] = s;
            }
        }
    }
}

// ============== hierarchical exclusive scan ==============
__global__ __launch_bounds__(256) void scan1_kernel(
    const int* __restrict__ cnt, int* __restrict__ off, int* __restrict__ bsum, int V)
{
    __shared__ int lds[4096];
    __shared__ int ssum[256];
    const int t = threadIdx.x;
    const int base = blockIdx.x * 4096;
    for (int i = t; i < 4096; i += 256) {
        int g = base + i;
        lds[i] = (g < V) ? cnt[g] : 0;
    }
    __syncthreads();
    int loc[16];
    int s = 0;
#pragma unroll
    for (int k = 0; k < 16; ++k) { loc[k] = s; s += lds[t * 16 + k]; }
    ssum[t] = s;
    __syncthreads();
    for (int d = 1; d < 256; d <<= 1) {
        int v = (t >= d) ? ssum[t - d] : 0;
        __syncthreads();
        ssum[t] += v;
        __syncthreads();
    }
    const int tbase = (t == 0) ? 0 : ssum[t - 1];
    if (t == 255 && bsum) bsum[blockIdx.x] = ssum[255];
#pragma unroll
    for (int k = 0; k < 16; ++k) lds[t * 16 + k] = tbase + loc[k];
    __syncthreads();
    for (int i = t; i < 4096; i += 256) {
        int g = base + i;
        if (g < V) off[g] = lds[i];
    }
}

__global__ __launch_bounds__(256) void scan_add_kernel(
    int* __restrict__ off, const int* __restrict__ bso, int V)
{
    int g = blockIdx.x * 256 + threadIdx.x;
    if (g < V) off[g] += bso[g >> 12];
}

// ======================= bucketed CSR build (L1, L2) =======================
__global__ __launch_bounds__(256) void bin_count_kernel(
    const int* __restrict__ edst, int* __restrict__ gcnt, int E, int shift)
{
    __shared__ int h[256];
    const int t = threadIdx.x;
    h[t] = 0;
    __syncthreads();
    const int base = blockIdx.x << 12;
#pragma unroll
    for (int k = 0; k < 16; ++k) {
        int e = base + (k << 8) + t;
        if (e < E) {
            int d = __builtin_nontemporal_load(&edst[e]);
            atomicAdd(&h[d >> shift], 1);
        }
    }
    __syncthreads();
    if (h[t]) atomicAdd(&gcnt[t], h[t]);
}

__global__ __launch_bounds__(256) void bin_scatter_kernel(
    const int* __restrict__ esrc, const int* __restrict__ edst,
    int* __restrict__ gcur, int* __restrict__ stD, int* __restrict__ stS,
    int E, int shift)
{
    __shared__ int d_l[4096];
    __shared__ int s_l[4096];
    __shared__ int h[256];
    __shared__ int rbase[256];
    const int t = threadIdx.x;
    h[t] = 0;
    __syncthreads();
    const int base = blockIdx.x << 12;
#pragma unroll
    for (int k = 0; k < 16; ++k) {
        int i = (k << 8) + t;
        int e = base + i;
        if (e < E) {
            int d = __builtin_nontemporal_load(&edst[e]);
            int s = __builtin_nontemporal_load(&esrc[e]);
            d_l[i] = d; s_l[i] = s;
            atomicAdd(&h[d >> shift], 1);
        }
    }
    __syncthreads();
    rbase[t] = h[t] ? atomicAdd(&gcur[t], h[t]) : 0;
    h[t] = 0;   // reuse as cursor
    __syncthreads();
#pragma unroll
    for (int k = 0; k < 16; ++k) {
        int i = (k << 8) + t;
        int e = base + i;
        if (e < E) {
            int d = d_l[i];
            int b = d >> shift;
            int r = atomicAdd(&h[b], 1);
            int pos = rbase[b] + r;
            stD[pos] = d;
            stS[pos] = s_l[i];
        }
    }
}

__global__ __launch_bounds__(1024) void bucket_csr_kernel(
    const int* __restrict__ gcur, const int* __restrict__ gcnt,
    const int* __restrict__ stD, const int* __restrict__ stS,
    int* __restrict__ cnt, int* __restrict__ off, int* __restrict__ srcs,
    int V, int shift)
{
    __shared__ int h[2048];
    __shared__ int o[2048];
    __shared__ int ps[1024];
    const int t = threadIdx.x;
    const int b = blockIdx.x;
    const int v0 = b << shift;
    const int nv = min(1 << shift, V - v0);
    const int s1 = gcur[b];
    const int s0 = s1 - gcnt[b];
    h[t] = 0; h[t + 1024] = 0;
    __syncthreads();
    for (int i = s0 + t; i < s1; i += 1024)
        atomicAdd(&h[stD[i] - v0], 1);
    __syncthreads();
    int a = h[2 * t], b2 = h[2 * t + 1];
    ps[t] = a + b2;
    __syncthreads();
    for (int d = 1; d < 1024; d <<= 1) {
        int v = (t >= d) ? ps[t - d] : 0;
        __syncthreads();
        ps[t] += v;
        __syncthreads();
    }
    int pb = (t == 0) ? 0 : ps[t - 1];
    o[2 * t] = pb;
    o[2 * t + 1] = pb + a;
    __syncthreads();
    for (int i = t; i < nv; i += 1024) {
        int hv = h[i];
        cnt[v0 + i] = hv;
        off[v0 + i] = s0 + o[i] + hv;   // segment END convention
    }
    __syncthreads();
    for (int i = s0 + t; i < s1; i += 1024) {
        int d = stD[i];
        int r = atomicAdd(&o[d - v0], 1);
        srcs[s0 + r] = stS[i];
    }
}

// ======================= pack (x, pos) into float4 for layer-1 gathers =======
__global__ __launch_bounds__(256) void pack_xpos_kernel(
    const float* __restrict__ x, const float* __restrict__ pos,
    float4* __restrict__ xp, int V)
{
    int n = blockIdx.x * 256 + threadIdx.x;
    if (n >= V) return;
    xp[n] = make_float4(x[n], pos[n * 3 + 0], pos[n * 3 + 1], pos[n * 3 + 2]);
}

// ========== Layer-1 fused, tsum formulation: one THREAD per node ==========
__global__ __launch_bounds__(256) void l1_fused_kernel(
    const int* __restrict__ off, const int* __restrict__ cnt, const int* __restrict__ srcs,
    const float4* __restrict__ xp,
    const float* __restrict__ Wk, const float* __restrict__ Wr,
    const float* __restrict__ bias, float* __restrict__ out,
    float inv2mv, int V)
{
    __shared__ float sWk[384];
    __shared__ float sWr[48];
    __shared__ float sB[16];
    const int t = threadIdx.x;
    for (int i = t; i < 384; i += 256) sWk[i] = Wk[i];
    if (t < 48) sWr[t] = Wr[t];
    if (t < 16) sB[t] = bias[t];
    __syncthreads();
    const int v = blockIdx.x * 256 + t;
    if (v >= V) return;
    const float4 d = xp[v];  // x, px, py, pt
    const int e1 = off[v];
    const int n = cnt[v];
    float ts[8][3];
#pragma unroll
    for (int s8 = 0; s8 < 8; ++s8) { ts[s8][0] = 0.f; ts[s8][1] = 0.f; ts[s8][2] = 0.f; }
    for (int j = e1 - n; j < e1; ++j) {
        float4 a = xp[srcs[j]];
        float p0 = clamp01f((d.y - a.y) * inv2mv + 0.5f);
        float p1 = clamp01f((d.z - a.z) * inv2mv + 0.5f);
        float p2 = clamp01f((d.w - a.w) * inv2mv + 0.5f);
        float q0 = 1.f - p0, q1 = 1.f - p1, q2 = 1.f - p2;
#pragma unroll
        for (int s8 = 0; s8 < 8; ++s8) {
            float bs = ((s8 & 1) ? p0 : q0) * ((s8 & 2) ? p1 : q1) * ((s8 & 4) ? p2 : q2);
            ts[s8][0] += bs * a.x;
            ts[s8][1] += bs * a.y;
            ts[s8][2] += bs * a.z;
        }
    }
    const float invn = 1.0f / fmaxf((float)n, 1.0f);
    float rr[16];
#pragma unroll
    for (int c = 0; c < 16; ++c) {
        float m = 0.f;
#pragma unroll
        for (int s8 = 0; s8 < 8; ++s8)
            m += ts[s8][0] * sWk[s8 * 48 + c]
               + ts[s8][1] * sWk[s8 * 48 + 16 + c]
               + ts[s8][2] * sWk[s8 * 48 + 32 + c];
        float r = m * invn + d.x * sWr[c] + d.y * sWr[16 + c] + d.z * sWr[32 + c] + sB[c];
        rr[c] = fmaxf(r, 0.0f);
    }
    float4* op = (float4*)(out + (size_t)v * 16);
#pragma unroll
    for (int k = 0; k < 4; ++k)
        op[k] = make_float4(rr[4 * k], rr[4 * k + 1], rr[4 * k + 2], rr[4 * k + 3]);
}

// ========== Layer-2 tsum, QUARTER-WAVE-per-node: 4 nodes/wave concurrent ==========
// Lane layout: wave = 4 quarters; quarter q owns node vbase+q; lane l16 owns ci=l16
// (features), lanes 0/1 additionally own ci=16/17 (src pos channels).
// 4 independent gather chains per wave; coalesced 64B feature reads per quarter.
template<int NW>
__global__ __launch_bounds__(64 * NW) void tsum16_layer_kernel(
    const int* __restrict__ off, const int* __restrict__ cnt, const int* __restrict__ srcs,
    const float* __restrict__ pos, const float* __restrict__ feat,
    const float* __restrict__ Wk, const float* __restrict__ Wr,
    const float* __restrict__ bias, float* __restrict__ out,
    float inv2mv, int V)
{
    __shared__ float tsum[NW][4][18][9];
    const int tid = threadIdx.x;
    const int w = tid >> 6, lane = tid & 63;
    const int q = lane >> 4, l16 = lane & 15;
    const int vbase = (blockIdx.x * NW + w) * 4;
    const int v = vbase + q;        // V = 98304 divisible by 4*NW -> always < V

    // ---- gather: 4 nodes per wave, one per quarter ----
    const float pdx = pos[v * 3 + 0], pdy = pos[v * 3 + 1], pdt = pos[v * 3 + 2];
    const int e1 = off[v];
    const int n = cnt[v];
    float accF[8], accP[8];
#pragma unroll
    for (int s8 = 0; s8 < 8; ++s8) { accF[s8] = 0.f; accP[s8] = 0.f; }
    for (int j = e1 - n; j < e1; ++j) {
        const int s = srcs[j];
        const float sx = pos[s * 3 + 0], sy = pos[s * 3 + 1], st = pos[s * 3 + 2];
        float p0 = clamp01f((pdx - sx) * inv2mv + 0.5f);
        float p1 = clamp01f((pdy - sy) * inv2mv + 0.5f);
        float p2 = clamp01f((pdt - st) * inv2mv + 0.5f);
        float q0 = 1.f - p0, q1 = 1.f - p1, q2 = 1.f - p2;
        const float f  = feat[(size_t)s * 16 + l16];
        const float fp = (l16 == 0) ? sx : ((l16 == 1) ? sy : 0.f);
#pragma unroll
        for (int s8 = 0; s8 < 8; ++s8) {
            float bs = ((s8 & 1) ? p0 : q0) * ((s8 & 2) ? p1 : q1) * ((s8 & 4) ? p2 : q2);
            accF[s8] += bs * f;
            accP[s8] += bs * fp;
        }
    }
#pragma unroll
    for (int s8 = 0; s8 < 8; ++s8)
        tsum[w][q][l16][s8] = accF[s8];
    tsum[w][q][l16][8] = feat[(size_t)v * 16 + l16];
    if (l16 < 2) {
#pragma unroll
        for (int s8 = 0; s8 < 8; ++s8)
            tsum[w][q][16 + l16][s8] = accP[s8];
        tsum[w][q][16 + l16][8] = (l16 == 0) ? pdx : pdy;
    }
    __syncthreads();

    // ---- contraction: lanes own c = lane (COUT=64); NV=4 nodes per wave ----
    float oA[4], oR[4];
#pragma unroll
    for (int b = 0; b < 4; ++b) { oA[b] = 0.f; oR[b] = 0.f; }
    for (int s8 = 0; s8 < 8; ++s8) {
        const float* W = Wk + (size_t)s8 * 18 * 64;
        for (int ci = 0; ci < 18; ++ci) {
            float wv = W[(size_t)ci * 64 + lane];
#pragma unroll
            for (int b = 0; b < 4; ++b)
                oA[b] += tsum[w][b][ci][s8] * wv;
        }
    }
    for (int ci = 0; ci < 18; ++ci) {
        float wv = Wr[(size_t)ci * 64 + lane];
#pragma unroll
        for (int b = 0; b < 4; ++b)
            oR[b] += tsum[w][b][ci][8] * wv;
    }
    const float bi = bias[lane];
#pragma unroll
    for (int b = 0; b < 4; ++b) {
        int vv = vbase + b;
        float invn = 1.0f / fmaxf((float)cnt[vv], 1.0f);
        out[(size_t)vv * 64 + lane] = fmaxf(oA[b] * invn + oR[b] + bi, 0.0f);
    }
}

// ========== Generic tsum layer (L3-5): wave-per-node gather + batched contraction ====
template<int CINF, int COUT, int NV, int NW>
__global__ __launch_bounds__(64 * NW) void tsum_layer_kernel(
    const int* __restrict__ off, const int* __restrict__ cnt, const int* __restrict__ srcs,
    const float* __restrict__ pos, const float* __restrict__ feat,
    const float* __restrict__ Wk, const float* __restrict__ Wr,
    const float* __restrict__ bias, float* __restrict__ out,
    float inv2mv, int V)
{
    constexpr int CIN = CINF + 2;
    constexpr int NCI = (CIN + 63) / 64;   // ci chunks per lane
    constexpr int NCC = COUT / 64;         // c per lane
    __shared__ float tsum[NW][NV][CIN][9];
    const int tid = threadIdx.x;
    const int w = tid >> 6, lane = tid & 63;
    const int vbase = (blockIdx.x * NW + w) * NV;

    for (int b = 0; b < NV; ++b) {
        const int v = vbase + b;
        if (v >= V) break;
        const float pdx = pos[v * 3 + 0], pdy = pos[v * 3 + 1], pdt = pos[v * 3 + 2];
        float acc[NCI][8];
#pragma unroll
        for (int k = 0; k < NCI; ++k)
#pragma unroll
            for (int s8 = 0; s8 < 8; ++s8) acc[k][s8] = 0.f;
        const int e1 = off[v];
        for (int j = e1 - cnt[v]; j < e1; ++j) {
            const int s = srcs[j];
            const float sx = pos[s * 3 + 0], sy = pos[s * 3 + 1], st = pos[s * 3 + 2];
            float p0 = clamp01f((pdx - sx) * inv2mv + 0.5f);
            float p1 = clamp01f((pdy - sy) * inv2mv + 0.5f);
            float p2 = clamp01f((pdt - st) * inv2mv + 0.5f);
            float q0 = 1.f - p0, q1 = 1.f - p1, q2 = 1.f - p2;
            float bs[8];
#pragma unroll
            for (int s8 = 0; s8 < 8; ++s8)
                bs[s8] = ((s8 & 1) ? p0 : q0) * ((s8 & 2) ? p1 : q1) * ((s8 & 4) ? p2 : q2);
#pragma unroll
            for (int k = 0; k < NCI; ++k) {
                int ci = lane + 64 * k;
                if (ci < CIN) {
                    float f = (ci < CINF) ? feat[(size_t)s * CINF + ci]
                                          : (ci == CINF ? sx : sy);
#pragma unroll
                    for (int s8 = 0; s8 < 8; ++s8)
                        acc[k][s8] += bs[s8] * f;
                }
            }
        }
#pragma unroll
        for (int k = 0; k < NCI; ++k) {
            int ci = lane + 64 * k;
            if (ci < CIN) {
#pragma unroll
                for (int s8 = 0; s8 < 8; ++s8)
                    tsum[w][b][ci][s8] = acc[k][s8];
                tsum[w][b][ci][8] = (ci < CINF) ? feat[(size_t)v * CINF + ci]
                                                : (ci == CINF ? pdx : pdy);
            }
        }
    }
    __syncthreads();

    float oA[NV][NCC], oR[NV][NCC];
#pragma unroll
    for (int b = 0; b < NV; ++b)
#pragma unroll
        for (int cc = 0; cc < NCC; ++cc) { oA[b][cc] = 0.f; oR[b][cc] = 0.f; }
    for (int s8 = 0; s8 < 8; ++s8) {
        const float* W = Wk + (size_t)s8 * CIN * COUT;
        for (int ci = 0; ci < CIN; ++ci) {
            float wv[NCC];
#pragma unroll
            for (int cc = 0; cc < NCC; ++cc)
                wv[cc] = W[(size_t)ci * COUT + cc * 64 + lane];
#pragma unroll
            for (int b = 0; b < NV; ++b) {
                float tv = tsum[w][b][ci][s8];
#pragma unroll
                for (int cc = 0; cc < NCC; ++cc) oA[b][cc] += tv * wv[cc];
            }
        }
    }
    for (int ci = 0; ci < CIN; ++ci) {
        float wv[NCC];
#pragma unroll
        for (int cc = 0; cc < NCC; ++cc)
            wv[cc] = Wr[(size_t)ci * COUT + cc * 64 + lane];
#pragma unroll
        for (int b = 0; b < NV; ++b) {
            float tv = tsum[w][b][ci][8];
#pragma unroll
            for (int cc = 0; cc < NCC; ++cc) oR[b][cc] += tv * wv[cc];
        }
    }
    for (int b = 0; b < NV; ++b) {
        int v = vbase + b;
        if (v >= V) break;
        float invn = 1.0f / fmaxf((float)cnt[v], 1.0f);
#pragma unroll
        for (int cc = 0; cc < NCC; ++cc) {
            int c = cc * 64 + lane;
            out[(size_t)v * COUT + c] =
                fmaxf(oA[b][cc] * invn + oR[b][cc] + bias[c], 0.0f);
        }
    }
}

// ======================= voxel pooling: counting-sort + copy + sequential reduce =====
__global__ __launch_bounds__(256) void pool_cluster_kernel(
    const float* __restrict__ pos, const int* __restrict__ batch, int bdiv, int V,
    int nx, int ny, int nt, int* __restrict__ cl, int* __restrict__ cnt)
{
    int n = blockIdx.x * 256 + threadIdx.x;
    if (n >= V) return;
    int b = batch ? batch[n] : (n / bdiv);
    float px = pos[n * 3 + 0], py = pos[n * 3 + 1], pt = pos[n * 3 + 2];
    int ix = (int)floorf(px * (float)nx); ix = min(max(ix, 0), nx - 1);
    int iy = (int)floorf(py * (float)ny); iy = min(max(iy, 0), ny - 1);
    int it = (int)floorf(pt * (float)nt); it = min(max(it, 0), nt - 1);
    int c = ((b * nx + ix) * ny + iy) * nt + it;
    cl[n] = c;
    atomicAdd(&cnt[c], 1);
}

__global__ __launch_bounds__(256) void pool_scatter_kernel(
    const int* __restrict__ cl, int* __restrict__ off, int* __restrict__ order, int V, int rv)
{
    const int lo = (int)(blockIdx.x & 7) * rv;
    const int hi = lo + rv;
    const int base = (int)(blockIdx.x >> 3) << 10;
#pragma unroll
    for (int k = 0; k < 4; ++k) {
        int n = base + (k << 8) + threadIdx.x;
        if (n < V) {
            int c = __builtin_nontemporal_load(&cl[n]);
            if (c >= lo && c < hi) {
                int slot = atomicAdd(&off[c], 1);
                order[slot] = n;
            }
        }
    }
}

template<int COUT>
__global__ __launch_bounds__(256) void pool_copy_kernel(
    const int* __restrict__ order, const float* __restrict__ h,
    const float* __restrict__ pos,
    float* __restrict__ S, float* __restrict__ Spos, int V)
{
    int g = blockIdx.x * 256 + threadIdx.x;
    if (g >= V * COUT) return;
    int slot = g / COUT;
    int c = g % COUT;
    int n = order[slot];
    S[g] = h[(size_t)n * COUT + c];
    if (c < 3) Spos[slot * 3 + c] = pos[n * 3 + c];
}

template<int COUT, int DOMEAN>
__global__ __launch_bounds__(256) void pool_reduce_kernel(
    const int* __restrict__ off, const int* __restrict__ cnt,
    const float* __restrict__ S, const float* __restrict__ Spos,
    float* __restrict__ hnext, float* __restrict__ pos_out, int Vc)
{
    const int g = blockIdx.x * 256 + threadIdx.x;
    if (g >= Vc * COUT) return;
    const int v = g / COUT;
    const int c = g % COUT;
    const int e1 = off[v];
    const int n0 = e1 - cnt[v];
    float acc = 0.0f;
    float ps = 0.0f;
    int j = n0;
    for (; j + 3 < e1; j += 4) {
        float a0 = S[(size_t)(j + 0) * COUT + c];
        float a1 = S[(size_t)(j + 1) * COUT + c];
        float a2 = S[(size_t)(j + 2) * COUT + c];
        float a3 = S[(size_t)(j + 3) * COUT + c];
        if (DOMEAN) acc += (a0 + a1) + (a2 + a3);
        else        acc = fmaxf(acc, fmaxf(fmaxf(a0, a1), fmaxf(a2, a3)));
        if (c < 3) {
            float p0 = Spos[(j + 0) * 3 + c];
            float p1 = Spos[(j + 1) * 3 + c];
            float p2 = Spos[(j + 2) * 3 + c];
            float p3 = Spos[(j + 3) * 3 + c];
            ps += (p0 + p1) + (p2 + p3);
        }
    }
    for (; j < e1; ++j) {
        float a0 = S[(size_t)j * COUT + c];
        acc = DOMEAN ? (acc + a0) : fmaxf(acc, a0);
        if (c < 3) ps += Spos[j * 3 + c];
    }
    float m = fmaxf((float)cnt[v], 1.0f);
    hnext[(size_t)v * COUT + c] = DOMEAN ? (acc / m) : acc;
    if (c < 3) pos_out[v * 3 + c] = ps / m;
}

// ======================= host =======================
extern "C" void kernel_launch(void* const* d_in, const int* in_sizes, int n_in,
                              void* d_out, int out_size, void* d_ws, size_t ws_size,
                              hipStream_t stream)
{
    (void)in_sizes; (void)n_in; (void)out_size;
    const float* x    = (const float*)d_in[0];
    const float* pos0 = (const float*)d_in[1];
    const int*   bat  = (const int*)d_in[2];
    const int* e1 = (const int*)d_in[3];
    const int* e2 = (const int*)d_in[4];
    const int* e3 = (const int*)d_in[5];
    const int* e4 = (const int*)d_in[6];
    const int* e5 = (const int*)d_in[7];
    const float* W1 = (const float*)d_in[8],  *R1 = (const float*)d_in[9],  *B1 = (const float*)d_in[10];
    const float* W2 = (const float*)d_in[11], *R2 = (const float*)d_in[12], *B2 = (const float*)d_in[13];
    const float* W3 = (const float*)d_in[14], *R3 = (const float*)d_in[15], *B3 = (const float*)d_in[16];
    const float* W4 = (const float*)d_in[17], *R4 = (const float*)d_in[18], *B4 = (const float*)d_in[19];
    const float* W5 = (const float*)d_in[20], *R5 = (const float*)d_in[21], *B5 = (const float*)d_in[22];

    const int E1 = 3600000, E2 = 786432, E3 = 196608, E4 = 24576, E5 = 3072;

    if (ws_size < (size_t)21800000 * sizeof(float)) return;
    float* ws = (float*)d_ws;
    // pools (floats): P0 12.6M (staging / pool scratch) | P1 6.3M (layer out)
    //                 P2 1.6M (pooled feat in) | P3 1.0M ints (CSR L2-5) | P4 0.3M (pos)
    float* P0 = ws;
    float* P1 = ws + 12600000;
    float* P2 = ws + 18900000;
    int*   P3 = (int*)(ws + 20500000);
    float* P4 = ws + 21500000;
    int* GCNT   = P3 + 990000;   // 256 ints (bucket counts)
    int* GCUR   = P3 + 990256;   // 256 ints (bucket cursors / bases)
    int* SCR_BS = P3 + 999744;   // pool-scan block sums
    int* SCR_BO = SCR_BS + 96;

    float* out3 = (float*)d_out;           // 1536*128
    float* hfin = (float*)d_out + 196608;  // 192*128

#define MSI(p, ni) hipMemsetAsync((p), 0, (size_t)(ni) * sizeof(int), stream)

#define SCAN(cntp, offp, Vn)                                                                     \
    {                                                                                            \
        int nb_ = ((Vn) + 4095) / 4096;                                                          \
        if (nb_ <= 1) {                                                                          \
            scan1_kernel<<<1, 256, 0, stream>>>((cntp), (offp), nullptr, (Vn));                  \
        } else {                                                                                 \
            scan1_kernel<<<nb_, 256, 0, stream>>>((cntp), (offp), SCR_BS, (Vn));                 \
            scan1_kernel<<<1, 256, 0, stream>>>(SCR_BS, SCR_BO, nullptr, nb_);                   \
            scan_add_kernel<<<((Vn) + 255) / 256, 256, 0, stream>>>((offp), SCR_BO, (Vn));       \
        }                                                                                        \
    }

#define BSORT(cntP, offP, srcP, stD, stS, ep, En, Vn, SHIFT, NB)                                 \
    {                                                                                            \
        MSI(GCNT, 256);                                                                          \
        bin_count_kernel<<<((En) + 4095) / 4096, 256, 0, stream>>>((ep) + (En), GCNT, En, SHIFT);\
        scan1_kernel<<<1, 256, 0, stream>>>(GCNT, GCUR, nullptr, NB);                            \
        bin_scatter_kernel<<<((En) + 4095) / 4096, 256, 0, stream>>>(                            \
            (ep), (ep) + (En), GCUR, stD, stS, En, SHIFT);                                       \
        bucket_csr_kernel<<<NB, 1024, 0, stream>>>(                                              \
            GCUR, GCNT, stD, stS, cntP, offP, srcP, Vn, SHIFT);                                  \
    }

#define ESORT(base, ep, En, Vn)                                                                  \
    int* cnt_ = (base);                                                                          \
    int* off_ = cnt_ + (Vn);                                                                     \
    int* src_ = off_ + (Vn);                                                                     \
    MSI(cnt_, (Vn));                                                                             \
    edge_count_kernel<<<((En) + 255) / 256, 256, 0, stream>>>((ep) + (En), cnt_, En);            \
    SCAN(cnt_, off_, (Vn));                                                                      \
    edge_scatter_kernel<<<8 * (((En) + 1023) / 1024), 256, 0, stream>>>(                         \
        (ep), (ep) + (En), off_, src_, En, (Vn) >> 3)

#define POOL(SB, hsrc, possrc, batp, bdiv, Vn, NX, NY, NT, COUTV, DM, hdst, posdst)         \
    {                                                                                       \
        int Vc = 4 * (NX) * (NY) * (NT);                                                    \
        float* SF   = (SB);                                                                 \
        float* SPOS = SF + (size_t)(Vn) * (COUTV);                                          \
        int* ICL  = (int*)(SPOS + (size_t)(Vn) * 3);                                        \
        int* IORD = ICL + (Vn);                                                             \
        int* ICNT = IORD + (Vn);                                                            \
        int* IOFF = ICNT + Vc;                                                              \
        MSI(ICNT, Vc);                                                                      \
        pool_cluster_kernel<<<((Vn) + 255) / 256, 256, 0, stream>>>(                        \
            possrc, batp, bdiv, Vn, NX, NY, NT, ICL, ICNT);                                 \
        SCAN(ICNT, IOFF, Vc);                                                               \
        pool_scatter_kernel<<<8 * (((Vn) + 1023) / 1024), 256, 0, stream>>>(                \
            ICL, IOFF, IORD, Vn, Vc >> 3);                                                  \
        pool_copy_kernel<COUTV><<<((size_t)(Vn) * (COUTV) + 255) / 256, 256, 0, stream>>>(  \
            IORD, hsrc, possrc, SF, SPOS, Vn);                                              \
        pool_reduce_kernel<COUTV, DM><<<((size_t)Vc * (COUTV) + 255) / 256, 256, 0,         \
            stream>>>(IOFF, ICNT, SF, SPOS, hdst, posdst, Vc);                              \
    }

    // ---------- Layer 1: 300000 nodes, CIN=3, COUT=16 ----------
    {
        int* cnt1 = (int*)P0;
        int* off1 = cnt1 + 300000;
        int* src1 = off1 + 300000;
        int* stD  = src1 + 3600000;
        int* stS  = stD + 3600000;
        float4* xp4 = (float4*)(P0 + 11400000);
        BSORT(cnt1, off1, src1, stD, stS, e1, E1, 300000, 11, 147);
        pack_xpos_kernel<<<(300000 + 255) / 256, 256, 0, stream>>>(x, pos0, xp4, 300000);
        l1_fused_kernel<<<(300000 + 255) / 256, 256, 0, stream>>>(
            off1, cnt1, src1, xp4, W1, R1, B1, P1, 20.0f, 300000);
        // CSR + staging + xp4 dead -> pool scratch at P0. h1 (stride 16) -> P2, pos2 -> P4.
        POOL(P0, P1, pos0, bat, 0, 300000, 64, 48, 8, 16, 0, P2, P4);
    }
    // ---------- Layer 2: 98304 nodes, CINF=16, COUT=64 (quarter-wave tsum) ----------
    {
        int* cnt2 = P3;
        int* off2 = cnt2 + 98304;
        int* src2 = off2 + 98304;
        int* stD  = (int*)P0;
        int* stS  = stD + E2;
        BSORT(cnt2, off2, src2, stD, stS, e2, E2, 98304, 10, 96);
        tsum16_layer_kernel<4><<<98304 / 16, 256, 0, stream>>>(
            off2, cnt2, src2, P4, P2, W2, R2, B2, P1, 10.0f, 98304);
        POOL(P0, P1, P4, nullptr, 24576, 98304, 32, 24, 4, 64, 0, P2, P4);
    }
    // ---------- Layer 3: 12288 nodes, CINF=64, COUT=128 (tsum path) ----------
    {
        ESORT(P3, e3, E3, 12288);
        tsum_layer_kernel<64, 128, 4, 4><<<12288 / 16, 256, 0, stream>>>(
            off_, cnt_, src_, P4, P2, W3, R3, B3, P1, 6.0f, 12288);
        POOL(P0, P1, P4, nullptr, 3072, 12288, 16, 12, 2, 128, 0, P2, P4);
    }
    // ---------- Layer 4: 1536 nodes, CINF=128, COUT=128 -> out3 ----------
    {
        ESORT(P3, e4, E4, 1536);
        tsum_layer_kernel<128, 128, 2, 4><<<1536 / 8, 256, 0, stream>>>(
            off_, cnt_, src_, P4, P2, W4, R4, B4, out3, 3.0f, 1536);
        POOL(P0, out3, P4, nullptr, 384, 1536, 8, 6, 1, 128, 1, P2, P4);
    }
    // ---------- Layer 5: 192 nodes, CINF=128, COUT=128 -> hfin ----------
    {
        ESORT(P3, e5, E5, 192);
        tsum_layer_kernel<128, 128, 2, 4><<<192 / 8, 256, 0, stream>>>(
            off_, cnt_, src_, P4, P2, W5, R5, B5, hfin, 1.5f, 192);
    }
#undef POOL
#undef ESORT
#undef BSORT
#undef SCAN
#undef MSI
}